// Round 9
// baseline (366.568 us; speedup 1.0000x reference)
//
#include <hip/hip_runtime.h>
#include <math.h>

#define BB 64
#define T_FR 200
#define NA 48000
#define NBINS 24001

typedef __attribute__((ext_vector_type(4))) float f32x4;
typedef __attribute__((ext_vector_type(8))) short bf16x8;

__device__ __forceinline__ unsigned short f2bf(float x)
{
    unsigned u = __float_as_uint(x);
    u = (u + 0x7FFFu + ((u >> 16) & 1u)) >> 16;
    return (unsigned short)u;
}
__device__ __forceinline__ float bf2f(unsigned short h)
{
    return __uint_as_float(((unsigned)h) << 16);
}

__device__ __forceinline__ float2 cmul(float2 a, float2 b)
{
    return make_float2(a.x * b.x - a.y * b.y, a.x * b.y + a.y * b.x);
}
__device__ __forceinline__ float2 cadd(float2 a, float2 b){ return make_float2(a.x+b.x, a.y+b.y); }
__device__ __forceinline__ float2 csub(float2 a, float2 b){ return make_float2(a.x-b.x, a.y-b.y); }

__device__ __forceinline__ float2 cis_rev(float rev)
{
    return make_float2(__builtin_amdgcn_cosf(rev), __builtin_amdgcn_sinf(rev));
}

// ---------------- root tables ----------------
template<int R> __device__ __forceinline__ void fill_roots(float (&cr)[R], float (&si)[R]);
template<> __device__ __forceinline__ void fill_roots<3>(float (&cr)[3], float (&si)[3])
{
    const float S = 0.86602540378443865f;
    cr[0]=1.f; cr[1]=-0.5f; cr[2]=-0.5f;
    si[0]=0.f; si[1]=S;     si[2]=-S;
}
template<> __device__ __forceinline__ void fill_roots<5>(float (&cr)[5], float (&si)[5])
{
    cr[0]=1.f; cr[1]=0.30901699437494742f; cr[2]=-0.80901699437494742f;
    cr[3]=-0.80901699437494742f; cr[4]=0.30901699437494742f;
    si[0]=0.f; si[1]=0.95105651629515357f; si[2]=0.58778525229247313f;
    si[3]=-0.58778525229247313f; si[4]=-0.95105651629515357f;
}
template<> __device__ __forceinline__ void fill_roots<8>(float (&cr)[8], float (&si)[8])
{
    const float C = 0.70710678118654752f;
    cr[0]=1.f; cr[1]=C;  cr[2]=0.f;  cr[3]=-C; cr[4]=-1.f; cr[5]=-C;  cr[6]=0.f;  cr[7]=C;
    si[0]=0.f; si[1]=C;  si[2]=1.f;  si[3]=C;  si[4]=0.f;  si[5]=-C;  si[6]=-1.f; si[7]=-C;
}

// dftR<S,R>: X[k] = sum_j v[j] * e^{S*2pi*i*j*k/R}
template<int S, int R>
__device__ __forceinline__ void dftR(float2 (&v)[R])
{
    float cr[R], si[R];
    fill_roots<R>(cr, si);
    float2 o[R];
#pragma unroll
    for (int k = 0; k < R; ++k) {
        float re = 0.f, im = 0.f;
#pragma unroll
        for (int j = 0; j < R; ++j) {
            int m = (j * k) % R;
            float ur = cr[m], ui = (S > 0) ? si[m] : -si[m];
            re += v[j].x * ur - v[j].y * ui;
            im += v[j].x * ui + v[j].y * ur;
        }
        o[k] = make_float2(re, im);
    }
#pragma unroll
    for (int k = 0; k < R; ++k) v[k] = o[k];
}

__device__ __constant__ float C25R[17] = {1.f,0.968583161f,0.876306680f,0.728968627f,0.535826795f,0.309016994f,0.062790520f,-0.187381315f,-0.425779292f,-0.637423990f,-0.809016994f,-0.929776486f,-0.992114701f,-0.992114701f,-0.929776486f,-0.809016994f,-0.637423990f};
__device__ __constant__ float C25I[17] = {0.f,0.248689887f,0.481753674f,0.684547106f,0.844327926f,0.951056516f,0.998026728f,0.982287251f,0.904827052f,0.770513243f,0.587785252f,0.368124553f,0.125333234f,-0.125333234f,-0.368124553f,-0.587785252f,-0.770513243f};
__device__ __constant__ float C15R[9] = {1.f,0.913545458f,0.669130606f,0.309016994f,-0.104528463f,-0.5f,-0.809016994f,-0.978147601f,-0.978147601f};
__device__ __constant__ float C15I[9] = {0.f,0.406736643f,0.743144825f,0.951056516f,0.994521895f,0.866025404f,0.587785252f,0.207911691f,-0.207911691f};
__device__ __constant__ float C16R[10] = {1.f,0.923879533f,0.707106781f,0.382683432f,0.f,-0.382683432f,-0.707106781f,-0.923879533f,-1.f,-0.923879533f};
__device__ __constant__ float C16I[10] = {0.f,0.382683432f,0.707106781f,0.923879533f,1.f,0.923879533f,0.707106781f,0.382683432f,0.f,-0.382683432f};

// twXX<S>(m) = e^{S*2pi*i*m/XX}
template<int S> __device__ __forceinline__ float2 tw25(int m){ return make_float2(C25R[m], S>0? C25I[m] : -C25I[m]); }
template<int S> __device__ __forceinline__ float2 tw15(int m){ return make_float2(C15R[m], S>0? C15I[m] : -C15I[m]); }
template<int S> __device__ __forceinline__ float2 tw16(int m){ return make_float2(C16R[m], S>0? C16I[m] : -C16I[m]); }

// ---------------- register sub-FFTs ----------------
template<int S> __device__ __forceinline__ void f4(float2& x0, float2& x1, float2& x2, float2& x3)
{
    float2 e = cadd(x0,x2), f = csub(x0,x2), g = cadd(x1,x3), h = csub(x1,x3);
    float2 r = (S<0) ? make_float2(h.y, -h.x) : make_float2(-h.y, h.x);
    x0 = cadd(e,g); x2 = csub(e,g); x1 = cadd(f,r); x3 = csub(f,r);
}

// fft16: natural-order in/out 16-point DFT (4x4), all registers.
template<int S> __device__ __forceinline__ void fft16(float2 (&v)[16])
{
    float2 t[4][4];
#pragma unroll
    for (int q = 0; q < 4; ++q) {
        float2 a = v[q], b = v[4+q], c = v[8+q], d = v[12+q];
        f4<S>(a,b,c,d);
        t[q][0]=a; t[q][1]=b; t[q][2]=c; t[q][3]=d;
    }
#pragma unroll
    for (int q = 1; q < 4; ++q)
#pragma unroll
        for (int r = 1; r < 4; ++r)
            t[q][r] = cmul(t[q][r], tw16<S>(q*r));
#pragma unroll
    for (int r = 0; r < 4; ++r) {
        float2 a=t[0][r], b=t[1][r], c=t[2][r], d=t[3][r];
        f4<S>(a,b,c,d);
        v[r]=a; v[r+4]=b; v[r+8]=c; v[r+12]=d;
    }
}

// fft15: natural-order in/out 15-point DFT (3x5), all registers.
template<int S> __device__ __forceinline__ void fft15(float2 (&v)[15])
{
    float2 t[5][3]; // t[d][e]
#pragma unroll
    for (int d = 0; d < 5; ++d) {
        float2 u[3] = { v[d], v[5+d], v[10+d] };
        dftR<S,3>(u);
        t[d][0]=u[0];
        t[d][1]=cmul(u[1], tw15<S>(d));
        t[d][2]=cmul(u[2], tw15<S>(2*d));
    }
#pragma unroll
    for (int e = 0; e < 3; ++e) {
        float2 u[5] = { t[0][e],t[1][e],t[2][e],t[3][e],t[4][e] };
        dftR<S,5>(u);
#pragma unroll
        for (int g = 0; g < 5; ++g) v[e + 3*g] = u[g];
    }
}

// fft25: natural-order in/out 25-point DFT (5x5), all registers.
template<int S> __device__ __forceinline__ void fft25(float2 (&v)[25])
{
    float2 t[5][5]; // t[d][e]
#pragma unroll
    for (int d = 0; d < 5; ++d) {
        float2 u[5] = { v[d], v[5+d], v[10+d], v[15+d], v[20+d] };
        dftR<S,5>(u);
        t[d][0] = u[0];
#pragma unroll
        for (int e = 1; e < 5; ++e) t[d][e] = cmul(u[e], tw25<S>(d*e));
    }
#pragma unroll
    for (int e = 0; e < 5; ++e) {
        float2 u[5] = { t[0][e],t[1][e],t[2][e],t[3][e],t[4][e] };
        dftR<S,5>(u);
#pragma unroll
        for (int g = 0; g < 5; ++g) v[e + 5*g] = u[g];
    }
}

// 200-spectrum slot: f = f1 + 8*f2 stored at 25*f1 + f2
__device__ __forceinline__ int slotn(int f) { return 25 * (f & 7) + (f >> 3); }

// Hermitian pair combine (verified)
__device__ __forceinline__ void pair_combine(float2 Za, float2 Zb, float g1, float g2,
                                             float2& C, float2& Cp, float& e1, float& e2)
{
    float2 X1 = make_float2(0.5f * (Za.x + Zb.x), 0.5f * (Za.y - Zb.y));
    float2 w  = make_float2(0.5f * (Za.x - Zb.x), 0.5f * (Za.y + Zb.y));
    float2 X2 = make_float2(w.y, -w.x);
    float2 Z1 = make_float2(g1 * X1.x, g1 * X1.y);
    float2 Z2 = make_float2(g2 * X2.x, g2 * X2.y);
    e1 = Z1.x * Z1.x + Z1.y * Z1.y;
    e2 = Z2.x * Z2.x + Z2.y * Z2.y;
    C  = make_float2(Z1.x - Z2.y,  Z1.y + Z2.x);
    Cp = make_float2(Z1.x + Z2.y, -Z1.y + Z2.x);
}

// ================= MFMA conv (unchanged, verified) =================
template<int NT, int TAPS, int CHUNKS, int CINP, int COUTP>
__global__ __launch_bounds__(256) void conv_mfma_kernel(
    const unsigned short* __restrict__ xT, int tRowsIn,
    const unsigned short* __restrict__ wT,
    const float* __restrict__ bias,
    unsigned short* __restrict__ outT, int tRowsOut, int tOffOut)
{
    const int b = blockIdx.y;
    const int t0 = blockIdx.x * 16;
    const int tid = threadIdx.x;
    const int wave = tid >> 6;
    const int lane = tid & 63;
    const int m = lane & 15;
    const int quad = lane >> 4;
    const int n0 = wave * (NT * 16);

    f32x4 acc[NT];
#pragma unroll
    for (int nt = 0; nt < NT; ++nt) acc[nt] = (f32x4){0.f, 0.f, 0.f, 0.f};

    const unsigned short* xb = xT + (size_t)b * tRowsIn * CINP;
#pragma unroll
    for (int kw = 0; kw < TAPS; ++kw) {
        const unsigned short* wk = wT + (size_t)kw * COUTP * CINP;
        const unsigned short* xrow = xb + (size_t)(t0 + kw + m) * CINP + quad * 8;
#pragma unroll
        for (int ch = 0; ch < CHUNKS; ++ch) {
            const int k0 = ch * 32;
            bf16x8 a = *(const bf16x8*)(xrow + k0);
#pragma unroll
            for (int nt = 0; nt < NT; ++nt) {
                bf16x8 bfr = *(const bf16x8*)(wk + (size_t)(n0 + nt * 16 + m) * CINP + k0 + quad * 8);
                acc[nt] = __builtin_amdgcn_mfma_f32_16x16x32_bf16(a, bfr, acc[nt], 0, 0, 0);
            }
        }
    }
#pragma unroll
    for (int nt = 0; nt < NT; ++nt) {
        const int n = n0 + nt * 16 + m;
        const float bz = bias[n];
#pragma unroll
        for (int r = 0; r < 4; ++r) {
            const int t = t0 + quad * 4 + r;
            if (t < 200) {
                float v = acc[nt][r] + bz;
                v = (v >= 0.f) ? v : 0.1f * v;
                outT[((size_t)b * tRowsOut + t + tOffOut) * COUTP + n] = f2bf(v);
            }
        }
    }
}

__global__ void prep_x1_kernel(const float* __restrict__ cond, const float* __restrict__ f0,
                               unsigned short* __restrict__ xpT1)
{
    int idx = blockIdx.x * 256 + threadIdx.x;
    const int total = BB * 212 * 160;
    if (idx >= total) return;
    int i = idx % 160;
    int rest = idx / 160;
    int tp = rest % 212;
    int b = rest / 212;
    int tt = tp - 2;
    float v = 0.f;
    if (tt >= 0 && tt < 200) {
        if (i < 128) v = cond[((size_t)b * 128 + i) * 200 + tt];
        else if (i == 128) v = (f0[b * 200 + tt] > 0.f) ? 1.f : 0.f;
    }
    xpT1[idx] = f2bf(v);
}

template<int TAPS, int CINR, int CINP, int COUTP>
__global__ void prep_w_kernel(const float* __restrict__ w, unsigned short* __restrict__ wT)
{
    int idx = blockIdx.x * 256 + threadIdx.x;
    const int total = TAPS * COUTP * CINP;
    if (idx >= total) return;
    int i = idx % CINP;
    int rest = idx / CINP;
    int o = rest % COUTP;
    int kw = rest / COUTP;
    float v = (i < CINR) ? w[((size_t)o * CINR + i) * TAPS + kw] : 0.f;
    wT[idx] = f2bf(v);
}

__global__ void zero16_kernel(uint4* __restrict__ p, int n16)
{
    int idx = blockIdx.x * 256 + threadIdx.x;
    if (idx < n16) p[idx] = make_uint4(0, 0, 0, 0);
}

// ================= FFT passes =================
// 240 = 16 x 15: n1 = 15a+b; f = f1 + 16*f2. LDS slot layout: col[f1*15 + b].
// 200 = 8 x 25 : e  = 25a+b; f = f1 +  8*f2. LDS slot layout: row[f1*25 + f2].
// All passes: single-wave 64-thread blocks (barrier drains elided by backend).

// pass A: 4 columns/block, 64 threads, grid 50x32.
__global__ __launch_bounds__(64) void passA_kernel(const float* __restrict__ wn,
                                                   float2* __restrict__ I)
{
    __shared__ float2 L[4 * 241];
    int q = blockIdx.y;
    const float* w1p = wn + (size_t)(2 * q) * NA;
    const float* w2p = wn + (size_t)(2 * q + 1) * NA;
    int n20 = blockIdx.x * 4;
    int tid = threadIdx.x;

    if (tid < 60) {
        int b = tid >> 2, j = tid & 3;
        int n2 = n20 + j;
        float2 v[16];
#pragma unroll
        for (int a = 0; a < 16; ++a) {
            int n = (15 * a + b) * 200 + n2;
            v[a] = make_float2(w1p[n], w2p[n]);
        }
        fft16<-1>(v);
#pragma unroll
        for (int f1 = 1; f1 < 16; ++f1)
            v[f1] = cmul(v[f1], cis_rev(-(float)(b * f1) * (1.f / 240.f)));
        float2* col = L + j * 241;
#pragma unroll
        for (int f1 = 0; f1 < 16; ++f1) col[f1 * 15 + b] = v[f1];
    }
    __syncthreads();
    {
        int f1 = tid >> 2, j = tid & 3;
        int n2 = n20 + j;
        float2* col = L + j * 241;
        float2 u[15];
#pragma unroll
        for (int b = 0; b < 15; ++b) u[b] = col[f1 * 15 + b];
        fft15<-1>(u);
#pragma unroll
        for (int f2 = 0; f2 < 15; ++f2) {
            int f = f1 + 16 * f2;
            I[(size_t)q * NA + (size_t)f * 200 + n2] =
                cmul(u[f2], cis_rev(-(float)(n2 * f) * (1.f / (float)NA)));
        }
    }
}

// pass B: 4 conjugate row-pairs per block, 64 threads (single wave), grid 30x32.
// (verified round 8)
template<int MODE>
__global__ __launch_bounds__(64) void passB_kernel(float2* __restrict__ I,
    const float* __restrict__ avg_shape, const float* __restrict__ fbins,
    const float* __restrict__ loc_w, float* __restrict__ acc, float* __restrict__ z0)
{
    __shared__ float2 L[8 * 202];
    __shared__ float g1sh[32], g2sh[32];
    int q = blockIdx.y;
    int b1 = 2 * q, b2 = 2 * q + 1;
    int bx = blockIdx.x;
    int tid = threadIdx.x;
    if (MODE == 0) {
        if (tid < 32) { g1sh[tid] = avg_shape[b1 * 32 + tid]; g2sh[tid] = avg_shape[b2 * 32 + tid]; }
    } else {
        if (tid < 5) { g1sh[tid] = loc_w[b1 * 5 + tid]; g2sh[tid] = loc_w[b2 * 5 + tid]; }
    }
    int Rrow[8];
#pragma unroll
    for (int s = 0; s < 8; ++s) {
        int p = s >> 1;
        int pi = 4 * bx + p;
        Rrow[s] = (pi == 0) ? ((s & 1) ? 120 : 0) : ((s & 1) ? 240 - pi : pi);
    }
    // F1
    for (int idx = tid; idx < 200; idx += 64) {
        int s = idx / 25, b = idx - 25 * s;
        const float2* g = I + (size_t)q * NA + (size_t)Rrow[s] * 200;
        float2 v[8];
#pragma unroll
        for (int a = 0; a < 8; ++a) v[a] = g[25 * a + b];
        dftR<-1, 8>(v);
#pragma unroll
        for (int f1 = 1; f1 < 8; ++f1)
            v[f1] = cmul(v[f1], cis_rev(-(float)(b * f1) * (1.f / 200.f)));
        float2* row = L + s * 202;
#pragma unroll
        for (int f1 = 0; f1 < 8; ++f1) row[f1 * 25 + b] = v[f1];
    }
    __syncthreads();
    // F2
    {
        int s = tid >> 3, f1 = tid & 7;
        float2* row = L + s * 202;
        float2 u[25];
#pragma unroll
        for (int b = 0; b < 25; ++b) u[b] = row[f1 * 25 + b];
        fft25<-1>(u);
#pragma unroll
        for (int f2 = 0; f2 < 25; ++f2) row[f1 * 25 + f2] = u[f2];
    }
    __syncthreads();
    // combine
    float part1 = 0.f, part2 = 0.f;
    for (int idx = tid; idx < 804; idx += 64) {
        int p = idx / 201, t = idx - p * 201;
        int pi = 4 * bx + p;
        float2* rwA = L + (2 * p) * 202;
        float2* rwB = L + (2 * p + 1) * 202;
        int k = -1;
        float2 Za, Zb;
        int sa = 0, sb = 0;
        float2* wa = rwA; float2* wb = rwB;
        bool self1 = false;
        if (pi != 0) {
            if (t >= 200) continue;
            sa = slotn(t); sb = slotn(199 - t);
            Za = rwA[sa]; Zb = rwB[sb];
            k = pi + 240 * t;
        } else if (t < 101) {
            wa = rwA; wb = rwA;
            if (t == 0 || t == 100) {
                sa = slotn(t); sb = sa;
                Za = rwA[sa]; Zb = Za;
                k = 240 * t;
                self1 = true;
            } else {
                sa = slotn(t); sb = slotn(200 - t);
                Za = rwA[sa]; Zb = rwA[sb];
                k = 240 * t;
            }
        } else {
            int t2 = t - 101;
            if (t2 >= 100) continue;
            wa = rwB; wb = rwB;
            sa = slotn(t2); sb = slotn(199 - t2);
            Za = rwB[sa]; Zb = rwB[sb];
            k = 120 + 240 * t2;
        }
        int kbin = min(k, NA - k);
        float g1, g2;
        if (MODE == 0) {
            int jj = (kbin * 32) / NBINS;
            if (jj < 31 && (NBINS * (jj + 1)) / 32 <= kbin) ++jj;
            g1 = g1sh[jj]; g2 = g2sh[jj];
        } else {
            g1 = 0.f; g2 = 0.f;
#pragma unroll
            for (int c = 0; c < 5; ++c) {
                float fb = fbins[c * NBINS + kbin];
                g1 += g1sh[c] * fb; g2 += g2sh[c] * fb;
            }
        }
        float2 C, Cp; float e1, e2;
        pair_combine(Za, Zb, g1, g2, C, Cp, e1, e2);
        if (MODE == 0) {
            float wgt = self1 ? 1.f : 2.f;
            part1 += wgt * e1; part2 += wgt * e2;
            if (k == 0) { z0[b1] = g1 * Za.x; z0[b2] = g2 * Za.y; }
        }
        wa[sa] = make_float2(C.x * (1.f / NA), C.y * (1.f / NA));
        if (!self1) wb[sb] = make_float2(Cp.x * (1.f / NA), Cp.y * (1.f / NA));
    }
    if (MODE == 0) {
        for (int o = 32; o > 0; o >>= 1) {
            part1 += __shfl_down(part1, o);
            part2 += __shfl_down(part2, o);
        }
        if (tid == 0) { atomicAdd(&acc[b1], part1); atomicAdd(&acc[b2], part2); }
    }
    __syncthreads();
    // I1
    {
        int s = tid >> 3, f1 = tid & 7;
        float2* row = L + s * 202;
        float2 u[25];
#pragma unroll
        for (int f2 = 0; f2 < 25; ++f2) u[f2] = row[f1 * 25 + f2];
        fft25<+1>(u);
#pragma unroll
        for (int b = 0; b < 25; ++b) row[f1 * 25 + b] = u[b];
    }
    __syncthreads();
    // I2
    for (int idx = tid; idx < 200; idx += 64) {
        int s = idx / 25, b = idx - 25 * s;
        float2* row = L + s * 202;
        float2 w[8];
#pragma unroll
        for (int f1 = 0; f1 < 8; ++f1) w[f1] = row[f1 * 25 + b];
#pragma unroll
        for (int f1 = 1; f1 < 8; ++f1)
            w[f1] = cmul(w[f1], cis_rev((float)(b * f1) * (1.f / 200.f)));
        dftR<+1, 8>(w);
        int rg = Rrow[s];
        float2* g = I + (size_t)q * NA + (size_t)rg * 200;
#pragma unroll
        for (int a = 0; a < 8; ++a) {
            int e = 25 * a + b;
            g[e] = cmul(w[a], cis_rev((float)(e * rg) * (1.f / (float)NA)));
        }
    }
}

// pass C: inv240 -> modulate -> fwd240; 4 columns/block, 64 threads, grid 50x32.
__global__ __launch_bounds__(64) void passC_kernel(float2* __restrict__ I,
    const float* __restrict__ control, const float* __restrict__ f0,
    const float* __restrict__ scale)
{
    __shared__ float2 L[4 * 241];
    __shared__ float ctlA[600], ctlB[600];
    __shared__ float f0A[200], f0B[200];
    int q = blockIdx.y;
    int b1 = 2 * q, b2 = 2 * q + 1;
    int n20 = blockIdx.x * 4;
    int tid = threadIdx.x;
    for (int i = tid; i < 600; i += 64) {
        ctlA[i] = control[(size_t)b1 * 1600 + i];
        ctlB[i] = control[(size_t)b2 * 1600 + i];
    }
    for (int i = tid; i < 200; i += 64) {
        f0A[i] = f0[b1 * 200 + i];
        f0B[i] = f0[b2 * 200 + i];
    }
    // ph1: (f1, j): gather 15 rows, fft15 inv -> LDS (64 items = all lanes)
    {
        int f1 = tid >> 2, j = tid & 3;
        int n2 = n20 + j;
        float2 u[15];
#pragma unroll
        for (int f2 = 0; f2 < 15; ++f2)
            u[f2] = I[(size_t)q * NA + (size_t)(f1 + 16 * f2) * 200 + n2];
        fft15<+1>(u);
        float2* col = L + j * 241;
#pragma unroll
        for (int b = 0; b < 15; ++b) col[f1 * 15 + b] = u[b];
    }
    __syncthreads();
    // ph2: (b, j): inv-fft16 + modulate + fwd-fft16 in registers (60 items)
    if (tid < 60) {
        int b = tid >> 2, j = tid & 3;
        int n2 = n20 + j;
        float2* col = L + j * 241;
        float sc1 = scale[b1], sc2 = scale[b2];
        float2 w[16];
#pragma unroll
        for (int f1 = 0; f1 < 16; ++f1) w[f1] = col[f1 * 15 + b];
#pragma unroll
        for (int f1 = 1; f1 < 16; ++f1)
            w[f1] = cmul(w[f1], cis_rev((float)(b * f1) * (1.f / 240.f)));
        fft16<+1>(w);
#pragma unroll
        for (int a = 0; a < 16; ++a) {
            int n = 200 * (15 * a + b) + n2;
            float sf = ((float)n + 0.5f) * (1.f / 240.f) - 0.5f;
            sf = fminf(fmaxf(sf, 0.f), 199.f);
            int i0 = (int)sf;
            int i1 = min(i0 + 1, 199);
            float wt = sf - (float)i0, w0 = 1.f - wt;
            float inh = ctlA[i0] * w0 + ctlA[i1] * wt;
            float exh = ctlA[200 + i0] * w0 + ctlA[200 + i1] * wt;
            float pr  = ctlA[400 + i0] * w0 + ctlA[400 + i1] * wt;
            float vv  = (f0A[i0] > 0.f ? 1.f : 0.f) * w0 + (f0A[i1] > 0.f ? 1.f : 0.f) * wt;
            float m1 = inh * (1.f - vv) + exh * pr;
            inh = ctlB[i0] * w0 + ctlB[i1] * wt;
            exh = ctlB[200 + i0] * w0 + ctlB[200 + i1] * wt;
            pr  = ctlB[400 + i0] * w0 + ctlB[400 + i1] * wt;
            vv  = (f0B[i0] > 0.f ? 1.f : 0.f) * w0 + (f0B[i1] > 0.f ? 1.f : 0.f) * wt;
            float m2 = inh * (1.f - vv) + exh * pr;
            w[a] = make_float2(w[a].x * sc1 * m1, w[a].y * sc2 * m2);
        }
        fft16<-1>(w);
#pragma unroll
        for (int f1 = 1; f1 < 16; ++f1)
            w[f1] = cmul(w[f1], cis_rev(-(float)(b * f1) * (1.f / 240.f)));
#pragma unroll
        for (int f1 = 0; f1 < 16; ++f1) col[f1 * 15 + b] = w[f1];
    }
    __syncthreads();
    // ph3: (f1, j): fft15 fwd, write global with 4-step twiddle (64 items)
    {
        int f1 = tid >> 2, j = tid & 3;
        int n2 = n20 + j;
        float2* col = L + j * 241;
        float2 u[15];
#pragma unroll
        for (int b = 0; b < 15; ++b) u[b] = col[f1 * 15 + b];
        fft15<-1>(u);
#pragma unroll
        for (int f2 = 0; f2 < 15; ++f2) {
            int f = f1 + 16 * f2;
            I[(size_t)q * NA + (size_t)f * 200 + n2] =
                cmul(u[f2], cis_rev(-(float)(n2 * f) * (1.f / (float)NA)));
        }
    }
}

// pass D: inv240 -> two real outputs; 4 columns/block, 64 threads, grid 50x32.
__global__ __launch_bounds__(64) void passD_kernel(const float2* __restrict__ I,
                                                   float* __restrict__ out)
{
    __shared__ float2 L[4 * 241];
    int q = blockIdx.y;
    int b1 = 2 * q, b2 = 2 * q + 1;
    int n20 = blockIdx.x * 4;
    int tid = threadIdx.x;
    {
        int f1 = tid >> 2, j = tid & 3;
        int n2 = n20 + j;
        float2 u[15];
#pragma unroll
        for (int f2 = 0; f2 < 15; ++f2)
            u[f2] = I[(size_t)q * NA + (size_t)(f1 + 16 * f2) * 200 + n2];
        fft15<+1>(u);
        float2* col = L + j * 241;
#pragma unroll
        for (int b = 0; b < 15; ++b) col[f1 * 15 + b] = u[b];
    }
    __syncthreads();
    if (tid < 60) {
        int b = tid >> 2, j = tid & 3;
        int n2 = n20 + j;
        float2* col = L + j * 241;
        float2 w[16];
#pragma unroll
        for (int f1 = 0; f1 < 16; ++f1) w[f1] = col[f1 * 15 + b];
#pragma unroll
        for (int f1 = 1; f1 < 16; ++f1)
            w[f1] = cmul(w[f1], cis_rev((float)(b * f1) * (1.f / 240.f)));
        fft16<+1>(w);
#pragma unroll
        for (int a = 0; a < 16; ++a) {
            int n = 200 * (15 * a + b) + n2;
            out[(size_t)b1 * NA + n] = w[a].x;
            out[(size_t)b2 * NA + n] = w[a].y;
        }
    }
}

__global__ void init_kernel(float* __restrict__ acc, float* __restrict__ z0)
{
    int i = threadIdx.x;
    if (i < 64) { acc[i] = 0.f; z0[i] = 0.f; }
}

__global__ void finalize_scale(const float* __restrict__ acc, const float* __restrict__ z0,
                               float* __restrict__ scale)
{
    int b = threadIdx.x;
    if (b < 64) {
        float var = (acc[b] - z0[b] * z0[b]) / (48000.f * 47999.f);
        scale[b] = 0.1f / sqrtf(var);
    }
}

// ---------------- head ----------------
__global__ void head_kernel(const unsigned short* __restrict__ h3T, const float* __restrict__ w4,
                            const float* __restrict__ b4, float* __restrict__ control,
                            float* __restrict__ avg_shape, float* __restrict__ out_bf)
{
    __shared__ float w4s[40 * 64];
    __shared__ float b4s[40];
    __shared__ float sp[200 * 33];
    int b = blockIdx.x;
    for (int j = threadIdx.x; j < 40 * 64; j += 256) w4s[j] = w4[j];
    if (threadIdx.x < 40) b4s[threadIdx.x] = b4[threadIdx.x];
    __syncthreads();
    int t = threadIdx.x;
    if (t < 200) {
        float p[40];
#pragma unroll
        for (int o = 0; o < 40; ++o) p[o] = b4s[o];
        const unsigned short* hb = h3T + ((size_t)b * 200 + t) * 64;
        for (int i = 0; i < 64; ++i) {
            float h = bf2f(hb[i]);
#pragma unroll
            for (int o = 0; o < 40; ++o) p[o] += h * w4s[o * 64 + i];
        }
        float inh = 1.f / (1.f + expf(-p[0]));
        float exh = 1.f / (1.f + expf(-p[1]));
        float pr  = 1.f / (1.f + expf(-p[2]));
        float mx = p[3];
#pragma unroll
        for (int c = 1; c < 32; ++c) mx = fmaxf(mx, p[3 + c]);
        float e[32];
        float sum = 0.f;
#pragma unroll
        for (int c = 0; c < 32; ++c) { e[c] = expf(p[3 + c] - mx); sum += e[c]; }
        float inv = 1.f / sum;
#pragma unroll
        for (int c = 0; c < 32; ++c) sp[t * 33 + c] = e[c] * inv;
        float mx2 = p[35];
#pragma unroll
        for (int c = 1; c < 5; ++c) mx2 = fmaxf(mx2, p[35 + c]);
        float e2[5];
        float s2 = 0.f;
#pragma unroll
        for (int c = 0; c < 5; ++c) { e2[c] = expf(p[35 + c] - mx2); s2 += e2[c]; }
        float inv2 = 1.f / s2;
        float* ctl = control + (size_t)b * 8 * 200;
        ctl[0 * 200 + t] = inh;
        ctl[1 * 200 + t] = exh;
        ctl[2 * 200 + t] = pr;
#pragma unroll
        for (int c = 0; c < 5; ++c) ctl[(3 + c) * 200 + t] = e2[c] * inv2;
        float* bf = out_bf + (size_t)b * 3 * 200;
        bf[0 * 200 + t] = pr;
        bf[1 * 200 + t] = inh;
        bf[2 * 200 + t] = exh;
    }
    __syncthreads();
    if (t < 32) {
        float s = 0.f;
        for (int j = 0; j < 200; ++j) s += sp[j * 33 + t];
        avg_shape[b * 32 + t] = s * (1.f / 200.f);
    }
}

// loc_w[b,c] = mean_t turb[b,c,t]
__global__ void locw_mean_kernel(const float* __restrict__ control, float* __restrict__ loc_w)
{
    int c = blockIdx.x, b = blockIdx.y;
    int tid = threadIdx.x;
    const float* src = control + ((size_t)b * 8 + 3 + c) * 200;
    float s = (tid < 200) ? src[tid] : 0.f;
    for (int o = 32; o > 0; o >>= 1) s += __shfl_down(s, o);
    __shared__ float red[4];
    if ((tid & 63) == 0) red[tid >> 6] = s;
    __syncthreads();
    if (tid == 0) loc_w[b * 5 + c] = (red[0] + red[1] + red[2] + red[3]) * (1.f / 200.f);
}

__device__ inline float filter_shape_val(int c, int i)
{
    float lin = (float)i * (1.f / 31.f);
    if (c == 0) { float z = (lin - 0.2f) * 10.f;          return expf(-0.5f * z * z); }
    if (c == 1) { float z = (lin - 0.1f) * 10.f;          return expf(-0.5f * z * z); }
    if (c == 2) { float z = (lin - 0.4f) * (1.f / 0.15f); return expf(-0.5f * z * z); }
    if (c == 3) { float z = (lin - 0.6f) * 10.f;          return expf(-0.5f * z * z); }
    float v = 0.1f + 0.9f * lin;
    return v * v;
}

__global__ void fbins_kernel(float* __restrict__ fbins)
{
    int k = blockIdx.x * 256 + threadIdx.x;
    if (k >= NBINS) return;
    float sf = (k + 0.5f) * (32.0f / 24001.0f) - 0.5f;
    sf = fminf(fmaxf(sf, 0.f), 31.f);
    int i0 = (int)sf;
    int i1 = min(i0 + 1, 31);
    float w = sf - (float)i0;
#pragma unroll
    for (int c = 0; c < 5; ++c)
        fbins[c * NBINS + k] = filter_shape_val(c, i0) * (1.f - w) + filter_shape_val(c, i1) * w;
}

extern "C" void kernel_launch(void* const* d_in, const int* in_sizes, int n_in,
                              void* d_out, int out_size, void* d_ws, size_t ws_size,
                              hipStream_t stream)
{
    const float* cond = (const float*)d_in[0];
    const float* f0   = (const float*)d_in[1];
    const float* wn   = (const float*)d_in[2];
    const float* w1   = (const float*)d_in[3];
    const float* b1   = (const float*)d_in[4];
    const float* w2   = (const float*)d_in[5];
    const float* b2   = (const float*)d_in[6];
    const float* w3   = (const float*)d_in[7];
    const float* b3   = (const float*)d_in[8];
    const float* w4   = (const float*)d_in[9];
    const float* b4   = (const float*)d_in[10];

    float* out = (float*)d_out;
    float* filtered = out;
    float* bf_out   = out + (size_t)BB * NA;

    char* ws = (char*)d_ws;
    size_t off = 0;
    float2* I = (float2*)(ws + off);            off += 24576000;
    unsigned short* xpT1 = (unsigned short*)(ws + off); off += (size_t)BB * 212 * 160 * 2;
    unsigned short* xpT2 = (unsigned short*)(ws + off); off += (size_t)BB * 210 * 256 * 2;
    unsigned short* xpT3 = (unsigned short*)(ws + off); off += (size_t)BB * 210 * 128 * 2;
    unsigned short* xpT4 = (unsigned short*)(ws + off); off += (size_t)BB * 200 * 64 * 2;
    unsigned short* wT1  = (unsigned short*)(ws + off); off += (size_t)5 * 256 * 160 * 2;
    unsigned short* wT2  = (unsigned short*)(ws + off); off += (size_t)3 * 128 * 256 * 2;
    unsigned short* wT3  = (unsigned short*)(ws + off); off += (size_t)3 * 64 * 128 * 2;
    float* control   = (float*)(ws + off);
    float* avg_shape = control + 102400;
    float* loc_w     = avg_shape + 2048;
    float* acc       = loc_w + 320;
    float* z0        = acc + 64;
    float* scale     = z0 + 64;
    float* fbins     = scale + 64;

    dim3 blk(256);

    init_kernel<<<1, 64, 0, stream>>>(acc, z0);

    // prep
    {
        int n1 = BB * 212 * 160;
        prep_x1_kernel<<<dim3((n1 + 255) / 256), blk, 0, stream>>>(cond, f0, xpT1);
        int z2 = (BB * 210 * 256 * 2) / 16;
        zero16_kernel<<<dim3((z2 + 255) / 256), blk, 0, stream>>>((uint4*)xpT2, z2);
        int z3 = (BB * 210 * 128 * 2) / 16;
        zero16_kernel<<<dim3((z3 + 255) / 256), blk, 0, stream>>>((uint4*)xpT3, z3);
        prep_w_kernel<5, 129, 160, 256><<<dim3((5 * 256 * 160 + 255) / 256), blk, 0, stream>>>(w1, wT1);
        prep_w_kernel<3, 256, 256, 128><<<dim3((3 * 128 * 256 + 255) / 256), blk, 0, stream>>>(w2, wT2);
        prep_w_kernel<3, 128, 128, 64><<<dim3((3 * 64 * 128 + 255) / 256), blk, 0, stream>>>(w3, wT3);
    }

    // MFMA conv stack
    conv_mfma_kernel<4, 5, 5, 160, 256><<<dim3(13, BB), blk, 0, stream>>>(
        xpT1, 212, wT1, b1, xpT2, 210, 1);
    conv_mfma_kernel<2, 3, 8, 256, 128><<<dim3(13, BB), blk, 0, stream>>>(
        xpT2, 210, wT2, b2, xpT3, 210, 1);
    conv_mfma_kernel<1, 3, 4, 128, 64><<<dim3(13, BB), blk, 0, stream>>>(
        xpT3, 210, wT3, b3, xpT4, 200, 0);

    head_kernel<<<dim3(BB), blk, 0, stream>>>(xpT4, w4, b4, control, avg_shape, bf_out);
    locw_mean_kernel<<<dim3(5, BB), blk, 0, stream>>>(control, loc_w);
    fbins_kernel<<<dim3((NBINS + 255) / 256), blk, 0, stream>>>(fbins);

    // batch-paired four-step FFT pipeline (32 complex signals carry 64 real batches)
    passA_kernel<<<dim3(50, 32), dim3(64), 0, stream>>>(wn, I);
    passB_kernel<0><<<dim3(30, 32), dim3(64), 0, stream>>>(I, avg_shape, fbins, loc_w, acc, z0);
    finalize_scale<<<1, 64, 0, stream>>>(acc, z0, scale);
    passC_kernel<<<dim3(50, 32), dim3(64), 0, stream>>>(I, control, f0, scale);
    passB_kernel<1><<<dim3(30, 32), dim3(64), 0, stream>>>(I, avg_shape, fbins, loc_w, acc, z0);
    passD_kernel<<<dim3(50, 32), dim3(64), 0, stream>>>(I, filtered);
}

// Round 10
// 340.727 us; speedup vs baseline: 1.0758x; 1.0758x over previous
//
#include <hip/hip_runtime.h>
#include <math.h>

#define BB 64
#define T_FR 200
#define NA 48000
#define NBINS 24001

typedef __attribute__((ext_vector_type(4))) float f32x4;
typedef __attribute__((ext_vector_type(8))) short bf16x8;

__device__ __forceinline__ unsigned short f2bf(float x)
{
    unsigned u = __float_as_uint(x);
    u = (u + 0x7FFFu + ((u >> 16) & 1u)) >> 16;
    return (unsigned short)u;
}
__device__ __forceinline__ float bf2f(unsigned short h)
{
    return __uint_as_float(((unsigned)h) << 16);
}

__device__ __forceinline__ float2 cmul(float2 a, float2 b)
{
    return make_float2(a.x * b.x - a.y * b.y, a.x * b.y + a.y * b.x);
}
__device__ __forceinline__ float2 cadd(float2 a, float2 b){ return make_float2(a.x+b.x, a.y+b.y); }
__device__ __forceinline__ float2 csub(float2 a, float2 b){ return make_float2(a.x-b.x, a.y-b.y); }

__device__ __forceinline__ float2 cis_rev(float rev)
{
    return make_float2(__builtin_amdgcn_cosf(rev), __builtin_amdgcn_sinf(rev));
}

// ---------------- root tables ----------------
template<int R> __device__ __forceinline__ void fill_roots(float (&cr)[R], float (&si)[R]);
template<> __device__ __forceinline__ void fill_roots<3>(float (&cr)[3], float (&si)[3])
{
    const float S = 0.86602540378443865f;
    cr[0]=1.f; cr[1]=-0.5f; cr[2]=-0.5f;
    si[0]=0.f; si[1]=S;     si[2]=-S;
}
template<> __device__ __forceinline__ void fill_roots<5>(float (&cr)[5], float (&si)[5])
{
    cr[0]=1.f; cr[1]=0.30901699437494742f; cr[2]=-0.80901699437494742f;
    cr[3]=-0.80901699437494742f; cr[4]=0.30901699437494742f;
    si[0]=0.f; si[1]=0.95105651629515357f; si[2]=0.58778525229247313f;
    si[3]=-0.58778525229247313f; si[4]=-0.95105651629515357f;
}
template<> __device__ __forceinline__ void fill_roots<8>(float (&cr)[8], float (&si)[8])
{
    const float C = 0.70710678118654752f;
    cr[0]=1.f; cr[1]=C;  cr[2]=0.f;  cr[3]=-C; cr[4]=-1.f; cr[5]=-C;  cr[6]=0.f;  cr[7]=C;
    si[0]=0.f; si[1]=C;  si[2]=1.f;  si[3]=C;  si[4]=0.f;  si[5]=-C;  si[6]=-1.f; si[7]=-C;
}

// dftR<S,R>: X[k] = sum_j v[j] * e^{S*2pi*i*j*k/R}
template<int S, int R>
__device__ __forceinline__ void dftR(float2 (&v)[R])
{
    float cr[R], si[R];
    fill_roots<R>(cr, si);
    float2 o[R];
#pragma unroll
    for (int k = 0; k < R; ++k) {
        float re = 0.f, im = 0.f;
#pragma unroll
        for (int j = 0; j < R; ++j) {
            int m = (j * k) % R;
            float ur = cr[m], ui = (S > 0) ? si[m] : -si[m];
            re += v[j].x * ur - v[j].y * ui;
            im += v[j].x * ui + v[j].y * ur;
        }
        o[k] = make_float2(re, im);
    }
#pragma unroll
    for (int k = 0; k < R; ++k) v[k] = o[k];
}

__device__ __constant__ float C25R[17] = {1.f,0.968583161f,0.876306680f,0.728968627f,0.535826795f,0.309016994f,0.062790520f,-0.187381315f,-0.425779292f,-0.637423990f,-0.809016994f,-0.929776486f,-0.992114701f,-0.992114701f,-0.929776486f,-0.809016994f,-0.637423990f};
__device__ __constant__ float C25I[17] = {0.f,0.248689887f,0.481753674f,0.684547106f,0.844327926f,0.951056516f,0.998026728f,0.982287251f,0.904827052f,0.770513243f,0.587785252f,0.368124553f,0.125333234f,-0.125333234f,-0.368124553f,-0.587785252f,-0.770513243f};
__device__ __constant__ float C15R[9] = {1.f,0.913545458f,0.669130606f,0.309016994f,-0.104528463f,-0.5f,-0.809016994f,-0.978147601f,-0.978147601f};
__device__ __constant__ float C15I[9] = {0.f,0.406736643f,0.743144825f,0.951056516f,0.994521895f,0.866025404f,0.587785252f,0.207911691f,-0.207911691f};
__device__ __constant__ float C16R[10] = {1.f,0.923879533f,0.707106781f,0.382683432f,0.f,-0.382683432f,-0.707106781f,-0.923879533f,-1.f,-0.923879533f};
__device__ __constant__ float C16I[10] = {0.f,0.382683432f,0.707106781f,0.923879533f,1.f,0.923879533f,0.707106781f,0.382683432f,0.f,-0.382683432f};

// twXX<S>(m) = e^{S*2pi*i*m/XX}
template<int S> __device__ __forceinline__ float2 tw25(int m){ return make_float2(C25R[m], S>0? C25I[m] : -C25I[m]); }
template<int S> __device__ __forceinline__ float2 tw15(int m){ return make_float2(C15R[m], S>0? C15I[m] : -C15I[m]); }
template<int S> __device__ __forceinline__ float2 tw16(int m){ return make_float2(C16R[m], S>0? C16I[m] : -C16I[m]); }

// ---------------- register sub-FFTs ----------------
template<int S> __device__ __forceinline__ void f4(float2& x0, float2& x1, float2& x2, float2& x3)
{
    float2 e = cadd(x0,x2), f = csub(x0,x2), g = cadd(x1,x3), h = csub(x1,x3);
    float2 r = (S<0) ? make_float2(h.y, -h.x) : make_float2(-h.y, h.x);
    x0 = cadd(e,g); x2 = csub(e,g); x1 = cadd(f,r); x3 = csub(f,r);
}

// fft16: natural-order in/out 16-point DFT (4x4), all registers.
template<int S> __device__ __forceinline__ void fft16(float2 (&v)[16])
{
    float2 t[4][4];
#pragma unroll
    for (int q = 0; q < 4; ++q) {
        float2 a = v[q], b = v[4+q], c = v[8+q], d = v[12+q];
        f4<S>(a,b,c,d);
        t[q][0]=a; t[q][1]=b; t[q][2]=c; t[q][3]=d;
    }
#pragma unroll
    for (int q = 1; q < 4; ++q)
#pragma unroll
        for (int r = 1; r < 4; ++r)
            t[q][r] = cmul(t[q][r], tw16<S>(q*r));
#pragma unroll
    for (int r = 0; r < 4; ++r) {
        float2 a=t[0][r], b=t[1][r], c=t[2][r], d=t[3][r];
        f4<S>(a,b,c,d);
        v[r]=a; v[r+4]=b; v[r+8]=c; v[r+12]=d;
    }
}

// fft15: natural-order in/out 15-point DFT (3x5), all registers.
template<int S> __device__ __forceinline__ void fft15(float2 (&v)[15])
{
    float2 t[5][3]; // t[d][e]
#pragma unroll
    for (int d = 0; d < 5; ++d) {
        float2 u[3] = { v[d], v[5+d], v[10+d] };
        dftR<S,3>(u);
        t[d][0]=u[0];
        t[d][1]=cmul(u[1], tw15<S>(d));
        t[d][2]=cmul(u[2], tw15<S>(2*d));
    }
#pragma unroll
    for (int e = 0; e < 3; ++e) {
        float2 u[5] = { t[0][e],t[1][e],t[2][e],t[3][e],t[4][e] };
        dftR<S,5>(u);
#pragma unroll
        for (int g = 0; g < 5; ++g) v[e + 3*g] = u[g];
    }
}

// fft25: natural-order in/out 25-point DFT (5x5), all registers.
template<int S> __device__ __forceinline__ void fft25(float2 (&v)[25])
{
    float2 t[5][5]; // t[d][e]
#pragma unroll
    for (int d = 0; d < 5; ++d) {
        float2 u[5] = { v[d], v[5+d], v[10+d], v[15+d], v[20+d] };
        dftR<S,5>(u);
        t[d][0] = u[0];
#pragma unroll
        for (int e = 1; e < 5; ++e) t[d][e] = cmul(u[e], tw25<S>(d*e));
    }
#pragma unroll
    for (int e = 0; e < 5; ++e) {
        float2 u[5] = { t[0][e],t[1][e],t[2][e],t[3][e],t[4][e] };
        dftR<S,5>(u);
#pragma unroll
        for (int g = 0; g < 5; ++g) v[e + 5*g] = u[g];
    }
}

// 200-spectrum slot: f = f1 + 8*f2 stored at 25*f1 + f2
__device__ __forceinline__ int slotn(int f) { return 25 * (f & 7) + (f >> 3); }

// Hermitian pair combine (verified)
__device__ __forceinline__ void pair_combine(float2 Za, float2 Zb, float g1, float g2,
                                             float2& C, float2& Cp, float& e1, float& e2)
{
    float2 X1 = make_float2(0.5f * (Za.x + Zb.x), 0.5f * (Za.y - Zb.y));
    float2 w  = make_float2(0.5f * (Za.x - Zb.x), 0.5f * (Za.y + Zb.y));
    float2 X2 = make_float2(w.y, -w.x);
    float2 Z1 = make_float2(g1 * X1.x, g1 * X1.y);
    float2 Z2 = make_float2(g2 * X2.x, g2 * X2.y);
    e1 = Z1.x * Z1.x + Z1.y * Z1.y;
    e2 = Z2.x * Z2.x + Z2.y * Z2.y;
    C  = make_float2(Z1.x - Z2.y,  Z1.y + Z2.x);
    Cp = make_float2(Z1.x + Z2.y, -Z1.y + Z2.x);
}

// ================= MFMA conv (unchanged, verified) =================
template<int NT, int TAPS, int CHUNKS, int CINP, int COUTP>
__global__ __launch_bounds__(256) void conv_mfma_kernel(
    const unsigned short* __restrict__ xT, int tRowsIn,
    const unsigned short* __restrict__ wT,
    const float* __restrict__ bias,
    unsigned short* __restrict__ outT, int tRowsOut, int tOffOut)
{
    const int b = blockIdx.y;
    const int t0 = blockIdx.x * 16;
    const int tid = threadIdx.x;
    const int wave = tid >> 6;
    const int lane = tid & 63;
    const int m = lane & 15;
    const int quad = lane >> 4;
    const int n0 = wave * (NT * 16);

    f32x4 acc[NT];
#pragma unroll
    for (int nt = 0; nt < NT; ++nt) acc[nt] = (f32x4){0.f, 0.f, 0.f, 0.f};

    const unsigned short* xb = xT + (size_t)b * tRowsIn * CINP;
#pragma unroll
    for (int kw = 0; kw < TAPS; ++kw) {
        const unsigned short* wk = wT + (size_t)kw * COUTP * CINP;
        const unsigned short* xrow = xb + (size_t)(t0 + kw + m) * CINP + quad * 8;
#pragma unroll
        for (int ch = 0; ch < CHUNKS; ++ch) {
            const int k0 = ch * 32;
            bf16x8 a = *(const bf16x8*)(xrow + k0);
#pragma unroll
            for (int nt = 0; nt < NT; ++nt) {
                bf16x8 bfr = *(const bf16x8*)(wk + (size_t)(n0 + nt * 16 + m) * CINP + k0 + quad * 8);
                acc[nt] = __builtin_amdgcn_mfma_f32_16x16x32_bf16(a, bfr, acc[nt], 0, 0, 0);
            }
        }
    }
#pragma unroll
    for (int nt = 0; nt < NT; ++nt) {
        const int n = n0 + nt * 16 + m;
        const float bz = bias[n];
#pragma unroll
        for (int r = 0; r < 4; ++r) {
            const int t = t0 + quad * 4 + r;
            if (t < 200) {
                float v = acc[nt][r] + bz;
                v = (v >= 0.f) ? v : 0.1f * v;
                outT[((size_t)b * tRowsOut + t + tOffOut) * COUTP + n] = f2bf(v);
            }
        }
    }
}

__global__ void prep_x1_kernel(const float* __restrict__ cond, const float* __restrict__ f0,
                               unsigned short* __restrict__ xpT1)
{
    int idx = blockIdx.x * 256 + threadIdx.x;
    const int total = BB * 212 * 160;
    if (idx >= total) return;
    int i = idx % 160;
    int rest = idx / 160;
    int tp = rest % 212;
    int b = rest / 212;
    int tt = tp - 2;
    float v = 0.f;
    if (tt >= 0 && tt < 200) {
        if (i < 128) v = cond[((size_t)b * 128 + i) * 200 + tt];
        else if (i == 128) v = (f0[b * 200 + tt] > 0.f) ? 1.f : 0.f;
    }
    xpT1[idx] = f2bf(v);
}

template<int TAPS, int CINR, int CINP, int COUTP>
__global__ void prep_w_kernel(const float* __restrict__ w, unsigned short* __restrict__ wT)
{
    int idx = blockIdx.x * 256 + threadIdx.x;
    const int total = TAPS * COUTP * CINP;
    if (idx >= total) return;
    int i = idx % CINP;
    int rest = idx / CINP;
    int o = rest % COUTP;
    int kw = rest / COUTP;
    float v = (i < CINR) ? w[((size_t)o * CINR + i) * TAPS + kw] : 0.f;
    wT[idx] = f2bf(v);
}

__global__ void zero16_kernel(uint4* __restrict__ p, int n16)
{
    int idx = blockIdx.x * 256 + threadIdx.x;
    if (idx < n16) p[idx] = make_uint4(0, 0, 0, 0);
}

// ================= FFT passes =================
// 240 = 16 x 15: n1 = 15a+b; f = f1 + 16*f2. LDS slot layout: col[f1*15 + b].
// 200 = 8 x 25 : e  = 25a+b; f = f1 +  8*f2. LDS slot layout: row[f1*25 + f2].

// pass A: 8 columns/block, 128 threads, ONE barrier. (verified round 4/8)
__global__ __launch_bounds__(128) void passA_kernel(const float* __restrict__ wn,
                                                    float2* __restrict__ I)
{
    __shared__ float2 L[8 * 241];
    int q = blockIdx.y;
    const float* w1p = wn + (size_t)(2 * q) * NA;
    const float* w2p = wn + (size_t)(2 * q + 1) * NA;
    int n20 = blockIdx.x * 8;
    int tid = threadIdx.x;

    if (tid < 120) {
        int b = tid >> 3, j = tid & 7;
        int n2 = n20 + j;
        float2 v[16];
#pragma unroll
        for (int a = 0; a < 16; ++a) {
            int n = (15 * a + b) * 200 + n2;
            v[a] = make_float2(w1p[n], w2p[n]);
        }
        fft16<-1>(v);
#pragma unroll
        for (int f1 = 1; f1 < 16; ++f1)
            v[f1] = cmul(v[f1], cis_rev(-(float)(b * f1) * (1.f / 240.f)));
        float2* col = L + j * 241;
#pragma unroll
        for (int f1 = 0; f1 < 16; ++f1) col[f1 * 15 + b] = v[f1];
    }
    __syncthreads();
    {
        int f1 = tid >> 3, j = tid & 7;
        int n2 = n20 + j;
        float2* col = L + j * 241;
        float2 u[15];
#pragma unroll
        for (int b = 0; b < 15; ++b) u[b] = col[f1 * 15 + b];
        fft15<-1>(u);
#pragma unroll
        for (int f2 = 0; f2 < 15; ++f2) {
            int f = f1 + 16 * f2;
            I[(size_t)q * NA + (size_t)f * 200 + n2] =
                cmul(u[f2], cis_rev(-(float)(n2 * f) * (1.f / (float)NA)));
        }
    }
}

// pass B: 4 conjugate row-pairs per block, 64 threads (single wave), grid 30x32.
// (verified round 8)
template<int MODE>
__global__ __launch_bounds__(64) void passB_kernel(float2* __restrict__ I,
    const float* __restrict__ avg_shape, const float* __restrict__ fbins,
    const float* __restrict__ loc_w, float* __restrict__ acc, float* __restrict__ z0)
{
    __shared__ float2 L[8 * 202];
    __shared__ float g1sh[32], g2sh[32];
    int q = blockIdx.y;
    int b1 = 2 * q, b2 = 2 * q + 1;
    int bx = blockIdx.x;
    int tid = threadIdx.x;
    if (MODE == 0) {
        if (tid < 32) { g1sh[tid] = avg_shape[b1 * 32 + tid]; g2sh[tid] = avg_shape[b2 * 32 + tid]; }
    } else {
        if (tid < 5) { g1sh[tid] = loc_w[b1 * 5 + tid]; g2sh[tid] = loc_w[b2 * 5 + tid]; }
    }
    int Rrow[8];
#pragma unroll
    for (int s = 0; s < 8; ++s) {
        int p = s >> 1;
        int pi = 4 * bx + p;
        Rrow[s] = (pi == 0) ? ((s & 1) ? 120 : 0) : ((s & 1) ? 240 - pi : pi);
    }
    // F1
    for (int idx = tid; idx < 200; idx += 64) {
        int s = idx / 25, b = idx - 25 * s;
        const float2* g = I + (size_t)q * NA + (size_t)Rrow[s] * 200;
        float2 v[8];
#pragma unroll
        for (int a = 0; a < 8; ++a) v[a] = g[25 * a + b];
        dftR<-1, 8>(v);
#pragma unroll
        for (int f1 = 1; f1 < 8; ++f1)
            v[f1] = cmul(v[f1], cis_rev(-(float)(b * f1) * (1.f / 200.f)));
        float2* row = L + s * 202;
#pragma unroll
        for (int f1 = 0; f1 < 8; ++f1) row[f1 * 25 + b] = v[f1];
    }
    __syncthreads();
    // F2
    {
        int s = tid >> 3, f1 = tid & 7;
        float2* row = L + s * 202;
        float2 u[25];
#pragma unroll
        for (int b = 0; b < 25; ++b) u[b] = row[f1 * 25 + b];
        fft25<-1>(u);
#pragma unroll
        for (int f2 = 0; f2 < 25; ++f2) row[f1 * 25 + f2] = u[f2];
    }
    __syncthreads();
    // combine
    float part1 = 0.f, part2 = 0.f;
    for (int idx = tid; idx < 804; idx += 64) {
        int p = idx / 201, t = idx - p * 201;
        int pi = 4 * bx + p;
        float2* rwA = L + (2 * p) * 202;
        float2* rwB = L + (2 * p + 1) * 202;
        int k = -1;
        float2 Za, Zb;
        int sa = 0, sb = 0;
        float2* wa = rwA; float2* wb = rwB;
        bool self1 = false;
        if (pi != 0) {
            if (t >= 200) continue;
            sa = slotn(t); sb = slotn(199 - t);
            Za = rwA[sa]; Zb = rwB[sb];
            k = pi + 240 * t;
        } else if (t < 101) {
            wa = rwA; wb = rwA;
            if (t == 0 || t == 100) {
                sa = slotn(t); sb = sa;
                Za = rwA[sa]; Zb = Za;
                k = 240 * t;
                self1 = true;
            } else {
                sa = slotn(t); sb = slotn(200 - t);
                Za = rwA[sa]; Zb = rwA[sb];
                k = 240 * t;
            }
        } else {
            int t2 = t - 101;
            if (t2 >= 100) continue;
            wa = rwB; wb = rwB;
            sa = slotn(t2); sb = slotn(199 - t2);
            Za = rwB[sa]; Zb = rwB[sb];
            k = 120 + 240 * t2;
        }
        int kbin = min(k, NA - k);
        float g1, g2;
        if (MODE == 0) {
            int jj = (kbin * 32) / NBINS;
            if (jj < 31 && (NBINS * (jj + 1)) / 32 <= kbin) ++jj;
            g1 = g1sh[jj]; g2 = g2sh[jj];
        } else {
            g1 = 0.f; g2 = 0.f;
#pragma unroll
            for (int c = 0; c < 5; ++c) {
                float fb = fbins[c * NBINS + kbin];
                g1 += g1sh[c] * fb; g2 += g2sh[c] * fb;
            }
        }
        float2 C, Cp; float e1, e2;
        pair_combine(Za, Zb, g1, g2, C, Cp, e1, e2);
        if (MODE == 0) {
            float wgt = self1 ? 1.f : 2.f;
            part1 += wgt * e1; part2 += wgt * e2;
            if (k == 0) { z0[b1] = g1 * Za.x; z0[b2] = g2 * Za.y; }
        }
        wa[sa] = make_float2(C.x * (1.f / NA), C.y * (1.f / NA));
        if (!self1) wb[sb] = make_float2(Cp.x * (1.f / NA), Cp.y * (1.f / NA));
    }
    if (MODE == 0) {
        for (int o = 32; o > 0; o >>= 1) {
            part1 += __shfl_down(part1, o);
            part2 += __shfl_down(part2, o);
        }
        if (tid == 0) { atomicAdd(&acc[b1], part1); atomicAdd(&acc[b2], part2); }
    }
    __syncthreads();
    // I1
    {
        int s = tid >> 3, f1 = tid & 7;
        float2* row = L + s * 202;
        float2 u[25];
#pragma unroll
        for (int f2 = 0; f2 < 25; ++f2) u[f2] = row[f1 * 25 + f2];
        fft25<+1>(u);
#pragma unroll
        for (int b = 0; b < 25; ++b) row[f1 * 25 + b] = u[b];
    }
    __syncthreads();
    // I2
    for (int idx = tid; idx < 200; idx += 64) {
        int s = idx / 25, b = idx - 25 * s;
        float2* row = L + s * 202;
        float2 w[8];
#pragma unroll
        for (int f1 = 0; f1 < 8; ++f1) w[f1] = row[f1 * 25 + b];
#pragma unroll
        for (int f1 = 1; f1 < 8; ++f1)
            w[f1] = cmul(w[f1], cis_rev((float)(b * f1) * (1.f / 200.f)));
        dftR<+1, 8>(w);
        int rg = Rrow[s];
        float2* g = I + (size_t)q * NA + (size_t)rg * 200;
#pragma unroll
        for (int a = 0; a < 8; ++a) {
            int e = 25 * a + b;
            g[e] = cmul(w[a], cis_rev((float)(e * rg) * (1.f / (float)NA)));
        }
    }
}

// pass C: inv240 -> modulate -> fwd240; 8 columns/block, 128 threads, TWO barriers.
__global__ __launch_bounds__(128) void passC_kernel(float2* __restrict__ I,
    const float* __restrict__ control, const float* __restrict__ f0,
    const float* __restrict__ scale)
{
    __shared__ float2 L[8 * 241];
    __shared__ float ctlA[600], ctlB[600];
    __shared__ float f0A[200], f0B[200];
    int q = blockIdx.y;
    int b1 = 2 * q, b2 = 2 * q + 1;
    int n20 = blockIdx.x * 8;
    int tid = threadIdx.x;
    for (int i = tid; i < 600; i += 128) {
        ctlA[i] = control[(size_t)b1 * 1600 + i];
        ctlB[i] = control[(size_t)b2 * 1600 + i];
    }
    for (int i = tid; i < 200; i += 128) {
        f0A[i] = f0[b1 * 200 + i];
        f0B[i] = f0[b2 * 200 + i];
    }
    {
        int f1 = tid >> 3, j = tid & 7;
        int n2 = n20 + j;
        float2 u[15];
#pragma unroll
        for (int f2 = 0; f2 < 15; ++f2)
            u[f2] = I[(size_t)q * NA + (size_t)(f1 + 16 * f2) * 200 + n2];
        fft15<+1>(u);
        float2* col = L + j * 241;
#pragma unroll
        for (int b = 0; b < 15; ++b) col[f1 * 15 + b] = u[b];
    }
    __syncthreads();
    if (tid < 120) {
        int b = tid >> 3, j = tid & 7;
        int n2 = n20 + j;
        float2* col = L + j * 241;
        float sc1 = scale[b1], sc2 = scale[b2];
        float2 w[16];
#pragma unroll
        for (int f1 = 0; f1 < 16; ++f1) w[f1] = col[f1 * 15 + b];
#pragma unroll
        for (int f1 = 1; f1 < 16; ++f1)
            w[f1] = cmul(w[f1], cis_rev((float)(b * f1) * (1.f / 240.f)));
        fft16<+1>(w);
#pragma unroll
        for (int a = 0; a < 16; ++a) {
            int n = 200 * (15 * a + b) + n2;
            float sf = ((float)n + 0.5f) * (1.f / 240.f) - 0.5f;
            sf = fminf(fmaxf(sf, 0.f), 199.f);
            int i0 = (int)sf;
            int i1 = min(i0 + 1, 199);
            float wt = sf - (float)i0, w0 = 1.f - wt;
            float inh = ctlA[i0] * w0 + ctlA[i1] * wt;
            float exh = ctlA[200 + i0] * w0 + ctlA[200 + i1] * wt;
            float pr  = ctlA[400 + i0] * w0 + ctlA[400 + i1] * wt;
            float vv  = (f0A[i0] > 0.f ? 1.f : 0.f) * w0 + (f0A[i1] > 0.f ? 1.f : 0.f) * wt;
            float m1 = inh * (1.f - vv) + exh * pr;
            inh = ctlB[i0] * w0 + ctlB[i1] * wt;
            exh = ctlB[200 + i0] * w0 + ctlB[200 + i1] * wt;
            pr  = ctlB[400 + i0] * w0 + ctlB[400 + i1] * wt;
            vv  = (f0B[i0] > 0.f ? 1.f : 0.f) * w0 + (f0B[i1] > 0.f ? 1.f : 0.f) * wt;
            float m2 = inh * (1.f - vv) + exh * pr;
            w[a] = make_float2(w[a].x * sc1 * m1, w[a].y * sc2 * m2);
        }
        fft16<-1>(w);
#pragma unroll
        for (int f1 = 1; f1 < 16; ++f1)
            w[f1] = cmul(w[f1], cis_rev(-(float)(b * f1) * (1.f / 240.f)));
#pragma unroll
        for (int f1 = 0; f1 < 16; ++f1) col[f1 * 15 + b] = w[f1];
    }
    __syncthreads();
    {
        int f1 = tid >> 3, j = tid & 7;
        int n2 = n20 + j;
        float2* col = L + j * 241;
        float2 u[15];
#pragma unroll
        for (int b = 0; b < 15; ++b) u[b] = col[f1 * 15 + b];
        fft15<-1>(u);
#pragma unroll
        for (int f2 = 0; f2 < 15; ++f2) {
            int f = f1 + 16 * f2;
            I[(size_t)q * NA + (size_t)f * 200 + n2] =
                cmul(u[f2], cis_rev(-(float)(n2 * f) * (1.f / (float)NA)));
        }
    }
}

// pass D: inv240 -> two real outputs; 8 columns/block, 128 threads, ONE barrier.
__global__ __launch_bounds__(128) void passD_kernel(const float2* __restrict__ I,
                                                    float* __restrict__ out)
{
    __shared__ float2 L[8 * 241];
    int q = blockIdx.y;
    int b1 = 2 * q, b2 = 2 * q + 1;
    int n20 = blockIdx.x * 8;
    int tid = threadIdx.x;
    {
        int f1 = tid >> 3, j = tid & 7;
        int n2 = n20 + j;
        float2 u[15];
#pragma unroll
        for (int f2 = 0; f2 < 15; ++f2)
            u[f2] = I[(size_t)q * NA + (size_t)(f1 + 16 * f2) * 200 + n2];
        fft15<+1>(u);
        float2* col = L + j * 241;
#pragma unroll
        for (int b = 0; b < 15; ++b) col[f1 * 15 + b] = u[b];
    }
    __syncthreads();
    if (tid < 120) {
        int b = tid >> 3, j = tid & 7;
        int n2 = n20 + j;
        float2* col = L + j * 241;
        float2 w[16];
#pragma unroll
        for (int f1 = 0; f1 < 16; ++f1) w[f1] = col[f1 * 15 + b];
#pragma unroll
        for (int f1 = 1; f1 < 16; ++f1)
            w[f1] = cmul(w[f1], cis_rev((float)(b * f1) * (1.f / 240.f)));
        fft16<+1>(w);
#pragma unroll
        for (int a = 0; a < 16; ++a) {
            int n = 200 * (15 * a + b) + n2;
            out[(size_t)b1 * NA + n] = w[a].x;
            out[(size_t)b2 * NA + n] = w[a].y;
        }
    }
}

__global__ void init_kernel(float* __restrict__ acc, float* __restrict__ z0)
{
    int i = threadIdx.x;
    if (i < 64) { acc[i] = 0.f; z0[i] = 0.f; }
}

__global__ void finalize_scale(const float* __restrict__ acc, const float* __restrict__ z0,
                               float* __restrict__ scale)
{
    int b = threadIdx.x;
    if (b < 64) {
        float var = (acc[b] - z0[b] * z0[b]) / (48000.f * 47999.f);
        scale[b] = 0.1f / sqrtf(var);
    }
}

// ---------------- head ----------------
__global__ void head_kernel(const unsigned short* __restrict__ h3T, const float* __restrict__ w4,
                            const float* __restrict__ b4, float* __restrict__ control,
                            float* __restrict__ avg_shape, float* __restrict__ out_bf)
{
    __shared__ float w4s[40 * 64];
    __shared__ float b4s[40];
    __shared__ float sp[200 * 33];
    int b = blockIdx.x;
    for (int j = threadIdx.x; j < 40 * 64; j += 256) w4s[j] = w4[j];
    if (threadIdx.x < 40) b4s[threadIdx.x] = b4[threadIdx.x];
    __syncthreads();
    int t = threadIdx.x;
    if (t < 200) {
        float p[40];
#pragma unroll
        for (int o = 0; o < 40; ++o) p[o] = b4s[o];
        const unsigned short* hb = h3T + ((size_t)b * 200 + t) * 64;
        for (int i = 0; i < 64; ++i) {
            float h = bf2f(hb[i]);
#pragma unroll
            for (int o = 0; o < 40; ++o) p[o] += h * w4s[o * 64 + i];
        }
        float inh = 1.f / (1.f + expf(-p[0]));
        float exh = 1.f / (1.f + expf(-p[1]));
        float pr  = 1.f / (1.f + expf(-p[2]));
        float mx = p[3];
#pragma unroll
        for (int c = 1; c < 32; ++c) mx = fmaxf(mx, p[3 + c]);
        float e[32];
        float sum = 0.f;
#pragma unroll
        for (int c = 0; c < 32; ++c) { e[c] = expf(p[3 + c] - mx); sum += e[c]; }
        float inv = 1.f / sum;
#pragma unroll
        for (int c = 0; c < 32; ++c) sp[t * 33 + c] = e[c] * inv;
        float mx2 = p[35];
#pragma unroll
        for (int c = 1; c < 5; ++c) mx2 = fmaxf(mx2, p[35 + c]);
        float e2[5];
        float s2 = 0.f;
#pragma unroll
        for (int c = 0; c < 5; ++c) { e2[c] = expf(p[35 + c] - mx2); s2 += e2[c]; }
        float inv2 = 1.f / s2;
        float* ctl = control + (size_t)b * 8 * 200;
        ctl[0 * 200 + t] = inh;
        ctl[1 * 200 + t] = exh;
        ctl[2 * 200 + t] = pr;
#pragma unroll
        for (int c = 0; c < 5; ++c) ctl[(3 + c) * 200 + t] = e2[c] * inv2;
        float* bf = out_bf + (size_t)b * 3 * 200;
        bf[0 * 200 + t] = pr;
        bf[1 * 200 + t] = inh;
        bf[2 * 200 + t] = exh;
    }
    __syncthreads();
    if (t < 32) {
        float s = 0.f;
        for (int j = 0; j < 200; ++j) s += sp[j * 33 + t];
        avg_shape[b * 32 + t] = s * (1.f / 200.f);
    }
}

// loc_w[b,c] = mean_t turb[b,c,t]
__global__ void locw_mean_kernel(const float* __restrict__ control, float* __restrict__ loc_w)
{
    int c = blockIdx.x, b = blockIdx.y;
    int tid = threadIdx.x;
    const float* src = control + ((size_t)b * 8 + 3 + c) * 200;
    float s = (tid < 200) ? src[tid] : 0.f;
    for (int o = 32; o > 0; o >>= 1) s += __shfl_down(s, o);
    __shared__ float red[4];
    if ((tid & 63) == 0) red[tid >> 6] = s;
    __syncthreads();
    if (tid == 0) loc_w[b * 5 + c] = (red[0] + red[1] + red[2] + red[3]) * (1.f / 200.f);
}

__device__ inline float filter_shape_val(int c, int i)
{
    float lin = (float)i * (1.f / 31.f);
    if (c == 0) { float z = (lin - 0.2f) * 10.f;          return expf(-0.5f * z * z); }
    if (c == 1) { float z = (lin - 0.1f) * 10.f;          return expf(-0.5f * z * z); }
    if (c == 2) { float z = (lin - 0.4f) * (1.f / 0.15f); return expf(-0.5f * z * z); }
    if (c == 3) { float z = (lin - 0.6f) * 10.f;          return expf(-0.5f * z * z); }
    float v = 0.1f + 0.9f * lin;
    return v * v;
}

__global__ void fbins_kernel(float* __restrict__ fbins)
{
    int k = blockIdx.x * 256 + threadIdx.x;
    if (k >= NBINS) return;
    float sf = (k + 0.5f) * (32.0f / 24001.0f) - 0.5f;
    sf = fminf(fmaxf(sf, 0.f), 31.f);
    int i0 = (int)sf;
    int i1 = min(i0 + 1, 31);
    float w = sf - (float)i0;
#pragma unroll
    for (int c = 0; c < 5; ++c)
        fbins[c * NBINS + k] = filter_shape_val(c, i0) * (1.f - w) + filter_shape_val(c, i1) * w;
}

extern "C" void kernel_launch(void* const* d_in, const int* in_sizes, int n_in,
                              void* d_out, int out_size, void* d_ws, size_t ws_size,
                              hipStream_t stream)
{
    const float* cond = (const float*)d_in[0];
    const float* f0   = (const float*)d_in[1];
    const float* wn   = (const float*)d_in[2];
    const float* w1   = (const float*)d_in[3];
    const float* b1   = (const float*)d_in[4];
    const float* w2   = (const float*)d_in[5];
    const float* b2   = (const float*)d_in[6];
    const float* w3   = (const float*)d_in[7];
    const float* b3   = (const float*)d_in[8];
    const float* w4   = (const float*)d_in[9];
    const float* b4   = (const float*)d_in[10];

    float* out = (float*)d_out;
    float* filtered = out;
    float* bf_out   = out + (size_t)BB * NA;

    char* ws = (char*)d_ws;
    size_t off = 0;
    float2* I = (float2*)(ws + off);            off += 24576000;
    unsigned short* xpT1 = (unsigned short*)(ws + off); off += (size_t)BB * 212 * 160 * 2;
    unsigned short* xpT2 = (unsigned short*)(ws + off); off += (size_t)BB * 210 * 256 * 2;
    unsigned short* xpT3 = (unsigned short*)(ws + off); off += (size_t)BB * 210 * 128 * 2;
    unsigned short* xpT4 = (unsigned short*)(ws + off); off += (size_t)BB * 200 * 64 * 2;
    unsigned short* wT1  = (unsigned short*)(ws + off); off += (size_t)5 * 256 * 160 * 2;
    unsigned short* wT2  = (unsigned short*)(ws + off); off += (size_t)3 * 128 * 256 * 2;
    unsigned short* wT3  = (unsigned short*)(ws + off); off += (size_t)3 * 64 * 128 * 2;
    float* control   = (float*)(ws + off);
    float* avg_shape = control + 102400;
    float* loc_w     = avg_shape + 2048;
    float* acc       = loc_w + 320;
    float* z0        = acc + 64;
    float* scale     = z0 + 64;
    float* fbins     = scale + 64;

    dim3 blk(256);

    init_kernel<<<1, 64, 0, stream>>>(acc, z0);

    // prep
    {
        int n1 = BB * 212 * 160;
        prep_x1_kernel<<<dim3((n1 + 255) / 256), blk, 0, stream>>>(cond, f0, xpT1);
        int z2 = (BB * 210 * 256 * 2) / 16;
        zero16_kernel<<<dim3((z2 + 255) / 256), blk, 0, stream>>>((uint4*)xpT2, z2);
        int z3 = (BB * 210 * 128 * 2) / 16;
        zero16_kernel<<<dim3((z3 + 255) / 256), blk, 0, stream>>>((uint4*)xpT3, z3);
        prep_w_kernel<5, 129, 160, 256><<<dim3((5 * 256 * 160 + 255) / 256), blk, 0, stream>>>(w1, wT1);
        prep_w_kernel<3, 256, 256, 128><<<dim3((3 * 128 * 256 + 255) / 256), blk, 0, stream>>>(w2, wT2);
        prep_w_kernel<3, 128, 128, 64><<<dim3((3 * 64 * 128 + 255) / 256), blk, 0, stream>>>(w3, wT3);
    }

    // MFMA conv stack
    conv_mfma_kernel<4, 5, 5, 160, 256><<<dim3(13, BB), blk, 0, stream>>>(
        xpT1, 212, wT1, b1, xpT2, 210, 1);
    conv_mfma_kernel<2, 3, 8, 256, 128><<<dim3(13, BB), blk, 0, stream>>>(
        xpT2, 210, wT2, b2, xpT3, 210, 1);
    conv_mfma_kernel<1, 3, 4, 128, 64><<<dim3(13, BB), blk, 0, stream>>>(
        xpT3, 210, wT3, b3, xpT4, 200, 0);

    head_kernel<<<dim3(BB), blk, 0, stream>>>(xpT4, w4, b4, control, avg_shape, bf_out);
    locw_mean_kernel<<<dim3(5, BB), blk, 0, stream>>>(control, loc_w);
    fbins_kernel<<<dim3((NBINS + 255) / 256), blk, 0, stream>>>(fbins);

    // batch-paired four-step FFT pipeline (32 complex signals carry 64 real batches)
    passA_kernel<<<dim3(25, 32), dim3(128), 0, stream>>>(wn, I);
    passB_kernel<0><<<dim3(30, 32), dim3(64), 0, stream>>>(I, avg_shape, fbins, loc_w, acc, z0);
    finalize_scale<<<1, 64, 0, stream>>>(acc, z0, scale);
    passC_kernel<<<dim3(25, 32), dim3(128), 0, stream>>>(I, control, f0, scale);
    passB_kernel<1><<<dim3(30, 32), dim3(64), 0, stream>>>(I, avg_shape, fbins, loc_w, acc, z0);
    passD_kernel<<<dim3(25, 32), dim3(128), 0, stream>>>(I, filtered);
}

// Round 11
// 319.557 us; speedup vs baseline: 1.1471x; 1.0662x over previous
//
#include <hip/hip_runtime.h>
#include <math.h>

#define BB 64
#define T_FR 200
#define NA 48000
#define NBINS 24001

typedef __attribute__((ext_vector_type(4))) float f32x4;
typedef __attribute__((ext_vector_type(8))) short bf16x8;

__device__ __forceinline__ unsigned short f2bf(float x)
{
    unsigned u = __float_as_uint(x);
    u = (u + 0x7FFFu + ((u >> 16) & 1u)) >> 16;
    return (unsigned short)u;
}
__device__ __forceinline__ float bf2f(unsigned short h)
{
    return __uint_as_float(((unsigned)h) << 16);
}

__device__ __forceinline__ float2 cmul(float2 a, float2 b)
{
    return make_float2(a.x * b.x - a.y * b.y, a.x * b.y + a.y * b.x);
}
__device__ __forceinline__ float2 cadd(float2 a, float2 b){ return make_float2(a.x+b.x, a.y+b.y); }
__device__ __forceinline__ float2 csub(float2 a, float2 b){ return make_float2(a.x-b.x, a.y-b.y); }

__device__ __forceinline__ float2 cis_rev(float rev)
{
    return make_float2(__builtin_amdgcn_cosf(rev), __builtin_amdgcn_sinf(rev));
}

// ---------------- root tables ----------------
template<int R> __device__ __forceinline__ void fill_roots(float (&cr)[R], float (&si)[R]);
template<> __device__ __forceinline__ void fill_roots<3>(float (&cr)[3], float (&si)[3])
{
    const float S = 0.86602540378443865f;
    cr[0]=1.f; cr[1]=-0.5f; cr[2]=-0.5f;
    si[0]=0.f; si[1]=S;     si[2]=-S;
}
template<> __device__ __forceinline__ void fill_roots<5>(float (&cr)[5], float (&si)[5])
{
    cr[0]=1.f; cr[1]=0.30901699437494742f; cr[2]=-0.80901699437494742f;
    cr[3]=-0.80901699437494742f; cr[4]=0.30901699437494742f;
    si[0]=0.f; si[1]=0.95105651629515357f; si[2]=0.58778525229247313f;
    si[3]=-0.58778525229247313f; si[4]=-0.95105651629515357f;
}
template<> __device__ __forceinline__ void fill_roots<8>(float (&cr)[8], float (&si)[8])
{
    const float C = 0.70710678118654752f;
    cr[0]=1.f; cr[1]=C;  cr[2]=0.f;  cr[3]=-C; cr[4]=-1.f; cr[5]=-C;  cr[6]=0.f;  cr[7]=C;
    si[0]=0.f; si[1]=C;  si[2]=1.f;  si[3]=C;  si[4]=0.f;  si[5]=-C;  si[6]=-1.f; si[7]=-C;
}

// dftR<S,R>: X[k] = sum_j v[j] * e^{S*2pi*i*j*k/R}
template<int S, int R>
__device__ __forceinline__ void dftR(float2 (&v)[R])
{
    float cr[R], si[R];
    fill_roots<R>(cr, si);
    float2 o[R];
#pragma unroll
    for (int k = 0; k < R; ++k) {
        float re = 0.f, im = 0.f;
#pragma unroll
        for (int j = 0; j < R; ++j) {
            int m = (j * k) % R;
            float ur = cr[m], ui = (S > 0) ? si[m] : -si[m];
            re += v[j].x * ur - v[j].y * ui;
            im += v[j].x * ui + v[j].y * ur;
        }
        o[k] = make_float2(re, im);
    }
#pragma unroll
    for (int k = 0; k < R; ++k) v[k] = o[k];
}

__device__ __constant__ float C25R[17] = {1.f,0.968583161f,0.876306680f,0.728968627f,0.535826795f,0.309016994f,0.062790520f,-0.187381315f,-0.425779292f,-0.637423990f,-0.809016994f,-0.929776486f,-0.992114701f,-0.992114701f,-0.929776486f,-0.809016994f,-0.637423990f};
__device__ __constant__ float C25I[17] = {0.f,0.248689887f,0.481753674f,0.684547106f,0.844327926f,0.951056516f,0.998026728f,0.982287251f,0.904827052f,0.770513243f,0.587785252f,0.368124553f,0.125333234f,-0.125333234f,-0.368124553f,-0.587785252f,-0.770513243f};
__device__ __constant__ float C15R[9] = {1.f,0.913545458f,0.669130606f,0.309016994f,-0.104528463f,-0.5f,-0.809016994f,-0.978147601f,-0.978147601f};
__device__ __constant__ float C15I[9] = {0.f,0.406736643f,0.743144825f,0.951056516f,0.994521895f,0.866025404f,0.587785252f,0.207911691f,-0.207911691f};
__device__ __constant__ float C16R[10] = {1.f,0.923879533f,0.707106781f,0.382683432f,0.f,-0.382683432f,-0.707106781f,-0.923879533f,-1.f,-0.923879533f};
__device__ __constant__ float C16I[10] = {0.f,0.382683432f,0.707106781f,0.923879533f,1.f,0.923879533f,0.707106781f,0.382683432f,0.f,-0.382683432f};

// twXX<S>(m) = e^{S*2pi*i*m/XX}
template<int S> __device__ __forceinline__ float2 tw25(int m){ return make_float2(C25R[m], S>0? C25I[m] : -C25I[m]); }
template<int S> __device__ __forceinline__ float2 tw15(int m){ return make_float2(C15R[m], S>0? C15I[m] : -C15I[m]); }
template<int S> __device__ __forceinline__ float2 tw16(int m){ return make_float2(C16R[m], S>0? C16I[m] : -C16I[m]); }

// ---------------- register sub-FFTs ----------------
template<int S> __device__ __forceinline__ void f4(float2& x0, float2& x1, float2& x2, float2& x3)
{
    float2 e = cadd(x0,x2), f = csub(x0,x2), g = cadd(x1,x3), h = csub(x1,x3);
    float2 r = (S<0) ? make_float2(h.y, -h.x) : make_float2(-h.y, h.x);
    x0 = cadd(e,g); x2 = csub(e,g); x1 = cadd(f,r); x3 = csub(f,r);
}

// fft16: natural-order in/out 16-point DFT (4x4), all registers.
template<int S> __device__ __forceinline__ void fft16(float2 (&v)[16])
{
    float2 t[4][4];
#pragma unroll
    for (int q = 0; q < 4; ++q) {
        float2 a = v[q], b = v[4+q], c = v[8+q], d = v[12+q];
        f4<S>(a,b,c,d);
        t[q][0]=a; t[q][1]=b; t[q][2]=c; t[q][3]=d;
    }
#pragma unroll
    for (int q = 1; q < 4; ++q)
#pragma unroll
        for (int r = 1; r < 4; ++r)
            t[q][r] = cmul(t[q][r], tw16<S>(q*r));
#pragma unroll
    for (int r = 0; r < 4; ++r) {
        float2 a=t[0][r], b=t[1][r], c=t[2][r], d=t[3][r];
        f4<S>(a,b,c,d);
        v[r]=a; v[r+4]=b; v[r+8]=c; v[r+12]=d;
    }
}

// fft15: natural-order in/out 15-point DFT (3x5), all registers.
template<int S> __device__ __forceinline__ void fft15(float2 (&v)[15])
{
    float2 t[5][3]; // t[d][e]
#pragma unroll
    for (int d = 0; d < 5; ++d) {
        float2 u[3] = { v[d], v[5+d], v[10+d] };
        dftR<S,3>(u);
        t[d][0]=u[0];
        t[d][1]=cmul(u[1], tw15<S>(d));
        t[d][2]=cmul(u[2], tw15<S>(2*d));
    }
#pragma unroll
    for (int e = 0; e < 3; ++e) {
        float2 u[5] = { t[0][e],t[1][e],t[2][e],t[3][e],t[4][e] };
        dftR<S,5>(u);
#pragma unroll
        for (int g = 0; g < 5; ++g) v[e + 3*g] = u[g];
    }
}

// fft25: natural-order in/out 25-point DFT (5x5), all registers.
template<int S> __device__ __forceinline__ void fft25(float2 (&v)[25])
{
    float2 t[5][5]; // t[d][e]
#pragma unroll
    for (int d = 0; d < 5; ++d) {
        float2 u[5] = { v[d], v[5+d], v[10+d], v[15+d], v[20+d] };
        dftR<S,5>(u);
        t[d][0] = u[0];
#pragma unroll
        for (int e = 1; e < 5; ++e) t[d][e] = cmul(u[e], tw25<S>(d*e));
    }
#pragma unroll
    for (int e = 0; e < 5; ++e) {
        float2 u[5] = { t[0][e],t[1][e],t[2][e],t[3][e],t[4][e] };
        dftR<S,5>(u);
#pragma unroll
        for (int g = 0; g < 5; ++g) v[e + 5*g] = u[g];
    }
}

// 200-spectrum slot: f = f1 + 8*f2 stored at 25*f1 + f2
__device__ __forceinline__ int slotn(int f) { return 25 * (f & 7) + (f >> 3); }

// Hermitian pair combine (verified)
__device__ __forceinline__ void pair_combine(float2 Za, float2 Zb, float g1, float g2,
                                             float2& C, float2& Cp, float& e1, float& e2)
{
    float2 X1 = make_float2(0.5f * (Za.x + Zb.x), 0.5f * (Za.y - Zb.y));
    float2 w  = make_float2(0.5f * (Za.x - Zb.x), 0.5f * (Za.y + Zb.y));
    float2 X2 = make_float2(w.y, -w.x);
    float2 Z1 = make_float2(g1 * X1.x, g1 * X1.y);
    float2 Z2 = make_float2(g2 * X2.x, g2 * X2.y);
    e1 = Z1.x * Z1.x + Z1.y * Z1.y;
    e2 = Z2.x * Z2.x + Z2.y * Z2.y;
    C  = make_float2(Z1.x - Z2.y,  Z1.y + Z2.x);
    Cp = make_float2(Z1.x + Z2.y, -Z1.y + Z2.x);
}

// filter shapes (5 channels over 32 bands) — same math as reference _filter_shapes
__device__ __forceinline__ float filter_shape_val(int c, int i)
{
    float lin = (float)i * (1.f / 31.f);
    if (c == 0) { float z = (lin - 0.2f) * 10.f;          return expf(-0.5f * z * z); }
    if (c == 1) { float z = (lin - 0.1f) * 10.f;          return expf(-0.5f * z * z); }
    if (c == 2) { float z = (lin - 0.4f) * (1.f / 0.15f); return expf(-0.5f * z * z); }
    if (c == 3) { float z = (lin - 0.6f) * 10.f;          return expf(-0.5f * z * z); }
    float v = 0.1f + 0.9f * lin;
    return v * v;
}

// ================= MFMA conv (unchanged, verified) =================
template<int NT, int TAPS, int CHUNKS, int CINP, int COUTP>
__global__ __launch_bounds__(256) void conv_mfma_kernel(
    const unsigned short* __restrict__ xT, int tRowsIn,
    const unsigned short* __restrict__ wT,
    const float* __restrict__ bias,
    unsigned short* __restrict__ outT, int tRowsOut, int tOffOut)
{
    const int b = blockIdx.y;
    const int t0 = blockIdx.x * 16;
    const int tid = threadIdx.x;
    const int wave = tid >> 6;
    const int lane = tid & 63;
    const int m = lane & 15;
    const int quad = lane >> 4;
    const int n0 = wave * (NT * 16);

    f32x4 acc[NT];
#pragma unroll
    for (int nt = 0; nt < NT; ++nt) acc[nt] = (f32x4){0.f, 0.f, 0.f, 0.f};

    const unsigned short* xb = xT + (size_t)b * tRowsIn * CINP;
#pragma unroll
    for (int kw = 0; kw < TAPS; ++kw) {
        const unsigned short* wk = wT + (size_t)kw * COUTP * CINP;
        const unsigned short* xrow = xb + (size_t)(t0 + kw + m) * CINP + quad * 8;
#pragma unroll
        for (int ch = 0; ch < CHUNKS; ++ch) {
            const int k0 = ch * 32;
            bf16x8 a = *(const bf16x8*)(xrow + k0);
#pragma unroll
            for (int nt = 0; nt < NT; ++nt) {
                bf16x8 bfr = *(const bf16x8*)(wk + (size_t)(n0 + nt * 16 + m) * CINP + k0 + quad * 8);
                acc[nt] = __builtin_amdgcn_mfma_f32_16x16x32_bf16(a, bfr, acc[nt], 0, 0, 0);
            }
        }
    }
#pragma unroll
    for (int nt = 0; nt < NT; ++nt) {
        const int n = n0 + nt * 16 + m;
        const float bz = bias[n];
#pragma unroll
        for (int r = 0; r < 4; ++r) {
            const int t = t0 + quad * 4 + r;
            if (t < 200) {
                float v = acc[nt][r] + bz;
                v = (v >= 0.f) ? v : 0.1f * v;
                outT[((size_t)b * tRowsOut + t + tOffOut) * COUTP + n] = f2bf(v);
            }
        }
    }
}

__global__ void prep_x1_kernel(const float* __restrict__ cond, const float* __restrict__ f0,
                               unsigned short* __restrict__ xpT1)
{
    int idx = blockIdx.x * 256 + threadIdx.x;
    const int total = BB * 212 * 160;
    if (idx >= total) return;
    int i = idx % 160;
    int rest = idx / 160;
    int tp = rest % 212;
    int b = rest / 212;
    int tt = tp - 2;
    float v = 0.f;
    if (tt >= 0 && tt < 200) {
        if (i < 128) v = cond[((size_t)b * 128 + i) * 200 + tt];
        else if (i == 128) v = (f0[b * 200 + tt] > 0.f) ? 1.f : 0.f;
    }
    xpT1[idx] = f2bf(v);
}

// merged weight-prep for all three conv layers + acc/z0 zero-init (folded launches)
__global__ void prep_w_all_kernel(const float* __restrict__ w1, const float* __restrict__ w2,
                                  const float* __restrict__ w3,
                                  unsigned short* __restrict__ wT1, unsigned short* __restrict__ wT2,
                                  unsigned short* __restrict__ wT3,
                                  float* __restrict__ acc, float* __restrict__ z0)
{
    int idx = blockIdx.x * 256 + threadIdx.x;
    if (blockIdx.x == 0) {
        if (threadIdx.x < 64) acc[threadIdx.x] = 0.f;
        else if (threadIdx.x < 128) z0[threadIdx.x - 64] = 0.f;
    }
    const int N1 = 5 * 256 * 160;   // layer1: TAPS=5, CINR=129, CINP=160, COUTP=256
    const int N2 = 3 * 128 * 256;   // layer2: TAPS=3, CINR=256, CINP=256, COUTP=128
    const int N3 = 3 * 64 * 128;    // layer3: TAPS=3, CINR=128, CINP=128, COUTP=64
    if (idx < N1) {
        int i = idx % 160; int rest = idx / 160; int o = rest % 256; int kw = rest / 256;
        float v = (i < 129) ? w1[((size_t)o * 129 + i) * 5 + kw] : 0.f;
        wT1[idx] = f2bf(v);
    } else if (idx < N1 + N2) {
        int j = idx - N1;
        int i = j % 256; int rest = j / 256; int o = rest % 128; int kw = rest / 128;
        float v = w2[((size_t)o * 256 + i) * 3 + kw];
        wT2[j] = f2bf(v);
    } else if (idx < N1 + N2 + N3) {
        int j = idx - N1 - N2;
        int i = j % 128; int rest = j / 128; int o = rest % 64; int kw = rest / 64;
        float v = w3[((size_t)o * 128 + i) * 3 + kw];
        wT3[j] = f2bf(v);
    }
}

__global__ void zero16_kernel(uint4* __restrict__ p, int n16)
{
    int idx = blockIdx.x * 256 + threadIdx.x;
    if (idx < n16) p[idx] = make_uint4(0, 0, 0, 0);
}

// ================= FFT passes =================
// 240 = 16 x 15: n1 = 15a+b; f = f1 + 16*f2. LDS slot layout: col[f1*15 + b].
// 200 = 8 x 25 : e  = 25a+b; f = f1 +  8*f2. LDS slot layout: row[f1*25 + f2].

// pass A: 8 columns/block, 128 threads, ONE barrier. (verified round 4/8)
__global__ __launch_bounds__(128) void passA_kernel(const float* __restrict__ wn,
                                                    float2* __restrict__ I)
{
    __shared__ float2 L[8 * 241];
    int q = blockIdx.y;
    const float* w1p = wn + (size_t)(2 * q) * NA;
    const float* w2p = wn + (size_t)(2 * q + 1) * NA;
    int n20 = blockIdx.x * 8;
    int tid = threadIdx.x;

    if (tid < 120) {
        int b = tid >> 3, j = tid & 7;
        int n2 = n20 + j;
        float2 v[16];
#pragma unroll
        for (int a = 0; a < 16; ++a) {
            int n = (15 * a + b) * 200 + n2;
            v[a] = make_float2(w1p[n], w2p[n]);
        }
        fft16<-1>(v);
#pragma unroll
        for (int f1 = 1; f1 < 16; ++f1)
            v[f1] = cmul(v[f1], cis_rev(-(float)(b * f1) * (1.f / 240.f)));
        float2* col = L + j * 241;
#pragma unroll
        for (int f1 = 0; f1 < 16; ++f1) col[f1 * 15 + b] = v[f1];
    }
    __syncthreads();
    {
        int f1 = tid >> 3, j = tid & 7;
        int n2 = n20 + j;
        float2* col = L + j * 241;
        float2 u[15];
#pragma unroll
        for (int b = 0; b < 15; ++b) u[b] = col[f1 * 15 + b];
        fft15<-1>(u);
#pragma unroll
        for (int f2 = 0; f2 < 15; ++f2) {
            int f = f1 + 16 * f2;
            I[(size_t)q * NA + (size_t)f * 200 + n2] =
                cmul(u[f2], cis_rev(-(float)(n2 * f) * (1.f / (float)NA)));
        }
    }
}

// pass B: 4 conjugate row-pairs per block, 64 threads (single wave), grid 30x32.
// (verified round 8; MODE=1 now computes the 5x32 filter-shape table in LDS
// and interpolates in-register — bit-identical math to the old fbins table.)
template<int MODE>
__global__ __launch_bounds__(64) void passB_kernel(float2* __restrict__ I,
    const float* __restrict__ avg_shape,
    const float* __restrict__ loc_w, float* __restrict__ acc, float* __restrict__ z0)
{
    __shared__ float2 L[8 * 202];
    __shared__ float g1sh[32], g2sh[32];
    __shared__ float fs[5][32];
    int q = blockIdx.y;
    int b1 = 2 * q, b2 = 2 * q + 1;
    int bx = blockIdx.x;
    int tid = threadIdx.x;
    if (MODE == 0) {
        if (tid < 32) { g1sh[tid] = avg_shape[b1 * 32 + tid]; g2sh[tid] = avg_shape[b2 * 32 + tid]; }
    } else {
        if (tid < 5) { g1sh[tid] = loc_w[b1 * 5 + tid]; g2sh[tid] = loc_w[b2 * 5 + tid]; }
        for (int idx = tid; idx < 160; idx += 64) {
            int c = idx >> 5, i = idx & 31;
            fs[c][i] = filter_shape_val(c, i);
        }
    }
    int Rrow[8];
#pragma unroll
    for (int s = 0; s < 8; ++s) {
        int p = s >> 1;
        int pi = 4 * bx + p;
        Rrow[s] = (pi == 0) ? ((s & 1) ? 120 : 0) : ((s & 1) ? 240 - pi : pi);
    }
    // F1
    for (int idx = tid; idx < 200; idx += 64) {
        int s = idx / 25, b = idx - 25 * s;
        const float2* g = I + (size_t)q * NA + (size_t)Rrow[s] * 200;
        float2 v[8];
#pragma unroll
        for (int a = 0; a < 8; ++a) v[a] = g[25 * a + b];
        dftR<-1, 8>(v);
#pragma unroll
        for (int f1 = 1; f1 < 8; ++f1)
            v[f1] = cmul(v[f1], cis_rev(-(float)(b * f1) * (1.f / 200.f)));
        float2* row = L + s * 202;
#pragma unroll
        for (int f1 = 0; f1 < 8; ++f1) row[f1 * 25 + b] = v[f1];
    }
    __syncthreads();
    // F2
    {
        int s = tid >> 3, f1 = tid & 7;
        float2* row = L + s * 202;
        float2 u[25];
#pragma unroll
        for (int b = 0; b < 25; ++b) u[b] = row[f1 * 25 + b];
        fft25<-1>(u);
#pragma unroll
        for (int f2 = 0; f2 < 25; ++f2) row[f1 * 25 + f2] = u[f2];
    }
    __syncthreads();
    // combine
    float part1 = 0.f, part2 = 0.f;
    for (int idx = tid; idx < 804; idx += 64) {
        int p = idx / 201, t = idx - p * 201;
        int pi = 4 * bx + p;
        float2* rwA = L + (2 * p) * 202;
        float2* rwB = L + (2 * p + 1) * 202;
        int k = -1;
        float2 Za, Zb;
        int sa = 0, sb = 0;
        float2* wa = rwA; float2* wb = rwB;
        bool self1 = false;
        if (pi != 0) {
            if (t >= 200) continue;
            sa = slotn(t); sb = slotn(199 - t);
            Za = rwA[sa]; Zb = rwB[sb];
            k = pi + 240 * t;
        } else if (t < 101) {
            wa = rwA; wb = rwA;
            if (t == 0 || t == 100) {
                sa = slotn(t); sb = sa;
                Za = rwA[sa]; Zb = Za;
                k = 240 * t;
                self1 = true;
            } else {
                sa = slotn(t); sb = slotn(200 - t);
                Za = rwA[sa]; Zb = rwA[sb];
                k = 240 * t;
            }
        } else {
            int t2 = t - 101;
            if (t2 >= 100) continue;
            wa = rwB; wb = rwB;
            sa = slotn(t2); sb = slotn(199 - t2);
            Za = rwB[sa]; Zb = rwB[sb];
            k = 120 + 240 * t2;
        }
        int kbin = min(k, NA - k);
        float g1, g2;
        if (MODE == 0) {
            int jj = (kbin * 32) / NBINS;
            if (jj < 31 && (NBINS * (jj + 1)) / 32 <= kbin) ++jj;
            g1 = g1sh[jj]; g2 = g2sh[jj];
        } else {
            // interpolated filter gain (same math as old fbins table)
            float sf = ((float)kbin + 0.5f) * (32.0f / 24001.0f) - 0.5f;
            sf = fminf(fmaxf(sf, 0.f), 31.f);
            int i0 = (int)sf;
            int i1 = min(i0 + 1, 31);
            float w = sf - (float)i0;
            g1 = 0.f; g2 = 0.f;
#pragma unroll
            for (int c = 0; c < 5; ++c) {
                float fb = fs[c][i0] * (1.f - w) + fs[c][i1] * w;
                g1 += g1sh[c] * fb; g2 += g2sh[c] * fb;
            }
        }
        float2 C, Cp; float e1, e2;
        pair_combine(Za, Zb, g1, g2, C, Cp, e1, e2);
        if (MODE == 0) {
            float wgt = self1 ? 1.f : 2.f;
            part1 += wgt * e1; part2 += wgt * e2;
            if (k == 0) { z0[b1] = g1 * Za.x; z0[b2] = g2 * Za.y; }
        }
        wa[sa] = make_float2(C.x * (1.f / NA), C.y * (1.f / NA));
        if (!self1) wb[sb] = make_float2(Cp.x * (1.f / NA), Cp.y * (1.f / NA));
    }
    if (MODE == 0) {
        for (int o = 32; o > 0; o >>= 1) {
            part1 += __shfl_down(part1, o);
            part2 += __shfl_down(part2, o);
        }
        if (tid == 0) { atomicAdd(&acc[b1], part1); atomicAdd(&acc[b2], part2); }
    }
    __syncthreads();
    // I1
    {
        int s = tid >> 3, f1 = tid & 7;
        float2* row = L + s * 202;
        float2 u[25];
#pragma unroll
        for (int f2 = 0; f2 < 25; ++f2) u[f2] = row[f1 * 25 + f2];
        fft25<+1>(u);
#pragma unroll
        for (int b = 0; b < 25; ++b) row[f1 * 25 + b] = u[b];
    }
    __syncthreads();
    // I2
    for (int idx = tid; idx < 200; idx += 64) {
        int s = idx / 25, b = idx - 25 * s;
        float2* row = L + s * 202;
        float2 w[8];
#pragma unroll
        for (int f1 = 0; f1 < 8; ++f1) w[f1] = row[f1 * 25 + b];
#pragma unroll
        for (int f1 = 1; f1 < 8; ++f1)
            w[f1] = cmul(w[f1], cis_rev((float)(b * f1) * (1.f / 200.f)));
        dftR<+1, 8>(w);
        int rg = Rrow[s];
        float2* g = I + (size_t)q * NA + (size_t)rg * 200;
#pragma unroll
        for (int a = 0; a < 8; ++a) {
            int e = 25 * a + b;
            g[e] = cmul(w[a], cis_rev((float)(e * rg) * (1.f / (float)NA)));
        }
    }
}

// pass C: inv240 -> modulate -> fwd240; 8 columns/block, 128 threads, TWO barriers.
// scale computed in-kernel from acc/z0 (finalize_scale folded in; identical math).
__global__ __launch_bounds__(128) void passC_kernel(float2* __restrict__ I,
    const float* __restrict__ control, const float* __restrict__ f0,
    const float* __restrict__ acc, const float* __restrict__ z0)
{
    __shared__ float2 L[8 * 241];
    __shared__ float ctlA[600], ctlB[600];
    __shared__ float f0A[200], f0B[200];
    int q = blockIdx.y;
    int b1 = 2 * q, b2 = 2 * q + 1;
    int n20 = blockIdx.x * 8;
    int tid = threadIdx.x;
    for (int i = tid; i < 600; i += 128) {
        ctlA[i] = control[(size_t)b1 * 1600 + i];
        ctlB[i] = control[(size_t)b2 * 1600 + i];
    }
    for (int i = tid; i < 200; i += 128) {
        f0A[i] = f0[b1 * 200 + i];
        f0B[i] = f0[b2 * 200 + i];
    }
    {
        int f1 = tid >> 3, j = tid & 7;
        int n2 = n20 + j;
        float2 u[15];
#pragma unroll
        for (int f2 = 0; f2 < 15; ++f2)
            u[f2] = I[(size_t)q * NA + (size_t)(f1 + 16 * f2) * 200 + n2];
        fft15<+1>(u);
        float2* col = L + j * 241;
#pragma unroll
        for (int b = 0; b < 15; ++b) col[f1 * 15 + b] = u[b];
    }
    __syncthreads();
    if (tid < 120) {
        int b = tid >> 3, j = tid & 7;
        int n2 = n20 + j;
        float2* col = L + j * 241;
        float var1 = (acc[b1] - z0[b1] * z0[b1]) / (48000.f * 47999.f);
        float sc1 = 0.1f / sqrtf(var1);
        float var2 = (acc[b2] - z0[b2] * z0[b2]) / (48000.f * 47999.f);
        float sc2 = 0.1f / sqrtf(var2);
        float2 w[16];
#pragma unroll
        for (int f1 = 0; f1 < 16; ++f1) w[f1] = col[f1 * 15 + b];
#pragma unroll
        for (int f1 = 1; f1 < 16; ++f1)
            w[f1] = cmul(w[f1], cis_rev((float)(b * f1) * (1.f / 240.f)));
        fft16<+1>(w);
#pragma unroll
        for (int a = 0; a < 16; ++a) {
            int n = 200 * (15 * a + b) + n2;
            float sf = ((float)n + 0.5f) * (1.f / 240.f) - 0.5f;
            sf = fminf(fmaxf(sf, 0.f), 199.f);
            int i0 = (int)sf;
            int i1 = min(i0 + 1, 199);
            float wt = sf - (float)i0, w0 = 1.f - wt;
            float inh = ctlA[i0] * w0 + ctlA[i1] * wt;
            float exh = ctlA[200 + i0] * w0 + ctlA[200 + i1] * wt;
            float pr  = ctlA[400 + i0] * w0 + ctlA[400 + i1] * wt;
            float vv  = (f0A[i0] > 0.f ? 1.f : 0.f) * w0 + (f0A[i1] > 0.f ? 1.f : 0.f) * wt;
            float m1 = inh * (1.f - vv) + exh * pr;
            inh = ctlB[i0] * w0 + ctlB[i1] * wt;
            exh = ctlB[200 + i0] * w0 + ctlB[200 + i1] * wt;
            pr  = ctlB[400 + i0] * w0 + ctlB[400 + i1] * wt;
            vv  = (f0B[i0] > 0.f ? 1.f : 0.f) * w0 + (f0B[i1] > 0.f ? 1.f : 0.f) * wt;
            float m2 = inh * (1.f - vv) + exh * pr;
            w[a] = make_float2(w[a].x * sc1 * m1, w[a].y * sc2 * m2);
        }
        fft16<-1>(w);
#pragma unroll
        for (int f1 = 1; f1 < 16; ++f1)
            w[f1] = cmul(w[f1], cis_rev(-(float)(b * f1) * (1.f / 240.f)));
#pragma unroll
        for (int f1 = 0; f1 < 16; ++f1) col[f1 * 15 + b] = w[f1];
    }
    __syncthreads();
    {
        int f1 = tid >> 3, j = tid & 7;
        int n2 = n20 + j;
        float2* col = L + j * 241;
        float2 u[15];
#pragma unroll
        for (int b = 0; b < 15; ++b) u[b] = col[f1 * 15 + b];
        fft15<-1>(u);
#pragma unroll
        for (int f2 = 0; f2 < 15; ++f2) {
            int f = f1 + 16 * f2;
            I[(size_t)q * NA + (size_t)f * 200 + n2] =
                cmul(u[f2], cis_rev(-(float)(n2 * f) * (1.f / (float)NA)));
        }
    }
}

// pass D: inv240 -> two real outputs; 8 columns/block, 128 threads, ONE barrier.
__global__ __launch_bounds__(128) void passD_kernel(const float2* __restrict__ I,
                                                    float* __restrict__ out)
{
    __shared__ float2 L[8 * 241];
    int q = blockIdx.y;
    int b1 = 2 * q, b2 = 2 * q + 1;
    int n20 = blockIdx.x * 8;
    int tid = threadIdx.x;
    {
        int f1 = tid >> 3, j = tid & 7;
        int n2 = n20 + j;
        float2 u[15];
#pragma unroll
        for (int f2 = 0; f2 < 15; ++f2)
            u[f2] = I[(size_t)q * NA + (size_t)(f1 + 16 * f2) * 200 + n2];
        fft15<+1>(u);
        float2* col = L + j * 241;
#pragma unroll
        for (int b = 0; b < 15; ++b) col[f1 * 15 + b] = u[b];
    }
    __syncthreads();
    if (tid < 120) {
        int b = tid >> 3, j = tid & 7;
        int n2 = n20 + j;
        float2* col = L + j * 241;
        float2 w[16];
#pragma unroll
        for (int f1 = 0; f1 < 16; ++f1) w[f1] = col[f1 * 15 + b];
#pragma unroll
        for (int f1 = 1; f1 < 16; ++f1)
            w[f1] = cmul(w[f1], cis_rev((float)(b * f1) * (1.f / 240.f)));
        fft16<+1>(w);
#pragma unroll
        for (int a = 0; a < 16; ++a) {
            int n = 200 * (15 * a + b) + n2;
            out[(size_t)b1 * NA + n] = w[a].x;
            out[(size_t)b2 * NA + n] = w[a].y;
        }
    }
}

// ---------------- head (locw_mean folded in) ----------------
__global__ void head_kernel(const unsigned short* __restrict__ h3T, const float* __restrict__ w4,
                            const float* __restrict__ b4, float* __restrict__ control,
                            float* __restrict__ avg_shape, float* __restrict__ out_bf,
                            float* __restrict__ loc_w)
{
    __shared__ float w4s[40 * 64];
    __shared__ float b4s[40];
    __shared__ float sp[200 * 33];
    __shared__ float turbsh[5][200];
    int b = blockIdx.x;
    for (int j = threadIdx.x; j < 40 * 64; j += 256) w4s[j] = w4[j];
    if (threadIdx.x < 40) b4s[threadIdx.x] = b4[threadIdx.x];
    __syncthreads();
    int t = threadIdx.x;
    if (t < 200) {
        float p[40];
#pragma unroll
        for (int o = 0; o < 40; ++o) p[o] = b4s[o];
        const unsigned short* hb = h3T + ((size_t)b * 200 + t) * 64;
        for (int i = 0; i < 64; ++i) {
            float h = bf2f(hb[i]);
#pragma unroll
            for (int o = 0; o < 40; ++o) p[o] += h * w4s[o * 64 + i];
        }
        float inh = 1.f / (1.f + expf(-p[0]));
        float exh = 1.f / (1.f + expf(-p[1]));
        float pr  = 1.f / (1.f + expf(-p[2]));
        float mx = p[3];
#pragma unroll
        for (int c = 1; c < 32; ++c) mx = fmaxf(mx, p[3 + c]);
        float e[32];
        float sum = 0.f;
#pragma unroll
        for (int c = 0; c < 32; ++c) { e[c] = expf(p[3 + c] - mx); sum += e[c]; }
        float inv = 1.f / sum;
#pragma unroll
        for (int c = 0; c < 32; ++c) sp[t * 33 + c] = e[c] * inv;
        float mx2 = p[35];
#pragma unroll
        for (int c = 1; c < 5; ++c) mx2 = fmaxf(mx2, p[35 + c]);
        float e2[5];
        float s2 = 0.f;
#pragma unroll
        for (int c = 0; c < 5; ++c) { e2[c] = expf(p[35 + c] - mx2); s2 += e2[c]; }
        float inv2 = 1.f / s2;
        float* ctl = control + (size_t)b * 8 * 200;
        ctl[0 * 200 + t] = inh;
        ctl[1 * 200 + t] = exh;
        ctl[2 * 200 + t] = pr;
#pragma unroll
        for (int c = 0; c < 5; ++c) {
            float tv = e2[c] * inv2;
            ctl[(3 + c) * 200 + t] = tv;
            turbsh[c][t] = tv;
        }
        float* bf = out_bf + (size_t)b * 3 * 200;
        bf[0 * 200 + t] = pr;
        bf[1 * 200 + t] = inh;
        bf[2 * 200 + t] = exh;
    }
    __syncthreads();
    if (t < 32) {
        float s = 0.f;
        for (int j = 0; j < 200; ++j) s += sp[j * 33 + t];
        avg_shape[b * 32 + t] = s * (1.f / 200.f);
    } else if (t < 37) {
        int c = t - 32;
        float s = 0.f;
        for (int j = 0; j < 200; ++j) s += turbsh[c][j];
        loc_w[b * 5 + c] = s * (1.f / 200.f);
    }
}

extern "C" void kernel_launch(void* const* d_in, const int* in_sizes, int n_in,
                              void* d_out, int out_size, void* d_ws, size_t ws_size,
                              hipStream_t stream)
{
    const float* cond = (const float*)d_in[0];
    const float* f0   = (const float*)d_in[1];
    const float* wn   = (const float*)d_in[2];
    const float* w1   = (const float*)d_in[3];
    const float* b1   = (const float*)d_in[4];
    const float* w2   = (const float*)d_in[5];
    const float* b2   = (const float*)d_in[6];
    const float* w3   = (const float*)d_in[7];
    const float* b3   = (const float*)d_in[8];
    const float* w4   = (const float*)d_in[9];
    const float* b4   = (const float*)d_in[10];

    float* out = (float*)d_out;
    float* filtered = out;
    float* bf_out   = out + (size_t)BB * NA;

    char* ws = (char*)d_ws;
    size_t off = 0;
    float2* I = (float2*)(ws + off);            off += 24576000;
    unsigned short* xpT1 = (unsigned short*)(ws + off); off += (size_t)BB * 212 * 160 * 2;
    unsigned short* xpT2 = (unsigned short*)(ws + off); off += (size_t)BB * 210 * 256 * 2;
    unsigned short* xpT3 = (unsigned short*)(ws + off); off += (size_t)BB * 210 * 128 * 2;
    unsigned short* xpT4 = (unsigned short*)(ws + off); off += (size_t)BB * 200 * 64 * 2;
    unsigned short* wT1  = (unsigned short*)(ws + off); off += (size_t)5 * 256 * 160 * 2;
    unsigned short* wT2  = (unsigned short*)(ws + off); off += (size_t)3 * 128 * 256 * 2;
    unsigned short* wT3  = (unsigned short*)(ws + off); off += (size_t)3 * 64 * 128 * 2;
    float* control   = (float*)(ws + off);
    float* avg_shape = control + 102400;
    float* loc_w     = avg_shape + 2048;
    float* acc       = loc_w + 320;
    float* z0        = acc + 64;

    dim3 blk(256);

    // prep (init/acc-z0 zero folded into prep_w_all; xpT2+xpT3 zeroed in one launch)
    {
        int n1 = BB * 212 * 160;
        prep_x1_kernel<<<dim3((n1 + 255) / 256), blk, 0, stream>>>(cond, f0, xpT1);
        int z23 = (BB * 210 * 256 * 2 + BB * 210 * 128 * 2) / 16;
        zero16_kernel<<<dim3((z23 + 255) / 256), blk, 0, stream>>>((uint4*)xpT2, z23);
        int nw = 5 * 256 * 160 + 3 * 128 * 256 + 3 * 64 * 128;
        prep_w_all_kernel<<<dim3((nw + 255) / 256), blk, 0, stream>>>(
            w1, w2, w3, wT1, wT2, wT3, acc, z0);
    }

    // MFMA conv stack
    conv_mfma_kernel<4, 5, 5, 160, 256><<<dim3(13, BB), blk, 0, stream>>>(
        xpT1, 212, wT1, b1, xpT2, 210, 1);
    conv_mfma_kernel<2, 3, 8, 256, 128><<<dim3(13, BB), blk, 0, stream>>>(
        xpT2, 210, wT2, b2, xpT3, 210, 1);
    conv_mfma_kernel<1, 3, 4, 128, 64><<<dim3(13, BB), blk, 0, stream>>>(
        xpT3, 210, wT3, b3, xpT4, 200, 0);

    head_kernel<<<dim3(BB), blk, 0, stream>>>(xpT4, w4, b4, control, avg_shape, bf_out, loc_w);

    // batch-paired four-step FFT pipeline (32 complex signals carry 64 real batches)
    passA_kernel<<<dim3(25, 32), dim3(128), 0, stream>>>(wn, I);
    passB_kernel<0><<<dim3(30, 32), dim3(64), 0, stream>>>(I, avg_shape, loc_w, acc, z0);
    passC_kernel<<<dim3(25, 32), dim3(128), 0, stream>>>(I, control, f0, acc, z0);
    passB_kernel<1><<<dim3(30, 32), dim3(64), 0, stream>>>(I, avg_shape, loc_w, acc, z0);
    passD_kernel<<<dim3(25, 32), dim3(128), 0, stream>>>(I, filtered);
}

// Round 12
// 317.826 us; speedup vs baseline: 1.1534x; 1.0054x over previous
//
#include <hip/hip_runtime.h>
#include <math.h>

#define BB 64
#define T_FR 200
#define NA 48000
#define NBINS 24001

typedef __attribute__((ext_vector_type(4))) float f32x4;
typedef __attribute__((ext_vector_type(8))) short bf16x8;

__device__ __forceinline__ unsigned short f2bf(float x)
{
    unsigned u = __float_as_uint(x);
    u = (u + 0x7FFFu + ((u >> 16) & 1u)) >> 16;
    return (unsigned short)u;
}
__device__ __forceinline__ float bf2f(unsigned short h)
{
    return __uint_as_float(((unsigned)h) << 16);
}

__device__ __forceinline__ float2 cmul(float2 a, float2 b)
{
    return make_float2(a.x * b.x - a.y * b.y, a.x * b.y + a.y * b.x);
}
__device__ __forceinline__ float2 cadd(float2 a, float2 b){ return make_float2(a.x+b.x, a.y+b.y); }
__device__ __forceinline__ float2 csub(float2 a, float2 b){ return make_float2(a.x-b.x, a.y-b.y); }

__device__ __forceinline__ float2 cis_rev(float rev)
{
    return make_float2(__builtin_amdgcn_cosf(rev), __builtin_amdgcn_sinf(rev));
}

// ---------------- root tables ----------------
template<int R> __device__ __forceinline__ void fill_roots(float (&cr)[R], float (&si)[R]);
template<> __device__ __forceinline__ void fill_roots<3>(float (&cr)[3], float (&si)[3])
{
    const float S = 0.86602540378443865f;
    cr[0]=1.f; cr[1]=-0.5f; cr[2]=-0.5f;
    si[0]=0.f; si[1]=S;     si[2]=-S;
}
template<> __device__ __forceinline__ void fill_roots<5>(float (&cr)[5], float (&si)[5])
{
    cr[0]=1.f; cr[1]=0.30901699437494742f; cr[2]=-0.80901699437494742f;
    cr[3]=-0.80901699437494742f; cr[4]=0.30901699437494742f;
    si[0]=0.f; si[1]=0.95105651629515357f; si[2]=0.58778525229247313f;
    si[3]=-0.58778525229247313f; si[4]=-0.95105651629515357f;
}
template<> __device__ __forceinline__ void fill_roots<8>(float (&cr)[8], float (&si)[8])
{
    const float C = 0.70710678118654752f;
    cr[0]=1.f; cr[1]=C;  cr[2]=0.f;  cr[3]=-C; cr[4]=-1.f; cr[5]=-C;  cr[6]=0.f;  cr[7]=C;
    si[0]=0.f; si[1]=C;  si[2]=1.f;  si[3]=C;  si[4]=0.f;  si[5]=-C;  si[6]=-1.f; si[7]=-C;
}

// dftR<S,R>: X[k] = sum_j v[j] * e^{S*2pi*i*j*k/R}
template<int S, int R>
__device__ __forceinline__ void dftR(float2 (&v)[R])
{
    float cr[R], si[R];
    fill_roots<R>(cr, si);
    float2 o[R];
#pragma unroll
    for (int k = 0; k < R; ++k) {
        float re = 0.f, im = 0.f;
#pragma unroll
        for (int j = 0; j < R; ++j) {
            int m = (j * k) % R;
            float ur = cr[m], ui = (S > 0) ? si[m] : -si[m];
            re += v[j].x * ur - v[j].y * ui;
            im += v[j].x * ui + v[j].y * ur;
        }
        o[k] = make_float2(re, im);
    }
#pragma unroll
    for (int k = 0; k < R; ++k) v[k] = o[k];
}

__device__ __constant__ float C25R[17] = {1.f,0.968583161f,0.876306680f,0.728968627f,0.535826795f,0.309016994f,0.062790520f,-0.187381315f,-0.425779292f,-0.637423990f,-0.809016994f,-0.929776486f,-0.992114701f,-0.992114701f,-0.929776486f,-0.809016994f,-0.637423990f};
__device__ __constant__ float C25I[17] = {0.f,0.248689887f,0.481753674f,0.684547106f,0.844327926f,0.951056516f,0.998026728f,0.982287251f,0.904827052f,0.770513243f,0.587785252f,0.368124553f,0.125333234f,-0.125333234f,-0.368124553f,-0.587785252f,-0.770513243f};
__device__ __constant__ float C15R[9] = {1.f,0.913545458f,0.669130606f,0.309016994f,-0.104528463f,-0.5f,-0.809016994f,-0.978147601f,-0.978147601f};
__device__ __constant__ float C15I[9] = {0.f,0.406736643f,0.743144825f,0.951056516f,0.994521895f,0.866025404f,0.587785252f,0.207911691f,-0.207911691f};
__device__ __constant__ float C16R[10] = {1.f,0.923879533f,0.707106781f,0.382683432f,0.f,-0.382683432f,-0.707106781f,-0.923879533f,-1.f,-0.923879533f};
__device__ __constant__ float C16I[10] = {0.f,0.382683432f,0.707106781f,0.923879533f,1.f,0.923879533f,0.707106781f,0.382683432f,0.f,-0.382683432f};

// twXX<S>(m) = e^{S*2pi*i*m/XX}
template<int S> __device__ __forceinline__ float2 tw25(int m){ return make_float2(C25R[m], S>0? C25I[m] : -C25I[m]); }
template<int S> __device__ __forceinline__ float2 tw15(int m){ return make_float2(C15R[m], S>0? C15I[m] : -C15I[m]); }
template<int S> __device__ __forceinline__ float2 tw16(int m){ return make_float2(C16R[m], S>0? C16I[m] : -C16I[m]); }

// ---------------- register sub-FFTs ----------------
template<int S> __device__ __forceinline__ void f4(float2& x0, float2& x1, float2& x2, float2& x3)
{
    float2 e = cadd(x0,x2), f = csub(x0,x2), g = cadd(x1,x3), h = csub(x1,x3);
    float2 r = (S<0) ? make_float2(h.y, -h.x) : make_float2(-h.y, h.x);
    x0 = cadd(e,g); x2 = csub(e,g); x1 = cadd(f,r); x3 = csub(f,r);
}

// fft16: natural-order in/out 16-point DFT (4x4), all registers.
template<int S> __device__ __forceinline__ void fft16(float2 (&v)[16])
{
    float2 t[4][4];
#pragma unroll
    for (int q = 0; q < 4; ++q) {
        float2 a = v[q], b = v[4+q], c = v[8+q], d = v[12+q];
        f4<S>(a,b,c,d);
        t[q][0]=a; t[q][1]=b; t[q][2]=c; t[q][3]=d;
    }
#pragma unroll
    for (int q = 1; q < 4; ++q)
#pragma unroll
        for (int r = 1; r < 4; ++r)
            t[q][r] = cmul(t[q][r], tw16<S>(q*r));
#pragma unroll
    for (int r = 0; r < 4; ++r) {
        float2 a=t[0][r], b=t[1][r], c=t[2][r], d=t[3][r];
        f4<S>(a,b,c,d);
        v[r]=a; v[r+4]=b; v[r+8]=c; v[r+12]=d;
    }
}

// fft15: natural-order in/out 15-point DFT (3x5), all registers.
template<int S> __device__ __forceinline__ void fft15(float2 (&v)[15])
{
    float2 t[5][3]; // t[d][e]
#pragma unroll
    for (int d = 0; d < 5; ++d) {
        float2 u[3] = { v[d], v[5+d], v[10+d] };
        dftR<S,3>(u);
        t[d][0]=u[0];
        t[d][1]=cmul(u[1], tw15<S>(d));
        t[d][2]=cmul(u[2], tw15<S>(2*d));
    }
#pragma unroll
    for (int e = 0; e < 3; ++e) {
        float2 u[5] = { t[0][e],t[1][e],t[2][e],t[3][e],t[4][e] };
        dftR<S,5>(u);
#pragma unroll
        for (int g = 0; g < 5; ++g) v[e + 3*g] = u[g];
    }
}

// fft25: natural-order in/out 25-point DFT (5x5), all registers.
template<int S> __device__ __forceinline__ void fft25(float2 (&v)[25])
{
    float2 t[5][5]; // t[d][e]
#pragma unroll
    for (int d = 0; d < 5; ++d) {
        float2 u[5] = { v[d], v[5+d], v[10+d], v[15+d], v[20+d] };
        dftR<S,5>(u);
        t[d][0] = u[0];
#pragma unroll
        for (int e = 1; e < 5; ++e) t[d][e] = cmul(u[e], tw25<S>(d*e));
    }
#pragma unroll
    for (int e = 0; e < 5; ++e) {
        float2 u[5] = { t[0][e],t[1][e],t[2][e],t[3][e],t[4][e] };
        dftR<S,5>(u);
#pragma unroll
        for (int g = 0; g < 5; ++g) v[e + 5*g] = u[g];
    }
}

// 200-spectrum slot: f = f1 + 8*f2 stored at 25*f1 + f2
__device__ __forceinline__ int slotn(int f) { return 25 * (f & 7) + (f >> 3); }

// Hermitian pair combine (verified)
__device__ __forceinline__ void pair_combine(float2 Za, float2 Zb, float g1, float g2,
                                             float2& C, float2& Cp, float& e1, float& e2)
{
    float2 X1 = make_float2(0.5f * (Za.x + Zb.x), 0.5f * (Za.y - Zb.y));
    float2 w  = make_float2(0.5f * (Za.x - Zb.x), 0.5f * (Za.y + Zb.y));
    float2 X2 = make_float2(w.y, -w.x);
    float2 Z1 = make_float2(g1 * X1.x, g1 * X1.y);
    float2 Z2 = make_float2(g2 * X2.x, g2 * X2.y);
    e1 = Z1.x * Z1.x + Z1.y * Z1.y;
    e2 = Z2.x * Z2.x + Z2.y * Z2.y;
    C  = make_float2(Z1.x - Z2.y,  Z1.y + Z2.x);
    Cp = make_float2(Z1.x + Z2.y, -Z1.y + Z2.x);
}

// filter shapes (5 channels over 32 bands) — same math as reference _filter_shapes
__device__ __forceinline__ float filter_shape_val(int c, int i)
{
    float lin = (float)i * (1.f / 31.f);
    if (c == 0) { float z = (lin - 0.2f) * 10.f;          return expf(-0.5f * z * z); }
    if (c == 1) { float z = (lin - 0.1f) * 10.f;          return expf(-0.5f * z * z); }
    if (c == 2) { float z = (lin - 0.4f) * (1.f / 0.15f); return expf(-0.5f * z * z); }
    if (c == 3) { float z = (lin - 0.6f) * 10.f;          return expf(-0.5f * z * z); }
    float v = 0.1f + 0.9f * lin;
    return v * v;
}

// ================= MFMA conv (unchanged, verified) =================
template<int NT, int TAPS, int CHUNKS, int CINP, int COUTP>
__global__ __launch_bounds__(256) void conv_mfma_kernel(
    const unsigned short* __restrict__ xT, int tRowsIn,
    const unsigned short* __restrict__ wT,
    const float* __restrict__ bias,
    unsigned short* __restrict__ outT, int tRowsOut, int tOffOut)
{
    const int b = blockIdx.y;
    const int t0 = blockIdx.x * 16;
    const int tid = threadIdx.x;
    const int wave = tid >> 6;
    const int lane = tid & 63;
    const int m = lane & 15;
    const int quad = lane >> 4;
    const int n0 = wave * (NT * 16);

    f32x4 acc[NT];
#pragma unroll
    for (int nt = 0; nt < NT; ++nt) acc[nt] = (f32x4){0.f, 0.f, 0.f, 0.f};

    const unsigned short* xb = xT + (size_t)b * tRowsIn * CINP;
#pragma unroll
    for (int kw = 0; kw < TAPS; ++kw) {
        const unsigned short* wk = wT + (size_t)kw * COUTP * CINP;
        const unsigned short* xrow = xb + (size_t)(t0 + kw + m) * CINP + quad * 8;
#pragma unroll
        for (int ch = 0; ch < CHUNKS; ++ch) {
            const int k0 = ch * 32;
            bf16x8 a = *(const bf16x8*)(xrow + k0);
#pragma unroll
            for (int nt = 0; nt < NT; ++nt) {
                bf16x8 bfr = *(const bf16x8*)(wk + (size_t)(n0 + nt * 16 + m) * CINP + k0 + quad * 8);
                acc[nt] = __builtin_amdgcn_mfma_f32_16x16x32_bf16(a, bfr, acc[nt], 0, 0, 0);
            }
        }
    }
#pragma unroll
    for (int nt = 0; nt < NT; ++nt) {
        const int n = n0 + nt * 16 + m;
        const float bz = bias[n];
#pragma unroll
        for (int r = 0; r < 4; ++r) {
            const int t = t0 + quad * 4 + r;
            if (t < 200) {
                float v = acc[nt][r] + bz;
                v = (v >= 0.f) ? v : 0.1f * v;
                outT[((size_t)b * tRowsOut + t + tOffOut) * COUTP + n] = f2bf(v);
            }
        }
    }
}

// ============ merged prep: x1 staging + xpT2/xpT3 zero + weight transpose + acc/z0 init ============
#define N_X1 (BB * 212 * 160)
#define N_Z16 ((BB * 210 * 256 * 2 + BB * 210 * 128 * 2) / 16)
#define NW1 (5 * 256 * 160)
#define NW2 (3 * 128 * 256)
#define NW3 (3 * 64 * 128)

__global__ void prep_all_kernel(const float* __restrict__ cond, const float* __restrict__ f0,
                                const float* __restrict__ w1, const float* __restrict__ w2,
                                const float* __restrict__ w3,
                                unsigned short* __restrict__ xpT1, uint4* __restrict__ zbase,
                                unsigned short* __restrict__ wT1, unsigned short* __restrict__ wT2,
                                unsigned short* __restrict__ wT3,
                                float* __restrict__ acc, float* __restrict__ z0)
{
    int idx = blockIdx.x * 256 + threadIdx.x;
    if (blockIdx.x == 0) {
        if (threadIdx.x < 64) acc[threadIdx.x] = 0.f;
        else if (threadIdx.x < 128) z0[threadIdx.x - 64] = 0.f;
    }
    if (idx < N_X1) {
        int i = idx % 160;
        int rest = idx / 160;
        int tp = rest % 212;
        int b = rest / 212;
        int tt = tp - 2;
        float v = 0.f;
        if (tt >= 0 && tt < 200) {
            if (i < 128) v = cond[((size_t)b * 128 + i) * 200 + tt];
            else if (i == 128) v = (f0[b * 200 + tt] > 0.f) ? 1.f : 0.f;
        }
        xpT1[idx] = f2bf(v);
    } else if (idx < N_X1 + N_Z16) {
        zbase[idx - N_X1] = make_uint4(0, 0, 0, 0);
    } else {
        int j = idx - N_X1 - N_Z16;
        if (j < NW1) {
            int i = j % 160; int rest = j / 160; int o = rest % 256; int kw = rest / 256;
            float v = (i < 129) ? w1[((size_t)o * 129 + i) * 5 + kw] : 0.f;
            wT1[j] = f2bf(v);
        } else if (j < NW1 + NW2) {
            int jj = j - NW1;
            int i = jj % 256; int rest = jj / 256; int o = rest % 128; int kw = rest / 128;
            wT2[jj] = f2bf(w2[((size_t)o * 256 + i) * 3 + kw]);
        } else if (j < NW1 + NW2 + NW3) {
            int jj = j - NW1 - NW2;
            int i = jj % 128; int rest = jj / 128; int o = rest % 64; int kw = rest / 64;
            wT3[jj] = f2bf(w3[((size_t)o * 128 + i) * 3 + kw]);
        }
    }
}

// ================= FFT passes =================
// 240 = 16 x 15: n1 = 15a+b; f = f1 + 16*f2. LDS slot layout: col[f1*15 + b].
// 200 = 8 x 25 : e  = 25a+b; f = f1 +  8*f2. LDS slot layout: row[f1*25 + f2].

// pass A: 8 columns/block, 128 threads, ONE barrier. (verified round 4/8)
__global__ __launch_bounds__(128) void passA_kernel(const float* __restrict__ wn,
                                                    float2* __restrict__ I)
{
    __shared__ float2 L[8 * 241];
    int q = blockIdx.y;
    const float* w1p = wn + (size_t)(2 * q) * NA;
    const float* w2p = wn + (size_t)(2 * q + 1) * NA;
    int n20 = blockIdx.x * 8;
    int tid = threadIdx.x;

    if (tid < 120) {
        int b = tid >> 3, j = tid & 7;
        int n2 = n20 + j;
        float2 v[16];
#pragma unroll
        for (int a = 0; a < 16; ++a) {
            int n = (15 * a + b) * 200 + n2;
            v[a] = make_float2(w1p[n], w2p[n]);
        }
        fft16<-1>(v);
#pragma unroll
        for (int f1 = 1; f1 < 16; ++f1)
            v[f1] = cmul(v[f1], cis_rev(-(float)(b * f1) * (1.f / 240.f)));
        float2* col = L + j * 241;
#pragma unroll
        for (int f1 = 0; f1 < 16; ++f1) col[f1 * 15 + b] = v[f1];
    }
    __syncthreads();
    {
        int f1 = tid >> 3, j = tid & 7;
        int n2 = n20 + j;
        float2* col = L + j * 241;
        float2 u[15];
#pragma unroll
        for (int b = 0; b < 15; ++b) u[b] = col[f1 * 15 + b];
        fft15<-1>(u);
#pragma unroll
        for (int f2 = 0; f2 < 15; ++f2) {
            int f = f1 + 16 * f2;
            I[(size_t)q * NA + (size_t)f * 200 + n2] =
                cmul(u[f2], cis_rev(-(float)(n2 * f) * (1.f / (float)NA)));
        }
    }
}

// pass B: 4 conjugate row-pairs per block, 64 threads (single wave), grid 30x32.
template<int MODE>
__global__ __launch_bounds__(64) void passB_kernel(float2* __restrict__ I,
    const float* __restrict__ avg_shape,
    const float* __restrict__ loc_w, float* __restrict__ acc, float* __restrict__ z0)
{
    __shared__ float2 L[8 * 202];
    __shared__ float g1sh[32], g2sh[32];
    __shared__ float fs[5][32];
    int q = blockIdx.y;
    int b1 = 2 * q, b2 = 2 * q + 1;
    int bx = blockIdx.x;
    int tid = threadIdx.x;
    if (MODE == 0) {
        if (tid < 32) { g1sh[tid] = avg_shape[b1 * 32 + tid]; g2sh[tid] = avg_shape[b2 * 32 + tid]; }
    } else {
        if (tid < 5) { g1sh[tid] = loc_w[b1 * 5 + tid]; g2sh[tid] = loc_w[b2 * 5 + tid]; }
        for (int idx = tid; idx < 160; idx += 64) {
            int c = idx >> 5, i = idx & 31;
            fs[c][i] = filter_shape_val(c, i);
        }
    }
    int Rrow[8];
#pragma unroll
    for (int s = 0; s < 8; ++s) {
        int p = s >> 1;
        int pi = 4 * bx + p;
        Rrow[s] = (pi == 0) ? ((s & 1) ? 120 : 0) : ((s & 1) ? 240 - pi : pi);
    }
    // F1
    for (int idx = tid; idx < 200; idx += 64) {
        int s = idx / 25, b = idx - 25 * s;
        const float2* g = I + (size_t)q * NA + (size_t)Rrow[s] * 200;
        float2 v[8];
#pragma unroll
        for (int a = 0; a < 8; ++a) v[a] = g[25 * a + b];
        dftR<-1, 8>(v);
#pragma unroll
        for (int f1 = 1; f1 < 8; ++f1)
            v[f1] = cmul(v[f1], cis_rev(-(float)(b * f1) * (1.f / 200.f)));
        float2* row = L + s * 202;
#pragma unroll
        for (int f1 = 0; f1 < 8; ++f1) row[f1 * 25 + b] = v[f1];
    }
    __syncthreads();
    // F2
    {
        int s = tid >> 3, f1 = tid & 7;
        float2* row = L + s * 202;
        float2 u[25];
#pragma unroll
        for (int b = 0; b < 25; ++b) u[b] = row[f1 * 25 + b];
        fft25<-1>(u);
#pragma unroll
        for (int f2 = 0; f2 < 25; ++f2) row[f1 * 25 + f2] = u[f2];
    }
    __syncthreads();
    // combine
    float part1 = 0.f, part2 = 0.f;
    for (int idx = tid; idx < 804; idx += 64) {
        int p = idx / 201, t = idx - p * 201;
        int pi = 4 * bx + p;
        float2* rwA = L + (2 * p) * 202;
        float2* rwB = L + (2 * p + 1) * 202;
        int k = -1;
        float2 Za, Zb;
        int sa = 0, sb = 0;
        float2* wa = rwA; float2* wb = rwB;
        bool self1 = false;
        if (pi != 0) {
            if (t >= 200) continue;
            sa = slotn(t); sb = slotn(199 - t);
            Za = rwA[sa]; Zb = rwB[sb];
            k = pi + 240 * t;
        } else if (t < 101) {
            wa = rwA; wb = rwA;
            if (t == 0 || t == 100) {
                sa = slotn(t); sb = sa;
                Za = rwA[sa]; Zb = Za;
                k = 240 * t;
                self1 = true;
            } else {
                sa = slotn(t); sb = slotn(200 - t);
                Za = rwA[sa]; Zb = rwA[sb];
                k = 240 * t;
            }
        } else {
            int t2 = t - 101;
            if (t2 >= 100) continue;
            wa = rwB; wb = rwB;
            sa = slotn(t2); sb = slotn(199 - t2);
            Za = rwB[sa]; Zb = rwB[sb];
            k = 120 + 240 * t2;
        }
        int kbin = min(k, NA - k);
        float g1, g2;
        if (MODE == 0) {
            int jj = (kbin * 32) / NBINS;
            if (jj < 31 && (NBINS * (jj + 1)) / 32 <= kbin) ++jj;
            g1 = g1sh[jj]; g2 = g2sh[jj];
        } else {
            float sf = ((float)kbin + 0.5f) * (32.0f / 24001.0f) - 0.5f;
            sf = fminf(fmaxf(sf, 0.f), 31.f);
            int i0 = (int)sf;
            int i1 = min(i0 + 1, 31);
            float w = sf - (float)i0;
            g1 = 0.f; g2 = 0.f;
#pragma unroll
            for (int c = 0; c < 5; ++c) {
                float fb = fs[c][i0] * (1.f - w) + fs[c][i1] * w;
                g1 += g1sh[c] * fb; g2 += g2sh[c] * fb;
            }
        }
        float2 C, Cp; float e1, e2;
        pair_combine(Za, Zb, g1, g2, C, Cp, e1, e2);
        if (MODE == 0) {
            float wgt = self1 ? 1.f : 2.f;
            part1 += wgt * e1; part2 += wgt * e2;
            if (k == 0) { z0[b1] = g1 * Za.x; z0[b2] = g2 * Za.y; }
        }
        wa[sa] = make_float2(C.x * (1.f / NA), C.y * (1.f / NA));
        if (!self1) wb[sb] = make_float2(Cp.x * (1.f / NA), Cp.y * (1.f / NA));
    }
    if (MODE == 0) {
        for (int o = 32; o > 0; o >>= 1) {
            part1 += __shfl_down(part1, o);
            part2 += __shfl_down(part2, o);
        }
        if (tid == 0) { atomicAdd(&acc[b1], part1); atomicAdd(&acc[b2], part2); }
    }
    __syncthreads();
    // I1
    {
        int s = tid >> 3, f1 = tid & 7;
        float2* row = L + s * 202;
        float2 u[25];
#pragma unroll
        for (int f2 = 0; f2 < 25; ++f2) u[f2] = row[f1 * 25 + f2];
        fft25<+1>(u);
#pragma unroll
        for (int b = 0; b < 25; ++b) row[f1 * 25 + b] = u[b];
    }
    __syncthreads();
    // I2
    for (int idx = tid; idx < 200; idx += 64) {
        int s = idx / 25, b = idx - 25 * s;
        float2* row = L + s * 202;
        float2 w[8];
#pragma unroll
        for (int f1 = 0; f1 < 8; ++f1) w[f1] = row[f1 * 25 + b];
#pragma unroll
        for (int f1 = 1; f1 < 8; ++f1)
            w[f1] = cmul(w[f1], cis_rev((float)(b * f1) * (1.f / 200.f)));
        dftR<+1, 8>(w);
        int rg = Rrow[s];
        float2* g = I + (size_t)q * NA + (size_t)rg * 200;
#pragma unroll
        for (int a = 0; a < 8; ++a) {
            int e = 25 * a + b;
            g[e] = cmul(w[a], cis_rev((float)(e * rg) * (1.f / (float)NA)));
        }
    }
}

// pass C: inv240 -> modulate -> fwd240; 8 columns/block, 128 threads, TWO barriers.
__global__ __launch_bounds__(128) void passC_kernel(float2* __restrict__ I,
    const float* __restrict__ control, const float* __restrict__ f0,
    const float* __restrict__ acc, const float* __restrict__ z0)
{
    __shared__ float2 L[8 * 241];
    __shared__ float ctlA[600], ctlB[600];
    __shared__ float f0A[200], f0B[200];
    int q = blockIdx.y;
    int b1 = 2 * q, b2 = 2 * q + 1;
    int n20 = blockIdx.x * 8;
    int tid = threadIdx.x;
    for (int i = tid; i < 600; i += 128) {
        ctlA[i] = control[(size_t)b1 * 1600 + i];
        ctlB[i] = control[(size_t)b2 * 1600 + i];
    }
    for (int i = tid; i < 200; i += 128) {
        f0A[i] = f0[b1 * 200 + i];
        f0B[i] = f0[b2 * 200 + i];
    }
    {
        int f1 = tid >> 3, j = tid & 7;
        int n2 = n20 + j;
        float2 u[15];
#pragma unroll
        for (int f2 = 0; f2 < 15; ++f2)
            u[f2] = I[(size_t)q * NA + (size_t)(f1 + 16 * f2) * 200 + n2];
        fft15<+1>(u);
        float2* col = L + j * 241;
#pragma unroll
        for (int b = 0; b < 15; ++b) col[f1 * 15 + b] = u[b];
    }
    __syncthreads();
    if (tid < 120) {
        int b = tid >> 3, j = tid & 7;
        int n2 = n20 + j;
        float2* col = L + j * 241;
        float var1 = (acc[b1] - z0[b1] * z0[b1]) / (48000.f * 47999.f);
        float sc1 = 0.1f / sqrtf(var1);
        float var2 = (acc[b2] - z0[b2] * z0[b2]) / (48000.f * 47999.f);
        float sc2 = 0.1f / sqrtf(var2);
        float2 w[16];
#pragma unroll
        for (int f1 = 0; f1 < 16; ++f1) w[f1] = col[f1 * 15 + b];
#pragma unroll
        for (int f1 = 1; f1 < 16; ++f1)
            w[f1] = cmul(w[f1], cis_rev((float)(b * f1) * (1.f / 240.f)));
        fft16<+1>(w);
#pragma unroll
        for (int a = 0; a < 16; ++a) {
            int n = 200 * (15 * a + b) + n2;
            float sf = ((float)n + 0.5f) * (1.f / 240.f) - 0.5f;
            sf = fminf(fmaxf(sf, 0.f), 199.f);
            int i0 = (int)sf;
            int i1 = min(i0 + 1, 199);
            float wt = sf - (float)i0, w0 = 1.f - wt;
            float inh = ctlA[i0] * w0 + ctlA[i1] * wt;
            float exh = ctlA[200 + i0] * w0 + ctlA[200 + i1] * wt;
            float pr  = ctlA[400 + i0] * w0 + ctlA[400 + i1] * wt;
            float vv  = (f0A[i0] > 0.f ? 1.f : 0.f) * w0 + (f0A[i1] > 0.f ? 1.f : 0.f) * wt;
            float m1 = inh * (1.f - vv) + exh * pr;
            inh = ctlB[i0] * w0 + ctlB[i1] * wt;
            exh = ctlB[200 + i0] * w0 + ctlB[200 + i1] * wt;
            pr  = ctlB[400 + i0] * w0 + ctlB[400 + i1] * wt;
            vv  = (f0B[i0] > 0.f ? 1.f : 0.f) * w0 + (f0B[i1] > 0.f ? 1.f : 0.f) * wt;
            float m2 = inh * (1.f - vv) + exh * pr;
            w[a] = make_float2(w[a].x * sc1 * m1, w[a].y * sc2 * m2);
        }
        fft16<-1>(w);
#pragma unroll
        for (int f1 = 1; f1 < 16; ++f1)
            w[f1] = cmul(w[f1], cis_rev(-(float)(b * f1) * (1.f / 240.f)));
#pragma unroll
        for (int f1 = 0; f1 < 16; ++f1) col[f1 * 15 + b] = w[f1];
    }
    __syncthreads();
    {
        int f1 = tid >> 3, j = tid & 7;
        int n2 = n20 + j;
        float2* col = L + j * 241;
        float2 u[15];
#pragma unroll
        for (int b = 0; b < 15; ++b) u[b] = col[f1 * 15 + b];
        fft15<-1>(u);
#pragma unroll
        for (int f2 = 0; f2 < 15; ++f2) {
            int f = f1 + 16 * f2;
            I[(size_t)q * NA + (size_t)f * 200 + n2] =
                cmul(u[f2], cis_rev(-(float)(n2 * f) * (1.f / (float)NA)));
        }
    }
}

// pass D: inv240 -> two real outputs; 8 columns/block, 128 threads, ONE barrier.
__global__ __launch_bounds__(128) void passD_kernel(const float2* __restrict__ I,
                                                    float* __restrict__ out)
{
    __shared__ float2 L[8 * 241];
    int q = blockIdx.y;
    int b1 = 2 * q, b2 = 2 * q + 1;
    int n20 = blockIdx.x * 8;
    int tid = threadIdx.x;
    {
        int f1 = tid >> 3, j = tid & 7;
        int n2 = n20 + j;
        float2 u[15];
#pragma unroll
        for (int f2 = 0; f2 < 15; ++f2)
            u[f2] = I[(size_t)q * NA + (size_t)(f1 + 16 * f2) * 200 + n2];
        fft15<+1>(u);
        float2* col = L + j * 241;
#pragma unroll
        for (int b = 0; b < 15; ++b) col[f1 * 15 + b] = u[b];
    }
    __syncthreads();
    if (tid < 120) {
        int b = tid >> 3, j = tid & 7;
        int n2 = n20 + j;
        float2* col = L + j * 241;
        float2 w[16];
#pragma unroll
        for (int f1 = 0; f1 < 16; ++f1) w[f1] = col[f1 * 15 + b];
#pragma unroll
        for (int f1 = 1; f1 < 16; ++f1)
            w[f1] = cmul(w[f1], cis_rev((float)(b * f1) * (1.f / 240.f)));
        fft16<+1>(w);
#pragma unroll
        for (int a = 0; a < 16; ++a) {
            int n = 200 * (15 * a + b) + n2;
            out[(size_t)b1 * NA + n] = w[a].x;
            out[(size_t)b2 * NA + n] = w[a].y;
        }
    }
}

// ---------------- head (locw_mean folded in) ----------------
__global__ void head_kernel(const unsigned short* __restrict__ h3T, const float* __restrict__ w4,
                            const float* __restrict__ b4, float* __restrict__ control,
                            float* __restrict__ avg_shape, float* __restrict__ out_bf,
                            float* __restrict__ loc_w)
{
    __shared__ float w4s[40 * 64];
    __shared__ float b4s[40];
    __shared__ float sp[200 * 33];
    __shared__ float turbsh[5][200];
    int b = blockIdx.x;
    for (int j = threadIdx.x; j < 40 * 64; j += 256) w4s[j] = w4[j];
    if (threadIdx.x < 40) b4s[threadIdx.x] = b4[threadIdx.x];
    __syncthreads();
    int t = threadIdx.x;
    if (t < 200) {
        float p[40];
#pragma unroll
        for (int o = 0; o < 40; ++o) p[o] = b4s[o];
        const unsigned short* hb = h3T + ((size_t)b * 200 + t) * 64;
        for (int i = 0; i < 64; ++i) {
            float h = bf2f(hb[i]);
#pragma unroll
            for (int o = 0; o < 40; ++o) p[o] += h * w4s[o * 64 + i];
        }
        float inh = 1.f / (1.f + expf(-p[0]));
        float exh = 1.f / (1.f + expf(-p[1]));
        float pr  = 1.f / (1.f + expf(-p[2]));
        float mx = p[3];
#pragma unroll
        for (int c = 1; c < 32; ++c) mx = fmaxf(mx, p[3 + c]);
        float e[32];
        float sum = 0.f;
#pragma unroll
        for (int c = 0; c < 32; ++c) { e[c] = expf(p[3 + c] - mx); sum += e[c]; }
        float inv = 1.f / sum;
#pragma unroll
        for (int c = 0; c < 32; ++c) sp[t * 33 + c] = e[c] * inv;
        float mx2 = p[35];
#pragma unroll
        for (int c = 1; c < 5; ++c) mx2 = fmaxf(mx2, p[35 + c]);
        float e2[5];
        float s2 = 0.f;
#pragma unroll
        for (int c = 0; c < 5; ++c) { e2[c] = expf(p[35 + c] - mx2); s2 += e2[c]; }
        float inv2 = 1.f / s2;
        float* ctl = control + (size_t)b * 8 * 200;
        ctl[0 * 200 + t] = inh;
        ctl[1 * 200 + t] = exh;
        ctl[2 * 200 + t] = pr;
#pragma unroll
        for (int c = 0; c < 5; ++c) {
            float tv = e2[c] * inv2;
            ctl[(3 + c) * 200 + t] = tv;
            turbsh[c][t] = tv;
        }
        float* bf = out_bf + (size_t)b * 3 * 200;
        bf[0 * 200 + t] = pr;
        bf[1 * 200 + t] = inh;
        bf[2 * 200 + t] = exh;
    }
    __syncthreads();
    if (t < 32) {
        float s = 0.f;
        for (int j = 0; j < 200; ++j) s += sp[j * 33 + t];
        avg_shape[b * 32 + t] = s * (1.f / 200.f);
    } else if (t < 37) {
        int c = t - 32;
        float s = 0.f;
        for (int j = 0; j < 200; ++j) s += turbsh[c][j];
        loc_w[b * 5 + c] = s * (1.f / 200.f);
    }
}

extern "C" void kernel_launch(void* const* d_in, const int* in_sizes, int n_in,
                              void* d_out, int out_size, void* d_ws, size_t ws_size,
                              hipStream_t stream)
{
    const float* cond = (const float*)d_in[0];
    const float* f0   = (const float*)d_in[1];
    const float* wn   = (const float*)d_in[2];
    const float* w1   = (const float*)d_in[3];
    const float* b1   = (const float*)d_in[4];
    const float* w2   = (const float*)d_in[5];
    const float* b2   = (const float*)d_in[6];
    const float* w3   = (const float*)d_in[7];
    const float* b3   = (const float*)d_in[8];
    const float* w4   = (const float*)d_in[9];
    const float* b4   = (const float*)d_in[10];

    float* out = (float*)d_out;
    float* filtered = out;
    float* bf_out   = out + (size_t)BB * NA;

    char* ws = (char*)d_ws;
    size_t off = 0;
    float2* I = (float2*)(ws + off);            off += 24576000;
    unsigned short* xpT1 = (unsigned short*)(ws + off); off += (size_t)BB * 212 * 160 * 2;
    unsigned short* xpT2 = (unsigned short*)(ws + off); off += (size_t)BB * 210 * 256 * 2;
    unsigned short* xpT3 = (unsigned short*)(ws + off); off += (size_t)BB * 210 * 128 * 2;
    unsigned short* xpT4 = (unsigned short*)(ws + off); off += (size_t)BB * 200 * 64 * 2;
    unsigned short* wT1  = (unsigned short*)(ws + off); off += (size_t)5 * 256 * 160 * 2;
    unsigned short* wT2  = (unsigned short*)(ws + off); off += (size_t)3 * 128 * 256 * 2;
    unsigned short* wT3  = (unsigned short*)(ws + off); off += (size_t)3 * 64 * 128 * 2;
    float* control   = (float*)(ws + off);
    float* avg_shape = control + 102400;
    float* loc_w     = avg_shape + 2048;
    float* acc       = loc_w + 320;
    float* z0        = acc + 64;

    dim3 blk(256);

    // single merged prep launch (x1 staging + xpT2/xpT3 zero + weight transpose + acc/z0 init)
    {
        int total = N_X1 + N_Z16 + NW1 + NW2 + NW3;
        prep_all_kernel<<<dim3((total + 255) / 256), blk, 0, stream>>>(
            cond, f0, w1, w2, w3, xpT1, (uint4*)xpT2, wT1, wT2, wT3, acc, z0);
    }

    // MFMA conv stack
    conv_mfma_kernel<4, 5, 5, 160, 256><<<dim3(13, BB), blk, 0, stream>>>(
        xpT1, 212, wT1, b1, xpT2, 210, 1);
    conv_mfma_kernel<2, 3, 8, 256, 128><<<dim3(13, BB), blk, 0, stream>>>(
        xpT2, 210, wT2, b2, xpT3, 210, 1);
    conv_mfma_kernel<1, 3, 4, 128, 64><<<dim3(13, BB), blk, 0, stream>>>(
        xpT3, 210, wT3, b3, xpT4, 200, 0);

    head_kernel<<<dim3(BB), blk, 0, stream>>>(xpT4, w4, b4, control, avg_shape, bf_out, loc_w);

    // batch-paired four-step FFT pipeline (32 complex signals carry 64 real batches)
    passA_kernel<<<dim3(25, 32), dim3(128), 0, stream>>>(wn, I);
    passB_kernel<0><<<dim3(30, 32), dim3(64), 0, stream>>>(I, avg_shape, loc_w, acc, z0);
    passC_kernel<<<dim3(25, 32), dim3(128), 0, stream>>>(I, control, f0, acc, z0);
    passB_kernel<1><<<dim3(30, 32), dim3(64), 0, stream>>>(I, avg_shape, loc_w, acc, z0);
    passD_kernel<<<dim3(25, 32), dim3(128), 0, stream>>>(I, filtered);
}

// Round 13
// 303.005 us; speedup vs baseline: 1.2098x; 1.0489x over previous
//
#include <hip/hip_runtime.h>
#include <math.h>

#define BB 64
#define T_FR 200
#define NA 48000
#define NBINS 24001

typedef __attribute__((ext_vector_type(4))) float f32x4;
typedef __attribute__((ext_vector_type(8))) short bf16x8;

__device__ __forceinline__ unsigned short f2bf(float x)
{
    unsigned u = __float_as_uint(x);
    u = (u + 0x7FFFu + ((u >> 16) & 1u)) >> 16;
    return (unsigned short)u;
}
__device__ __forceinline__ float bf2f(unsigned short h)
{
    return __uint_as_float(((unsigned)h) << 16);
}

__device__ __forceinline__ float2 cmul(float2 a, float2 b)
{
    return make_float2(a.x * b.x - a.y * b.y, a.x * b.y + a.y * b.x);
}
__device__ __forceinline__ float2 cadd(float2 a, float2 b){ return make_float2(a.x+b.x, a.y+b.y); }
__device__ __forceinline__ float2 csub(float2 a, float2 b){ return make_float2(a.x-b.x, a.y-b.y); }

__device__ __forceinline__ float2 cis_rev(float rev)
{
    return make_float2(__builtin_amdgcn_cosf(rev), __builtin_amdgcn_sinf(rev));
}

// ---------------- root tables ----------------
template<int R> __device__ __forceinline__ void fill_roots(float (&cr)[R], float (&si)[R]);
template<> __device__ __forceinline__ void fill_roots<3>(float (&cr)[3], float (&si)[3])
{
    const float S = 0.86602540378443865f;
    cr[0]=1.f; cr[1]=-0.5f; cr[2]=-0.5f;
    si[0]=0.f; si[1]=S;     si[2]=-S;
}
template<> __device__ __forceinline__ void fill_roots<5>(float (&cr)[5], float (&si)[5])
{
    cr[0]=1.f; cr[1]=0.30901699437494742f; cr[2]=-0.80901699437494742f;
    cr[3]=-0.80901699437494742f; cr[4]=0.30901699437494742f;
    si[0]=0.f; si[1]=0.95105651629515357f; si[2]=0.58778525229247313f;
    si[3]=-0.58778525229247313f; si[4]=-0.95105651629515357f;
}
template<> __device__ __forceinline__ void fill_roots<8>(float (&cr)[8], float (&si)[8])
{
    const float C = 0.70710678118654752f;
    cr[0]=1.f; cr[1]=C;  cr[2]=0.f;  cr[3]=-C; cr[4]=-1.f; cr[5]=-C;  cr[6]=0.f;  cr[7]=C;
    si[0]=0.f; si[1]=C;  si[2]=1.f;  si[3]=C;  si[4]=0.f;  si[5]=-C;  si[6]=-1.f; si[7]=-C;
}

// dftR<S,R>: X[k] = sum_j v[j] * e^{S*2pi*i*j*k/R}
template<int S, int R>
__device__ __forceinline__ void dftR(float2 (&v)[R])
{
    float cr[R], si[R];
    fill_roots<R>(cr, si);
    float2 o[R];
#pragma unroll
    for (int k = 0; k < R; ++k) {
        float re = 0.f, im = 0.f;
#pragma unroll
        for (int j = 0; j < R; ++j) {
            int m = (j * k) % R;
            float ur = cr[m], ui = (S > 0) ? si[m] : -si[m];
            re += v[j].x * ur - v[j].y * ui;
            im += v[j].x * ui + v[j].y * ur;
        }
        o[k] = make_float2(re, im);
    }
#pragma unroll
    for (int k = 0; k < R; ++k) v[k] = o[k];
}

__device__ __constant__ float C25R[17] = {1.f,0.968583161f,0.876306680f,0.728968627f,0.535826795f,0.309016994f,0.062790520f,-0.187381315f,-0.425779292f,-0.637423990f,-0.809016994f,-0.929776486f,-0.992114701f,-0.992114701f,-0.929776486f,-0.809016994f,-0.637423990f};
__device__ __constant__ float C25I[17] = {0.f,0.248689887f,0.481753674f,0.684547106f,0.844327926f,0.951056516f,0.998026728f,0.982287251f,0.904827052f,0.770513243f,0.587785252f,0.368124553f,0.125333234f,-0.125333234f,-0.368124553f,-0.587785252f,-0.770513243f};
__device__ __constant__ float C15R[9] = {1.f,0.913545458f,0.669130606f,0.309016994f,-0.104528463f,-0.5f,-0.809016994f,-0.978147601f,-0.978147601f};
__device__ __constant__ float C15I[9] = {0.f,0.406736643f,0.743144825f,0.951056516f,0.994521895f,0.866025404f,0.587785252f,0.207911691f,-0.207911691f};
__device__ __constant__ float C16R[10] = {1.f,0.923879533f,0.707106781f,0.382683432f,0.f,-0.382683432f,-0.707106781f,-0.923879533f,-1.f,-0.923879533f};
__device__ __constant__ float C16I[10] = {0.f,0.382683432f,0.707106781f,0.923879533f,1.f,0.923879533f,0.707106781f,0.382683432f,0.f,-0.382683432f};

// twXX<S>(m) = e^{S*2pi*i*m/XX}
template<int S> __device__ __forceinline__ float2 tw25(int m){ return make_float2(C25R[m], S>0? C25I[m] : -C25I[m]); }
template<int S> __device__ __forceinline__ float2 tw15(int m){ return make_float2(C15R[m], S>0? C15I[m] : -C15I[m]); }
template<int S> __device__ __forceinline__ float2 tw16(int m){ return make_float2(C16R[m], S>0? C16I[m] : -C16I[m]); }

// ---------------- register sub-FFTs ----------------
template<int S> __device__ __forceinline__ void f4(float2& x0, float2& x1, float2& x2, float2& x3)
{
    float2 e = cadd(x0,x2), f = csub(x0,x2), g = cadd(x1,x3), h = csub(x1,x3);
    float2 r = (S<0) ? make_float2(h.y, -h.x) : make_float2(-h.y, h.x);
    x0 = cadd(e,g); x2 = csub(e,g); x1 = cadd(f,r); x3 = csub(f,r);
}

// fft16: natural-order in/out 16-point DFT (4x4), all registers.
template<int S> __device__ __forceinline__ void fft16(float2 (&v)[16])
{
    float2 t[4][4];
#pragma unroll
    for (int q = 0; q < 4; ++q) {
        float2 a = v[q], b = v[4+q], c = v[8+q], d = v[12+q];
        f4<S>(a,b,c,d);
        t[q][0]=a; t[q][1]=b; t[q][2]=c; t[q][3]=d;
    }
#pragma unroll
    for (int q = 1; q < 4; ++q)
#pragma unroll
        for (int r = 1; r < 4; ++r)
            t[q][r] = cmul(t[q][r], tw16<S>(q*r));
#pragma unroll
    for (int r = 0; r < 4; ++r) {
        float2 a=t[0][r], b=t[1][r], c=t[2][r], d=t[3][r];
        f4<S>(a,b,c,d);
        v[r]=a; v[r+4]=b; v[r+8]=c; v[r+12]=d;
    }
}

// fft15: natural-order in/out 15-point DFT (3x5), all registers.
template<int S> __device__ __forceinline__ void fft15(float2 (&v)[15])
{
    float2 t[5][3]; // t[d][e]
#pragma unroll
    for (int d = 0; d < 5; ++d) {
        float2 u[3] = { v[d], v[5+d], v[10+d] };
        dftR<S,3>(u);
        t[d][0]=u[0];
        t[d][1]=cmul(u[1], tw15<S>(d));
        t[d][2]=cmul(u[2], tw15<S>(2*d));
    }
#pragma unroll
    for (int e = 0; e < 3; ++e) {
        float2 u[5] = { t[0][e],t[1][e],t[2][e],t[3][e],t[4][e] };
        dftR<S,5>(u);
#pragma unroll
        for (int g = 0; g < 5; ++g) v[e + 3*g] = u[g];
    }
}

// fft25: natural-order in/out 25-point DFT (5x5), all registers.
template<int S> __device__ __forceinline__ void fft25(float2 (&v)[25])
{
    float2 t[5][5]; // t[d][e]
#pragma unroll
    for (int d = 0; d < 5; ++d) {
        float2 u[5] = { v[d], v[5+d], v[10+d], v[15+d], v[20+d] };
        dftR<S,5>(u);
        t[d][0] = u[0];
#pragma unroll
        for (int e = 1; e < 5; ++e) t[d][e] = cmul(u[e], tw25<S>(d*e));
    }
#pragma unroll
    for (int e = 0; e < 5; ++e) {
        float2 u[5] = { t[0][e],t[1][e],t[2][e],t[3][e],t[4][e] };
        dftR<S,5>(u);
#pragma unroll
        for (int g = 0; g < 5; ++g) v[e + 5*g] = u[g];
    }
}

// 200-spectrum slot: f = f1 + 8*f2 stored at 25*f1 + f2
__device__ __forceinline__ int slotn(int f) { return 25 * (f & 7) + (f >> 3); }

// Hermitian pair combine (verified)
__device__ __forceinline__ void pair_combine(float2 Za, float2 Zb, float g1, float g2,
                                             float2& C, float2& Cp, float& e1, float& e2)
{
    float2 X1 = make_float2(0.5f * (Za.x + Zb.x), 0.5f * (Za.y - Zb.y));
    float2 w  = make_float2(0.5f * (Za.x - Zb.x), 0.5f * (Za.y + Zb.y));
    float2 X2 = make_float2(w.y, -w.x);
    float2 Z1 = make_float2(g1 * X1.x, g1 * X1.y);
    float2 Z2 = make_float2(g2 * X2.x, g2 * X2.y);
    e1 = Z1.x * Z1.x + Z1.y * Z1.y;
    e2 = Z2.x * Z2.x + Z2.y * Z2.y;
    C  = make_float2(Z1.x - Z2.y,  Z1.y + Z2.x);
    Cp = make_float2(Z1.x + Z2.y, -Z1.y + Z2.x);
}

// filter shapes (5 channels over 32 bands) — same math as reference _filter_shapes
__device__ __forceinline__ float filter_shape_val(int c, int i)
{
    float lin = (float)i * (1.f / 31.f);
    if (c == 0) { float z = (lin - 0.2f) * 10.f;          return expf(-0.5f * z * z); }
    if (c == 1) { float z = (lin - 0.1f) * 10.f;          return expf(-0.5f * z * z); }
    if (c == 2) { float z = (lin - 0.4f) * (1.f / 0.15f); return expf(-0.5f * z * z); }
    if (c == 3) { float z = (lin - 0.6f) * 10.f;          return expf(-0.5f * z * z); }
    float v = 0.1f + 0.9f * lin;
    return v * v;
}

// ================= MFMA conv (unchanged, verified) =================
template<int NT, int TAPS, int CHUNKS, int CINP, int COUTP>
__global__ __launch_bounds__(256) void conv_mfma_kernel(
    const unsigned short* __restrict__ xT, int tRowsIn,
    const unsigned short* __restrict__ wT,
    const float* __restrict__ bias,
    unsigned short* __restrict__ outT, int tRowsOut, int tOffOut)
{
    const int b = blockIdx.y;
    const int t0 = blockIdx.x * 16;
    const int tid = threadIdx.x;
    const int wave = tid >> 6;
    const int lane = tid & 63;
    const int m = lane & 15;
    const int quad = lane >> 4;
    const int n0 = wave * (NT * 16);

    f32x4 acc[NT];
#pragma unroll
    for (int nt = 0; nt < NT; ++nt) acc[nt] = (f32x4){0.f, 0.f, 0.f, 0.f};

    const unsigned short* xb = xT + (size_t)b * tRowsIn * CINP;
#pragma unroll
    for (int kw = 0; kw < TAPS; ++kw) {
        const unsigned short* wk = wT + (size_t)kw * COUTP * CINP;
        const unsigned short* xrow = xb + (size_t)(t0 + kw + m) * CINP + quad * 8;
#pragma unroll
        for (int ch = 0; ch < CHUNKS; ++ch) {
            const int k0 = ch * 32;
            bf16x8 a = *(const bf16x8*)(xrow + k0);
#pragma unroll
            for (int nt = 0; nt < NT; ++nt) {
                bf16x8 bfr = *(const bf16x8*)(wk + (size_t)(n0 + nt * 16 + m) * CINP + k0 + quad * 8);
                acc[nt] = __builtin_amdgcn_mfma_f32_16x16x32_bf16(a, bfr, acc[nt], 0, 0, 0);
            }
        }
    }
#pragma unroll
    for (int nt = 0; nt < NT; ++nt) {
        const int n = n0 + nt * 16 + m;
        const float bz = bias[n];
#pragma unroll
        for (int r = 0; r < 4; ++r) {
            const int t = t0 + quad * 4 + r;
            if (t < 200) {
                float v = acc[nt][r] + bz;
                v = (v >= 0.f) ? v : 0.1f * v;
                outT[((size_t)b * tRowsOut + t + tOffOut) * COUTP + n] = f2bf(v);
            }
        }
    }
}

// ============ merged prep: x1 staging + halo zero + stat zero + weight transpose ============
// xpT2/xpT3 halo rows (0 and 201..209 per batch) are the only rows conv never writes
// but conv-next reads; zero just those instead of the whole buffers.
#define N_X1 (BB * 212 * 160)
#define N_H2 (BB * 10 * 32)    // uint4 per xpT2 halo (10 rows x 256 shorts = 32 uint4/row)
#define N_H3 (BB * 10 * 16)    // uint4 per xpT3 halo
#define N_ZF 624               // uint4 zeroing avg_shape..z0 (2496 floats, contiguous)
#define NW1 (5 * 256 * 160)
#define NW2 (3 * 128 * 256)
#define NW3 (3 * 64 * 128)

__global__ void prep_all_kernel(const float* __restrict__ cond, const float* __restrict__ f0,
                                const float* __restrict__ w1, const float* __restrict__ w2,
                                const float* __restrict__ w3,
                                unsigned short* __restrict__ xpT1,
                                uint4* __restrict__ xpT2v, uint4* __restrict__ xpT3v,
                                unsigned short* __restrict__ wT1, unsigned short* __restrict__ wT2,
                                unsigned short* __restrict__ wT3,
                                uint4* __restrict__ zf)
{
    int idx = blockIdx.x * 256 + threadIdx.x;
    if (idx < N_X1) {
        int i = idx % 160;
        int rest = idx / 160;
        int tp = rest % 212;
        int b = rest / 212;
        int tt = tp - 2;
        float v = 0.f;
        if (tt >= 0 && tt < 200) {
            if (i < 128) v = cond[((size_t)b * 128 + i) * 200 + tt];
            else if (i == 128) v = (f0[b * 200 + tt] > 0.f) ? 1.f : 0.f;
        }
        xpT1[idx] = f2bf(v);
    } else if (idx < N_X1 + N_H2) {
        int h = idx - N_X1;
        int b = h / 320; int rem = h - b * 320;
        int r10 = rem >> 5, c = rem & 31;
        int row = (r10 == 0) ? 0 : 200 + r10;
        xpT2v[(size_t)(b * 210 + row) * 32 + c] = make_uint4(0, 0, 0, 0);
    } else if (idx < N_X1 + N_H2 + N_H3) {
        int h = idx - N_X1 - N_H2;
        int b = h / 160; int rem = h - b * 160;
        int r10 = rem >> 4, c = rem & 15;
        int row = (r10 == 0) ? 0 : 200 + r10;
        xpT3v[(size_t)(b * 210 + row) * 16 + c] = make_uint4(0, 0, 0, 0);
    } else if (idx < N_X1 + N_H2 + N_H3 + N_ZF) {
        zf[idx - N_X1 - N_H2 - N_H3] = make_uint4(0, 0, 0, 0);
    } else {
        int j = idx - N_X1 - N_H2 - N_H3 - N_ZF;
        if (j < NW1) {
            int i = j % 160; int rest = j / 160; int o = rest % 256; int kw = rest / 256;
            float v = (i < 129) ? w1[((size_t)o * 129 + i) * 5 + kw] : 0.f;
            wT1[j] = f2bf(v);
        } else if (j < NW1 + NW2) {
            int jj = j - NW1;
            int i = jj % 256; int rest = jj / 256; int o = rest % 128; int kw = rest / 128;
            wT2[jj] = f2bf(w2[((size_t)o * 256 + i) * 3 + kw]);
        } else if (j < NW1 + NW2 + NW3) {
            int jj = j - NW1 - NW2;
            int i = jj % 128; int rest = jj / 128; int o = rest % 64; int kw = rest / 64;
            wT3[jj] = f2bf(w3[((size_t)o * 128 + i) * 3 + kw]);
        }
    }
}

// ================= FFT passes =================
// 240 = 16 x 15: n1 = 15a+b; f = f1 + 16*f2. LDS slot layout: col[f1*15 + b].
// 200 = 8 x 25 : e  = 25a+b; f = f1 +  8*f2. LDS slot layout: row[f1*25 + f2].

// pass A: 8 columns/block, 128 threads, ONE barrier. (verified round 4/8)
__global__ __launch_bounds__(128) void passA_kernel(const float* __restrict__ wn,
                                                    float2* __restrict__ I)
{
    __shared__ float2 L[8 * 241];
    int q = blockIdx.y;
    const float* w1p = wn + (size_t)(2 * q) * NA;
    const float* w2p = wn + (size_t)(2 * q + 1) * NA;
    int n20 = blockIdx.x * 8;
    int tid = threadIdx.x;

    if (tid < 120) {
        int b = tid >> 3, j = tid & 7;
        int n2 = n20 + j;
        float2 v[16];
#pragma unroll
        for (int a = 0; a < 16; ++a) {
            int n = (15 * a + b) * 200 + n2;
            v[a] = make_float2(w1p[n], w2p[n]);
        }
        fft16<-1>(v);
#pragma unroll
        for (int f1 = 1; f1 < 16; ++f1)
            v[f1] = cmul(v[f1], cis_rev(-(float)(b * f1) * (1.f / 240.f)));
        float2* col = L + j * 241;
#pragma unroll
        for (int f1 = 0; f1 < 16; ++f1) col[f1 * 15 + b] = v[f1];
    }
    __syncthreads();
    {
        int f1 = tid >> 3, j = tid & 7;
        int n2 = n20 + j;
        float2* col = L + j * 241;
        float2 u[15];
#pragma unroll
        for (int b = 0; b < 15; ++b) u[b] = col[f1 * 15 + b];
        fft15<-1>(u);
#pragma unroll
        for (int f2 = 0; f2 < 15; ++f2) {
            int f = f1 + 16 * f2;
            I[(size_t)q * NA + (size_t)f * 200 + n2] =
                cmul(u[f2], cis_rev(-(float)(n2 * f) * (1.f / (float)NA)));
        }
    }
}

// pass B: 4 conjugate row-pairs per block, 64 threads (single wave), grid 30x32.
template<int MODE>
__global__ __launch_bounds__(64) void passB_kernel(float2* __restrict__ I,
    const float* __restrict__ avg_shape,
    const float* __restrict__ loc_w, float* __restrict__ acc, float* __restrict__ z0)
{
    __shared__ float2 L[8 * 202];
    __shared__ float g1sh[32], g2sh[32];
    __shared__ float fs[5][32];
    int q = blockIdx.y;
    int b1 = 2 * q, b2 = 2 * q + 1;
    int bx = blockIdx.x;
    int tid = threadIdx.x;
    if (MODE == 0) {
        if (tid < 32) { g1sh[tid] = avg_shape[b1 * 32 + tid]; g2sh[tid] = avg_shape[b2 * 32 + tid]; }
    } else {
        if (tid < 5) { g1sh[tid] = loc_w[b1 * 5 + tid]; g2sh[tid] = loc_w[b2 * 5 + tid]; }
        for (int idx = tid; idx < 160; idx += 64) {
            int c = idx >> 5, i = idx & 31;
            fs[c][i] = filter_shape_val(c, i);
        }
    }
    int Rrow[8];
#pragma unroll
    for (int s = 0; s < 8; ++s) {
        int p = s >> 1;
        int pi = 4 * bx + p;
        Rrow[s] = (pi == 0) ? ((s & 1) ? 120 : 0) : ((s & 1) ? 240 - pi : pi);
    }
    // F1
    for (int idx = tid; idx < 200; idx += 64) {
        int s = idx / 25, b = idx - 25 * s;
        const float2* g = I + (size_t)q * NA + (size_t)Rrow[s] * 200;
        float2 v[8];
#pragma unroll
        for (int a = 0; a < 8; ++a) v[a] = g[25 * a + b];
        dftR<-1, 8>(v);
#pragma unroll
        for (int f1 = 1; f1 < 8; ++f1)
            v[f1] = cmul(v[f1], cis_rev(-(float)(b * f1) * (1.f / 200.f)));
        float2* row = L + s * 202;
#pragma unroll
        for (int f1 = 0; f1 < 8; ++f1) row[f1 * 25 + b] = v[f1];
    }
    __syncthreads();
    // F2
    {
        int s = tid >> 3, f1 = tid & 7;
        float2* row = L + s * 202;
        float2 u[25];
#pragma unroll
        for (int b = 0; b < 25; ++b) u[b] = row[f1 * 25 + b];
        fft25<-1>(u);
#pragma unroll
        for (int f2 = 0; f2 < 25; ++f2) row[f1 * 25 + f2] = u[f2];
    }
    __syncthreads();
    // combine
    float part1 = 0.f, part2 = 0.f;
    for (int idx = tid; idx < 804; idx += 64) {
        int p = idx / 201, t = idx - p * 201;
        int pi = 4 * bx + p;
        float2* rwA = L + (2 * p) * 202;
        float2* rwB = L + (2 * p + 1) * 202;
        int k = -1;
        float2 Za, Zb;
        int sa = 0, sb = 0;
        float2* wa = rwA; float2* wb = rwB;
        bool self1 = false;
        if (pi != 0) {
            if (t >= 200) continue;
            sa = slotn(t); sb = slotn(199 - t);
            Za = rwA[sa]; Zb = rwB[sb];
            k = pi + 240 * t;
        } else if (t < 101) {
            wa = rwA; wb = rwA;
            if (t == 0 || t == 100) {
                sa = slotn(t); sb = sa;
                Za = rwA[sa]; Zb = Za;
                k = 240 * t;
                self1 = true;
            } else {
                sa = slotn(t); sb = slotn(200 - t);
                Za = rwA[sa]; Zb = rwA[sb];
                k = 240 * t;
            }
        } else {
            int t2 = t - 101;
            if (t2 >= 100) continue;
            wa = rwB; wb = rwB;
            sa = slotn(t2); sb = slotn(199 - t2);
            Za = rwB[sa]; Zb = rwB[sb];
            k = 120 + 240 * t2;
        }
        int kbin = min(k, NA - k);
        float g1, g2;
        if (MODE == 0) {
            int jj = (kbin * 32) / NBINS;
            if (jj < 31 && (NBINS * (jj + 1)) / 32 <= kbin) ++jj;
            g1 = g1sh[jj]; g2 = g2sh[jj];
        } else {
            float sf = ((float)kbin + 0.5f) * (32.0f / 24001.0f) - 0.5f;
            sf = fminf(fmaxf(sf, 0.f), 31.f);
            int i0 = (int)sf;
            int i1 = min(i0 + 1, 31);
            float w = sf - (float)i0;
            g1 = 0.f; g2 = 0.f;
#pragma unroll
            for (int c = 0; c < 5; ++c) {
                float fb = fs[c][i0] * (1.f - w) + fs[c][i1] * w;
                g1 += g1sh[c] * fb; g2 += g2sh[c] * fb;
            }
        }
        float2 C, Cp; float e1, e2;
        pair_combine(Za, Zb, g1, g2, C, Cp, e1, e2);
        if (MODE == 0) {
            float wgt = self1 ? 1.f : 2.f;
            part1 += wgt * e1; part2 += wgt * e2;
            if (k == 0) { z0[b1] = g1 * Za.x; z0[b2] = g2 * Za.y; }
        }
        wa[sa] = make_float2(C.x * (1.f / NA), C.y * (1.f / NA));
        if (!self1) wb[sb] = make_float2(Cp.x * (1.f / NA), Cp.y * (1.f / NA));
    }
    if (MODE == 0) {
        for (int o = 32; o > 0; o >>= 1) {
            part1 += __shfl_down(part1, o);
            part2 += __shfl_down(part2, o);
        }
        if (tid == 0) { atomicAdd(&acc[b1], part1); atomicAdd(&acc[b2], part2); }
    }
    __syncthreads();
    // I1
    {
        int s = tid >> 3, f1 = tid & 7;
        float2* row = L + s * 202;
        float2 u[25];
#pragma unroll
        for (int f2 = 0; f2 < 25; ++f2) u[f2] = row[f1 * 25 + f2];
        fft25<+1>(u);
#pragma unroll
        for (int b = 0; b < 25; ++b) row[f1 * 25 + b] = u[b];
    }
    __syncthreads();
    // I2
    for (int idx = tid; idx < 200; idx += 64) {
        int s = idx / 25, b = idx - 25 * s;
        float2* row = L + s * 202;
        float2 w[8];
#pragma unroll
        for (int f1 = 0; f1 < 8; ++f1) w[f1] = row[f1 * 25 + b];
#pragma unroll
        for (int f1 = 1; f1 < 8; ++f1)
            w[f1] = cmul(w[f1], cis_rev((float)(b * f1) * (1.f / 200.f)));
        dftR<+1, 8>(w);
        int rg = Rrow[s];
        float2* g = I + (size_t)q * NA + (size_t)rg * 200;
#pragma unroll
        for (int a = 0; a < 8; ++a) {
            int e = 25 * a + b;
            g[e] = cmul(w[a], cis_rev((float)(e * rg) * (1.f / (float)NA)));
        }
    }
}

// pass C: inv240 -> modulate -> fwd240; 8 columns/block, 128 threads, TWO barriers.
__global__ __launch_bounds__(128) void passC_kernel(float2* __restrict__ I,
    const float* __restrict__ control, const float* __restrict__ f0,
    const float* __restrict__ acc, const float* __restrict__ z0)
{
    __shared__ float2 L[8 * 241];
    __shared__ float ctlA[600], ctlB[600];
    __shared__ float f0A[200], f0B[200];
    int q = blockIdx.y;
    int b1 = 2 * q, b2 = 2 * q + 1;
    int n20 = blockIdx.x * 8;
    int tid = threadIdx.x;
    for (int i = tid; i < 600; i += 128) {
        ctlA[i] = control[(size_t)b1 * 1600 + i];
        ctlB[i] = control[(size_t)b2 * 1600 + i];
    }
    for (int i = tid; i < 200; i += 128) {
        f0A[i] = f0[b1 * 200 + i];
        f0B[i] = f0[b2 * 200 + i];
    }
    {
        int f1 = tid >> 3, j = tid & 7;
        int n2 = n20 + j;
        float2 u[15];
#pragma unroll
        for (int f2 = 0; f2 < 15; ++f2)
            u[f2] = I[(size_t)q * NA + (size_t)(f1 + 16 * f2) * 200 + n2];
        fft15<+1>(u);
        float2* col = L + j * 241;
#pragma unroll
        for (int b = 0; b < 15; ++b) col[f1 * 15 + b] = u[b];
    }
    __syncthreads();
    if (tid < 120) {
        int b = tid >> 3, j = tid & 7;
        int n2 = n20 + j;
        float2* col = L + j * 241;
        float var1 = (acc[b1] - z0[b1] * z0[b1]) / (48000.f * 47999.f);
        float sc1 = 0.1f / sqrtf(var1);
        float var2 = (acc[b2] - z0[b2] * z0[b2]) / (48000.f * 47999.f);
        float sc2 = 0.1f / sqrtf(var2);
        float2 w[16];
#pragma unroll
        for (int f1 = 0; f1 < 16; ++f1) w[f1] = col[f1 * 15 + b];
#pragma unroll
        for (int f1 = 1; f1 < 16; ++f1)
            w[f1] = cmul(w[f1], cis_rev((float)(b * f1) * (1.f / 240.f)));
        fft16<+1>(w);
#pragma unroll
        for (int a = 0; a < 16; ++a) {
            int n = 200 * (15 * a + b) + n2;
            float sf = ((float)n + 0.5f) * (1.f / 240.f) - 0.5f;
            sf = fminf(fmaxf(sf, 0.f), 199.f);
            int i0 = (int)sf;
            int i1 = min(i0 + 1, 199);
            float wt = sf - (float)i0, w0 = 1.f - wt;
            float inh = ctlA[i0] * w0 + ctlA[i1] * wt;
            float exh = ctlA[200 + i0] * w0 + ctlA[200 + i1] * wt;
            float pr  = ctlA[400 + i0] * w0 + ctlA[400 + i1] * wt;
            float vv  = (f0A[i0] > 0.f ? 1.f : 0.f) * w0 + (f0A[i1] > 0.f ? 1.f : 0.f) * wt;
            float m1 = inh * (1.f - vv) + exh * pr;
            inh = ctlB[i0] * w0 + ctlB[i1] * wt;
            exh = ctlB[200 + i0] * w0 + ctlB[200 + i1] * wt;
            pr  = ctlB[400 + i0] * w0 + ctlB[400 + i1] * wt;
            vv  = (f0B[i0] > 0.f ? 1.f : 0.f) * w0 + (f0B[i1] > 0.f ? 1.f : 0.f) * wt;
            float m2 = inh * (1.f - vv) + exh * pr;
            w[a] = make_float2(w[a].x * sc1 * m1, w[a].y * sc2 * m2);
        }
        fft16<-1>(w);
#pragma unroll
        for (int f1 = 1; f1 < 16; ++f1)
            w[f1] = cmul(w[f1], cis_rev(-(float)(b * f1) * (1.f / 240.f)));
#pragma unroll
        for (int f1 = 0; f1 < 16; ++f1) col[f1 * 15 + b] = w[f1];
    }
    __syncthreads();
    {
        int f1 = tid >> 3, j = tid & 7;
        int n2 = n20 + j;
        float2* col = L + j * 241;
        float2 u[15];
#pragma unroll
        for (int b = 0; b < 15; ++b) u[b] = col[f1 * 15 + b];
        fft15<-1>(u);
#pragma unroll
        for (int f2 = 0; f2 < 15; ++f2) {
            int f = f1 + 16 * f2;
            I[(size_t)q * NA + (size_t)f * 200 + n2] =
                cmul(u[f2], cis_rev(-(float)(n2 * f) * (1.f / (float)NA)));
        }
    }
}

// pass D: inv240 -> two real outputs; 8 columns/block, 128 threads, ONE barrier.
__global__ __launch_bounds__(128) void passD_kernel(const float2* __restrict__ I,
                                                    float* __restrict__ out)
{
    __shared__ float2 L[8 * 241];
    int q = blockIdx.y;
    int b1 = 2 * q, b2 = 2 * q + 1;
    int n20 = blockIdx.x * 8;
    int tid = threadIdx.x;
    {
        int f1 = tid >> 3, j = tid & 7;
        int n2 = n20 + j;
        float2 u[15];
#pragma unroll
        for (int f2 = 0; f2 < 15; ++f2)
            u[f2] = I[(size_t)q * NA + (size_t)(f1 + 16 * f2) * 200 + n2];
        fft15<+1>(u);
        float2* col = L + j * 241;
#pragma unroll
        for (int b = 0; b < 15; ++b) col[f1 * 15 + b] = u[b];
    }
    __syncthreads();
    if (tid < 120) {
        int b = tid >> 3, j = tid & 7;
        int n2 = n20 + j;
        float2* col = L + j * 241;
        float2 w[16];
#pragma unroll
        for (int f1 = 0; f1 < 16; ++f1) w[f1] = col[f1 * 15 + b];
#pragma unroll
        for (int f1 = 1; f1 < 16; ++f1)
            w[f1] = cmul(w[f1], cis_rev((float)(b * f1) * (1.f / 240.f)));
        fft16<+1>(w);
#pragma unroll
        for (int a = 0; a < 16; ++a) {
            int n = 200 * (15 * a + b) + n2;
            out[(size_t)b1 * NA + n] = w[a].x;
            out[(size_t)b2 * NA + n] = w[a].y;
        }
    }
}

// ---------------- head: grid (4, BB) x 64 threads; 50 t-rows per block ----------------
// avg_shape/loc_w accumulated via atomicAdd of per-block partial means (zeroed in prep).
__global__ __launch_bounds__(64) void head_kernel(const unsigned short* __restrict__ h3T,
                            const float* __restrict__ w4,
                            const float* __restrict__ b4, float* __restrict__ control,
                            float* __restrict__ avg_shape, float* __restrict__ out_bf,
                            float* __restrict__ loc_w)
{
    __shared__ float w4s[40 * 64];
    __shared__ float b4s[40];
    __shared__ float sp[50 * 33];
    __shared__ float turbsh[5][50];
    int b = blockIdx.y;
    int t0 = blockIdx.x * 50;
    int tid = threadIdx.x;
    for (int j = tid; j < 40 * 64; j += 64) w4s[j] = w4[j];
    if (tid < 40) b4s[tid] = b4[tid];
    __syncthreads();
    if (tid < 50) {
        int t = t0 + tid;
        float p[40];
#pragma unroll
        for (int o = 0; o < 40; ++o) p[o] = b4s[o];
        const unsigned short* hb = h3T + ((size_t)b * 200 + t) * 64;
        for (int i = 0; i < 64; ++i) {
            float h = bf2f(hb[i]);
#pragma unroll
            for (int o = 0; o < 40; ++o) p[o] += h * w4s[o * 64 + i];
        }
        float inh = 1.f / (1.f + expf(-p[0]));
        float exh = 1.f / (1.f + expf(-p[1]));
        float pr  = 1.f / (1.f + expf(-p[2]));
        float mx = p[3];
#pragma unroll
        for (int c = 1; c < 32; ++c) mx = fmaxf(mx, p[3 + c]);
        float e[32];
        float sum = 0.f;
#pragma unroll
        for (int c = 0; c < 32; ++c) { e[c] = expf(p[3 + c] - mx); sum += e[c]; }
        float inv = 1.f / sum;
#pragma unroll
        for (int c = 0; c < 32; ++c) sp[tid * 33 + c] = e[c] * inv;
        float mx2 = p[35];
#pragma unroll
        for (int c = 1; c < 5; ++c) mx2 = fmaxf(mx2, p[35 + c]);
        float e2[5];
        float s2 = 0.f;
#pragma unroll
        for (int c = 0; c < 5; ++c) { e2[c] = expf(p[35 + c] - mx2); s2 += e2[c]; }
        float inv2 = 1.f / s2;
        float* ctl = control + (size_t)b * 8 * 200;
        ctl[0 * 200 + t] = inh;
        ctl[1 * 200 + t] = exh;
        ctl[2 * 200 + t] = pr;
#pragma unroll
        for (int c = 0; c < 5; ++c) {
            float tv = e2[c] * inv2;
            ctl[(3 + c) * 200 + t] = tv;
            turbsh[c][tid] = tv;
        }
        float* bf = out_bf + (size_t)b * 3 * 200;
        bf[0 * 200 + t] = pr;
        bf[1 * 200 + t] = inh;
        bf[2 * 200 + t] = exh;
    }
    __syncthreads();
    if (tid < 32) {
        float s = 0.f;
        for (int j = 0; j < 50; ++j) s += sp[j * 33 + tid];
        atomicAdd(&avg_shape[b * 32 + tid], s * (1.f / 200.f));
    } else if (tid < 37) {
        int c = tid - 32;
        float s = 0.f;
        for (int j = 0; j < 50; ++j) s += turbsh[c][j];
        atomicAdd(&loc_w[b * 5 + c], s * (1.f / 200.f));
    }
}

extern "C" void kernel_launch(void* const* d_in, const int* in_sizes, int n_in,
                              void* d_out, int out_size, void* d_ws, size_t ws_size,
                              hipStream_t stream)
{
    const float* cond = (const float*)d_in[0];
    const float* f0   = (const float*)d_in[1];
    const float* wn   = (const float*)d_in[2];
    const float* w1   = (const float*)d_in[3];
    const float* b1   = (const float*)d_in[4];
    const float* w2   = (const float*)d_in[5];
    const float* b2   = (const float*)d_in[6];
    const float* w3   = (const float*)d_in[7];
    const float* b3   = (const float*)d_in[8];
    const float* w4   = (const float*)d_in[9];
    const float* b4   = (const float*)d_in[10];

    float* out = (float*)d_out;
    float* filtered = out;
    float* bf_out   = out + (size_t)BB * NA;

    char* ws = (char*)d_ws;
    size_t off = 0;
    float2* I = (float2*)(ws + off);            off += 24576000;
    unsigned short* xpT1 = (unsigned short*)(ws + off); off += (size_t)BB * 212 * 160 * 2;
    unsigned short* xpT2 = (unsigned short*)(ws + off); off += (size_t)BB * 210 * 256 * 2;
    unsigned short* xpT3 = (unsigned short*)(ws + off); off += (size_t)BB * 210 * 128 * 2;
    unsigned short* xpT4 = (unsigned short*)(ws + off); off += (size_t)BB * 200 * 64 * 2;
    unsigned short* wT1  = (unsigned short*)(ws + off); off += (size_t)5 * 256 * 160 * 2;
    unsigned short* wT2  = (unsigned short*)(ws + off); off += (size_t)3 * 128 * 256 * 2;
    unsigned short* wT3  = (unsigned short*)(ws + off); off += (size_t)3 * 64 * 128 * 2;
    float* control   = (float*)(ws + off);
    float* avg_shape = control + 102400;
    float* loc_w     = avg_shape + 2048;
    float* acc       = loc_w + 320;
    float* z0        = acc + 64;

    dim3 blk(256);

    // single merged prep launch (x1 staging + halo zero + stat zero + weight transpose)
    {
        int total = N_X1 + N_H2 + N_H3 + N_ZF + NW1 + NW2 + NW3;
        prep_all_kernel<<<dim3((total + 255) / 256), blk, 0, stream>>>(
            cond, f0, w1, w2, w3, xpT1, (uint4*)xpT2, (uint4*)xpT3,
            wT1, wT2, wT3, (uint4*)avg_shape);
    }

    // MFMA conv stack
    conv_mfma_kernel<4, 5, 5, 160, 256><<<dim3(13, BB), blk, 0, stream>>>(
        xpT1, 212, wT1, b1, xpT2, 210, 1);
    conv_mfma_kernel<2, 3, 8, 256, 128><<<dim3(13, BB), blk, 0, stream>>>(
        xpT2, 210, wT2, b2, xpT3, 210, 1);
    conv_mfma_kernel<1, 3, 4, 128, 64><<<dim3(13, BB), blk, 0, stream>>>(
        xpT3, 210, wT3, b3, xpT4, 200, 0);

    head_kernel<<<dim3(4, BB), dim3(64), 0, stream>>>(xpT4, w4, b4, control, avg_shape, bf_out, loc_w);

    // batch-paired four-step FFT pipeline (32 complex signals carry 64 real batches)
    passA_kernel<<<dim3(25, 32), dim3(128), 0, stream>>>(wn, I);
    passB_kernel<0><<<dim3(30, 32), dim3(64), 0, stream>>>(I, avg_shape, loc_w, acc, z0);
    passC_kernel<<<dim3(25, 32), dim3(128), 0, stream>>>(I, control, f0, acc, z0);
    passB_kernel<1><<<dim3(30, 32), dim3(64), 0, stream>>>(I, avg_shape, loc_w, acc, z0);
    passD_kernel<<<dim3(25, 32), dim3(128), 0, stream>>>(I, filtered);
}

// Round 15
// 295.363 us; speedup vs baseline: 1.2411x; 1.0259x over previous
//
#include <hip/hip_runtime.h>
#include <math.h>

#define BB 64
#define T_FR 200
#define NA 48000
#define NBINS 24001

typedef __attribute__((ext_vector_type(4))) float f32x4;
typedef __attribute__((ext_vector_type(8))) short bf16x8;

__device__ __forceinline__ unsigned short f2bf(float x)
{
    unsigned u = __float_as_uint(x);
    u = (u + 0x7FFFu + ((u >> 16) & 1u)) >> 16;
    return (unsigned short)u;
}
__device__ __forceinline__ float bf2f(unsigned short h)
{
    return __uint_as_float(((unsigned)h) << 16);
}

__device__ __forceinline__ float2 cmul(float2 a, float2 b)
{
    return make_float2(a.x * b.x - a.y * b.y, a.x * b.y + a.y * b.x);
}
__device__ __forceinline__ float2 cadd(float2 a, float2 b){ return make_float2(a.x+b.x, a.y+b.y); }
__device__ __forceinline__ float2 csub(float2 a, float2 b){ return make_float2(a.x-b.x, a.y-b.y); }

__device__ __forceinline__ float2 cis_rev(float rev)
{
    return make_float2(__builtin_amdgcn_cosf(rev), __builtin_amdgcn_sinf(rev));
}

// ---------------- root tables ----------------
template<int R> __device__ __forceinline__ void fill_roots(float (&cr)[R], float (&si)[R]);
template<> __device__ __forceinline__ void fill_roots<3>(float (&cr)[3], float (&si)[3])
{
    const float S = 0.86602540378443865f;
    cr[0]=1.f; cr[1]=-0.5f; cr[2]=-0.5f;
    si[0]=0.f; si[1]=S;     si[2]=-S;
}
template<> __device__ __forceinline__ void fill_roots<5>(float (&cr)[5], float (&si)[5])
{
    cr[0]=1.f; cr[1]=0.30901699437494742f; cr[2]=-0.80901699437494742f;
    cr[3]=-0.80901699437494742f; cr[4]=0.30901699437494742f;
    si[0]=0.f; si[1]=0.95105651629515357f; si[2]=0.58778525229247313f;
    si[3]=-0.58778525229247313f; si[4]=-0.95105651629515357f;
}
template<> __device__ __forceinline__ void fill_roots<8>(float (&cr)[8], float (&si)[8])
{
    const float C = 0.70710678118654752f;
    cr[0]=1.f; cr[1]=C;  cr[2]=0.f;  cr[3]=-C; cr[4]=-1.f; cr[5]=-C;  cr[6]=0.f;  cr[7]=C;
    si[0]=0.f; si[1]=C;  si[2]=1.f;  si[3]=C;  si[4]=0.f;  si[5]=-C;  si[6]=-1.f; si[7]=-C;
}

// dftR<S,R>: X[k] = sum_j v[j] * e^{S*2pi*i*j*k/R}
template<int S, int R>
__device__ __forceinline__ void dftR(float2 (&v)[R])
{
    float cr[R], si[R];
    fill_roots<R>(cr, si);
    float2 o[R];
#pragma unroll
    for (int k = 0; k < R; ++k) {
        float re = 0.f, im = 0.f;
#pragma unroll
        for (int j = 0; j < R; ++j) {
            int m = (j * k) % R;
            float ur = cr[m], ui = (S > 0) ? si[m] : -si[m];
            re += v[j].x * ur - v[j].y * ui;
            im += v[j].x * ui + v[j].y * ur;
        }
        o[k] = make_float2(re, im);
    }
#pragma unroll
    for (int k = 0; k < R; ++k) v[k] = o[k];
}

__device__ __constant__ float C25R[17] = {1.f,0.968583161f,0.876306680f,0.728968627f,0.535826795f,0.309016994f,0.062790520f,-0.187381315f,-0.425779292f,-0.637423990f,-0.809016994f,-0.929776486f,-0.992114701f,-0.992114701f,-0.929776486f,-0.809016994f,-0.637423990f};
__device__ __constant__ float C25I[17] = {0.f,0.248689887f,0.481753674f,0.684547106f,0.844327926f,0.951056516f,0.998026728f,0.982287251f,0.904827052f,0.770513243f,0.587785252f,0.368124553f,0.125333234f,-0.125333234f,-0.368124553f,-0.587785252f,-0.770513243f};
__device__ __constant__ float C15R[9] = {1.f,0.913545458f,0.669130606f,0.309016994f,-0.104528463f,-0.5f,-0.809016994f,-0.978147601f,-0.978147601f};
__device__ __constant__ float C15I[9] = {0.f,0.406736643f,0.743144825f,0.951056516f,0.994521895f,0.866025404f,0.587785252f,0.207911691f,-0.207911691f};
__device__ __constant__ float C16R[10] = {1.f,0.923879533f,0.707106781f,0.382683432f,0.f,-0.382683432f,-0.707106781f,-0.923879533f,-1.f,-0.923879533f};
__device__ __constant__ float C16I[10] = {0.f,0.382683432f,0.707106781f,0.923879533f,1.f,0.923879533f,0.707106781f,0.382683432f,0.f,-0.382683432f};

// twXX<S>(m) = e^{S*2pi*i*m/XX}
template<int S> __device__ __forceinline__ float2 tw25(int m){ return make_float2(C25R[m], S>0? C25I[m] : -C25I[m]); }
template<int S> __device__ __forceinline__ float2 tw15(int m){ return make_float2(C15R[m], S>0? C15I[m] : -C15I[m]); }
template<int S> __device__ __forceinline__ float2 tw16(int m){ return make_float2(C16R[m], S>0? C16I[m] : -C16I[m]); }

// ---------------- register sub-FFTs ----------------
template<int S> __device__ __forceinline__ void f4(float2& x0, float2& x1, float2& x2, float2& x3)
{
    float2 e = cadd(x0,x2), f = csub(x0,x2), g = cadd(x1,x3), h = csub(x1,x3);
    float2 r = (S<0) ? make_float2(h.y, -h.x) : make_float2(-h.y, h.x);
    x0 = cadd(e,g); x2 = csub(e,g); x1 = cadd(f,r); x3 = csub(f,r);
}

// fft16: natural-order in/out 16-point DFT (4x4), all registers.
template<int S> __device__ __forceinline__ void fft16(float2 (&v)[16])
{
    float2 t[4][4];
#pragma unroll
    for (int q = 0; q < 4; ++q) {
        float2 a = v[q], b = v[4+q], c = v[8+q], d = v[12+q];
        f4<S>(a,b,c,d);
        t[q][0]=a; t[q][1]=b; t[q][2]=c; t[q][3]=d;
    }
#pragma unroll
    for (int q = 1; q < 4; ++q)
#pragma unroll
        for (int r = 1; r < 4; ++r)
            t[q][r] = cmul(t[q][r], tw16<S>(q*r));
#pragma unroll
    for (int r = 0; r < 4; ++r) {
        float2 a=t[0][r], b=t[1][r], c=t[2][r], d=t[3][r];
        f4<S>(a,b,c,d);
        v[r]=a; v[r+4]=b; v[r+8]=c; v[r+12]=d;
    }
}

// fft15: natural-order in/out 15-point DFT (3x5), all registers.
template<int S> __device__ __forceinline__ void fft15(float2 (&v)[15])
{
    float2 t[5][3]; // t[d][e]
#pragma unroll
    for (int d = 0; d < 5; ++d) {
        float2 u[3] = { v[d], v[5+d], v[10+d] };
        dftR<S,3>(u);
        t[d][0]=u[0];
        t[d][1]=cmul(u[1], tw15<S>(d));
        t[d][2]=cmul(u[2], tw15<S>(2*d));
    }
#pragma unroll
    for (int e = 0; e < 3; ++e) {
        float2 u[5] = { t[0][e],t[1][e],t[2][e],t[3][e],t[4][e] };
        dftR<S,5>(u);
#pragma unroll
        for (int g = 0; g < 5; ++g) v[e + 3*g] = u[g];
    }
}

// fft25: natural-order in/out 25-point DFT (5x5), all registers.
template<int S> __device__ __forceinline__ void fft25(float2 (&v)[25])
{
    float2 t[5][5]; // t[d][e]
#pragma unroll
    for (int d = 0; d < 5; ++d) {
        float2 u[5] = { v[d], v[5+d], v[10+d], v[15+d], v[20+d] };
        dftR<S,5>(u);
        t[d][0] = u[0];
#pragma unroll
        for (int e = 1; e < 5; ++e) t[d][e] = cmul(u[e], tw25<S>(d*e));
    }
#pragma unroll
    for (int e = 0; e < 5; ++e) {
        float2 u[5] = { t[0][e],t[1][e],t[2][e],t[3][e],t[4][e] };
        dftR<S,5>(u);
#pragma unroll
        for (int g = 0; g < 5; ++g) v[e + 5*g] = u[g];
    }
}

// 200-spectrum slot: f = f1 + 8*f2 stored at 25*f1 + f2
__device__ __forceinline__ int slotn(int f) { return 25 * (f & 7) + (f >> 3); }

// Hermitian pair combine (verified)
__device__ __forceinline__ void pair_combine(float2 Za, float2 Zb, float g1, float g2,
                                             float2& C, float2& Cp, float& e1, float& e2)
{
    float2 X1 = make_float2(0.5f * (Za.x + Zb.x), 0.5f * (Za.y - Zb.y));
    float2 w  = make_float2(0.5f * (Za.x - Zb.x), 0.5f * (Za.y + Zb.y));
    float2 X2 = make_float2(w.y, -w.x);
    float2 Z1 = make_float2(g1 * X1.x, g1 * X1.y);
    float2 Z2 = make_float2(g2 * X2.x, g2 * X2.y);
    e1 = Z1.x * Z1.x + Z1.y * Z1.y;
    e2 = Z2.x * Z2.x + Z2.y * Z2.y;
    C  = make_float2(Z1.x - Z2.y,  Z1.y + Z2.x);
    Cp = make_float2(Z1.x + Z2.y, -Z1.y + Z2.x);
}

// filter shapes (5 channels over 32 bands) — same math as reference _filter_shapes
__device__ __forceinline__ float filter_shape_val(int c, int i)
{
    float lin = (float)i * (1.f / 31.f);
    if (c == 0) { float z = (lin - 0.2f) * 10.f;          return expf(-0.5f * z * z); }
    if (c == 1) { float z = (lin - 0.1f) * 10.f;          return expf(-0.5f * z * z); }
    if (c == 2) { float z = (lin - 0.4f) * (1.f / 0.15f); return expf(-0.5f * z * z); }
    if (c == 3) { float z = (lin - 0.6f) * 10.f;          return expf(-0.5f * z * z); }
    float v = 0.1f + 0.9f * lin;
    return v * v;
}

// ================= MFMA conv (unchanged, verified) =================
template<int NT, int TAPS, int CHUNKS, int CINP, int COUTP>
__global__ __launch_bounds__(256) void conv_mfma_kernel(
    const unsigned short* __restrict__ xT, int tRowsIn,
    const unsigned short* __restrict__ wT,
    const float* __restrict__ bias,
    unsigned short* __restrict__ outT, int tRowsOut, int tOffOut)
{
    const int b = blockIdx.y;
    const int t0 = blockIdx.x * 16;
    const int tid = threadIdx.x;
    const int wave = tid >> 6;
    const int lane = tid & 63;
    const int m = lane & 15;
    const int quad = lane >> 4;
    const int n0 = wave * (NT * 16);

    f32x4 acc[NT];
#pragma unroll
    for (int nt = 0; nt < NT; ++nt) acc[nt] = (f32x4){0.f, 0.f, 0.f, 0.f};

    const unsigned short* xb = xT + (size_t)b * tRowsIn * CINP;
#pragma unroll
    for (int kw = 0; kw < TAPS; ++kw) {
        const unsigned short* wk = wT + (size_t)kw * COUTP * CINP;
        const unsigned short* xrow = xb + (size_t)(t0 + kw + m) * CINP + quad * 8;
#pragma unroll
        for (int ch = 0; ch < CHUNKS; ++ch) {
            const int k0 = ch * 32;
            bf16x8 a = *(const bf16x8*)(xrow + k0);
#pragma unroll
            for (int nt = 0; nt < NT; ++nt) {
                bf16x8 bfr = *(const bf16x8*)(wk + (size_t)(n0 + nt * 16 + m) * CINP + k0 + quad * 8);
                acc[nt] = __builtin_amdgcn_mfma_f32_16x16x32_bf16(a, bfr, acc[nt], 0, 0, 0);
            }
        }
    }
#pragma unroll
    for (int nt = 0; nt < NT; ++nt) {
        const int n = n0 + nt * 16 + m;
        const float bz = bias[n];
#pragma unroll
        for (int r = 0; r < 4; ++r) {
            const int t = t0 + quad * 4 + r;
            if (t < 200) {
                float v = acc[nt][r] + bz;
                v = (v >= 0.f) ? v : 0.1f * v;
                outT[((size_t)b * tRowsOut + t + tOffOut) * COUTP + n] = f2bf(v);
            }
        }
    }
}

// ============ merged prep: x1 staging + halo zero + stat zero + weight transpose ============
#define N_X1 (BB * 212 * 160)
#define N_H2 (BB * 10 * 32)    // uint4 per xpT2 halo (10 rows x 256 shorts = 32 uint4/row)
#define N_H3 (BB * 10 * 16)    // uint4 per xpT3 halo
#define N_ZF 624               // uint4 zeroing avg_shape..z0 (2496 floats, contiguous)
#define NW1 (5 * 256 * 160)
#define NW2 (3 * 128 * 256)
#define NW3 (3 * 64 * 128)

__global__ void prep_all_kernel(const float* __restrict__ cond, const float* __restrict__ f0,
                                const float* __restrict__ w1, const float* __restrict__ w2,
                                const float* __restrict__ w3,
                                unsigned short* __restrict__ xpT1,
                                uint4* __restrict__ xpT2v, uint4* __restrict__ xpT3v,
                                unsigned short* __restrict__ wT1, unsigned short* __restrict__ wT2,
                                unsigned short* __restrict__ wT3,
                                uint4* __restrict__ zf)
{
    int idx = blockIdx.x * 256 + threadIdx.x;
    if (idx < N_X1) {
        int i = idx % 160;
        int rest = idx / 160;
        int tp = rest % 212;
        int b = rest / 212;
        int tt = tp - 2;
        float v = 0.f;
        if (tt >= 0 && tt < 200) {
            if (i < 128) v = cond[((size_t)b * 128 + i) * 200 + tt];
            else if (i == 128) v = (f0[b * 200 + tt] > 0.f) ? 1.f : 0.f;
        }
        xpT1[idx] = f2bf(v);
    } else if (idx < N_X1 + N_H2) {
        int h = idx - N_X1;
        int b = h / 320; int rem = h - b * 320;
        int r10 = rem >> 5, c = rem & 31;
        int row = (r10 == 0) ? 0 : 200 + r10;
        xpT2v[(size_t)(b * 210 + row) * 32 + c] = make_uint4(0, 0, 0, 0);
    } else if (idx < N_X1 + N_H2 + N_H3) {
        int h = idx - N_X1 - N_H2;
        int b = h / 160; int rem = h - b * 160;
        int r10 = rem >> 4, c = rem & 15;
        int row = (r10 == 0) ? 0 : 200 + r10;
        xpT3v[(size_t)(b * 210 + row) * 16 + c] = make_uint4(0, 0, 0, 0);
    } else if (idx < N_X1 + N_H2 + N_H3 + N_ZF) {
        zf[idx - N_X1 - N_H2 - N_H3] = make_uint4(0, 0, 0, 0);
    } else {
        int j = idx - N_X1 - N_H2 - N_H3 - N_ZF;
        if (j < NW1) {
            int i = j % 160; int rest = j / 160; int o = rest % 256; int kw = rest / 256;
            float v = (i < 129) ? w1[((size_t)o * 129 + i) * 5 + kw] : 0.f;
            wT1[j] = f2bf(v);
        } else if (j < NW1 + NW2) {
            int jj = j - NW1;
            int i = jj % 256; int rest = jj / 256; int o = rest % 128; int kw = rest / 128;
            wT2[jj] = f2bf(w2[((size_t)o * 256 + i) * 3 + kw]);
        } else if (j < NW1 + NW2 + NW3) {
            int jj = j - NW1 - NW2;
            int i = jj % 128; int rest = jj / 128; int o = rest % 64; int kw = rest / 64;
            wT3[jj] = f2bf(w3[((size_t)o * 128 + i) * 3 + kw]);
        }
    }
}

// ================= FFT passes =================
// 240 = 16 x 15: n1 = 15a+b; f = f1 + 16*f2. LDS slot layout: col[f1*15 + b].
// 200 = 8 x 25 : e  = 25a+b; f = f1 +  8*f2. LDS slot layout: row[f1*25 + f2].

// pass A: 8 columns/block, 64 threads (single wave; work/block unchanged — 2 tasks/thread).
__global__ __launch_bounds__(64) void passA_kernel(const float* __restrict__ wn,
                                                   float2* __restrict__ I)
{
    __shared__ float2 L[8 * 241];
    int q = blockIdx.y;
    const float* w1p = wn + (size_t)(2 * q) * NA;
    const float* w2p = wn + (size_t)(2 * q + 1) * NA;
    int n20 = blockIdx.x * 8;
    int tid = threadIdx.x;

    for (int task = tid; task < 120; task += 64) {
        int b = task >> 3, j = task & 7;
        int n2 = n20 + j;
        float2 v[16];
#pragma unroll
        for (int a = 0; a < 16; ++a) {
            int n = (15 * a + b) * 200 + n2;
            v[a] = make_float2(w1p[n], w2p[n]);
        }
        fft16<-1>(v);
#pragma unroll
        for (int f1 = 1; f1 < 16; ++f1)
            v[f1] = cmul(v[f1], cis_rev(-(float)(b * f1) * (1.f / 240.f)));
        float2* col = L + j * 241;
#pragma unroll
        for (int f1 = 0; f1 < 16; ++f1) col[f1 * 15 + b] = v[f1];
    }
    __syncthreads();
    for (int task = tid; task < 128; task += 64) {
        int f1 = task >> 3, j = task & 7;
        int n2 = n20 + j;
        float2* col = L + j * 241;
        float2 u[15];
#pragma unroll
        for (int b = 0; b < 15; ++b) u[b] = col[f1 * 15 + b];
        fft15<-1>(u);
#pragma unroll
        for (int f2 = 0; f2 < 15; ++f2) {
            int f = f1 + 16 * f2;
            I[(size_t)q * NA + (size_t)f * 200 + n2] =
                cmul(u[f2], cis_rev(-(float)(n2 * f) * (1.f / (float)NA)));
        }
    }
}

// pass B: 4 conjugate row-pairs per block, 64 threads (single wave), grid 30x32.
template<int MODE>
__global__ __launch_bounds__(64) void passB_kernel(float2* __restrict__ I,
    const float* __restrict__ avg_shape,
    const float* __restrict__ loc_w, float* __restrict__ acc, float* __restrict__ z0)
{
    __shared__ float2 L[8 * 202];
    __shared__ float g1sh[32], g2sh[32];
    __shared__ float fs[5][32];
    int q = blockIdx.y;
    int b1 = 2 * q, b2 = 2 * q + 1;
    int bx = blockIdx.x;
    int tid = threadIdx.x;
    if (MODE == 0) {
        if (tid < 32) { g1sh[tid] = avg_shape[b1 * 32 + tid]; g2sh[tid] = avg_shape[b2 * 32 + tid]; }
    } else {
        if (tid < 5) { g1sh[tid] = loc_w[b1 * 5 + tid]; g2sh[tid] = loc_w[b2 * 5 + tid]; }
        for (int idx = tid; idx < 160; idx += 64) {
            int c = idx >> 5, i = idx & 31;
            fs[c][i] = filter_shape_val(c, i);
        }
    }
    int Rrow[8];
#pragma unroll
    for (int s = 0; s < 8; ++s) {
        int p = s >> 1;
        int pi = 4 * bx + p;
        Rrow[s] = (pi == 0) ? ((s & 1) ? 120 : 0) : ((s & 1) ? 240 - pi : pi);
    }
    // F1
    for (int idx = tid; idx < 200; idx += 64) {
        int s = idx / 25, b = idx - 25 * s;
        const float2* g = I + (size_t)q * NA + (size_t)Rrow[s] * 200;
        float2 v[8];
#pragma unroll
        for (int a = 0; a < 8; ++a) v[a] = g[25 * a + b];
        dftR<-1, 8>(v);
#pragma unroll
        for (int f1 = 1; f1 < 8; ++f1)
            v[f1] = cmul(v[f1], cis_rev(-(float)(b * f1) * (1.f / 200.f)));
        float2* row = L + s * 202;
#pragma unroll
        for (int f1 = 0; f1 < 8; ++f1) row[f1 * 25 + b] = v[f1];
    }
    __syncthreads();
    // F2
    {
        int s = tid >> 3, f1 = tid & 7;
        float2* row = L + s * 202;
        float2 u[25];
#pragma unroll
        for (int b = 0; b < 25; ++b) u[b] = row[f1 * 25 + b];
        fft25<-1>(u);
#pragma unroll
        for (int f2 = 0; f2 < 25; ++f2) row[f1 * 25 + f2] = u[f2];
    }
    __syncthreads();
    // combine
    float part1 = 0.f, part2 = 0.f;
    for (int idx = tid; idx < 804; idx += 64) {
        int p = idx / 201, t = idx - p * 201;
        int pi = 4 * bx + p;
        float2* rwA = L + (2 * p) * 202;
        float2* rwB = L + (2 * p + 1) * 202;
        int k = -1;
        float2 Za, Zb;
        int sa = 0, sb = 0;
        float2* wa = rwA; float2* wb = rwB;
        bool self1 = false;
        if (pi != 0) {
            if (t >= 200) continue;
            sa = slotn(t); sb = slotn(199 - t);
            Za = rwA[sa]; Zb = rwB[sb];
            k = pi + 240 * t;
        } else if (t < 101) {
            wa = rwA; wb = rwA;
            if (t == 0 || t == 100) {
                sa = slotn(t); sb = sa;
                Za = rwA[sa]; Zb = Za;
                k = 240 * t;
                self1 = true;
            } else {
                sa = slotn(t); sb = slotn(200 - t);
                Za = rwA[sa]; Zb = rwA[sb];
                k = 240 * t;
            }
        } else {
            int t2 = t - 101;
            if (t2 >= 100) continue;
            wa = rwB; wb = rwB;
            sa = slotn(t2); sb = slotn(199 - t2);
            Za = rwB[sa]; Zb = rwB[sb];
            k = 120 + 240 * t2;
        }
        int kbin = min(k, NA - k);
        float g1, g2;
        if (MODE == 0) {
            int jj = (kbin * 32) / NBINS;
            if (jj < 31 && (NBINS * (jj + 1)) / 32 <= kbin) ++jj;
            g1 = g1sh[jj]; g2 = g2sh[jj];
        } else {
            float sf = ((float)kbin + 0.5f) * (32.0f / 24001.0f) - 0.5f;
            sf = fminf(fmaxf(sf, 0.f), 31.f);
            int i0 = (int)sf;
            int i1 = min(i0 + 1, 31);
            float w = sf - (float)i0;
            g1 = 0.f; g2 = 0.f;
#pragma unroll
            for (int c = 0; c < 5; ++c) {
                float fb = fs[c][i0] * (1.f - w) + fs[c][i1] * w;
                g1 += g1sh[c] * fb; g2 += g2sh[c] * fb;
            }
        }
        float2 C, Cp; float e1, e2;
        pair_combine(Za, Zb, g1, g2, C, Cp, e1, e2);
        if (MODE == 0) {
            float wgt = self1 ? 1.f : 2.f;
            part1 += wgt * e1; part2 += wgt * e2;
            if (k == 0) { z0[b1] = g1 * Za.x; z0[b2] = g2 * Za.y; }
        }
        wa[sa] = make_float2(C.x * (1.f / NA), C.y * (1.f / NA));
        if (!self1) wb[sb] = make_float2(Cp.x * (1.f / NA), Cp.y * (1.f / NA));
    }
    if (MODE == 0) {
        for (int o = 32; o > 0; o >>= 1) {
            part1 += __shfl_down(part1, o);
            part2 += __shfl_down(part2, o);
        }
        if (tid == 0) { atomicAdd(&acc[b1], part1); atomicAdd(&acc[b2], part2); }
    }
    __syncthreads();
    // I1
    {
        int s = tid >> 3, f1 = tid & 7;
        float2* row = L + s * 202;
        float2 u[25];
#pragma unroll
        for (int f2 = 0; f2 < 25; ++f2) u[f2] = row[f1 * 25 + f2];
        fft25<+1>(u);
#pragma unroll
        for (int b = 0; b < 25; ++b) row[f1 * 25 + b] = u[b];
    }
    __syncthreads();
    // I2
    for (int idx = tid; idx < 200; idx += 64) {
        int s = idx / 25, b = idx - 25 * s;
        float2* row = L + s * 202;
        float2 w[8];
#pragma unroll
        for (int f1 = 0; f1 < 8; ++f1) w[f1] = row[f1 * 25 + b];
#pragma unroll
        for (int f1 = 1; f1 < 8; ++f1)
            w[f1] = cmul(w[f1], cis_rev((float)(b * f1) * (1.f / 200.f)));
        dftR<+1, 8>(w);
        int rg = Rrow[s];
        float2* g = I + (size_t)q * NA + (size_t)rg * 200;
#pragma unroll
        for (int a = 0; a < 8; ++a) {
            int e = 25 * a + b;
            g[e] = cmul(w[a], cis_rev((float)(e * rg) * (1.f / (float)NA)));
        }
    }
}

// pass C: inv240 -> modulate -> fwd240; 8 columns/block, 128 threads, TWO barriers.
__global__ __launch_bounds__(128) void passC_kernel(float2* __restrict__ I,
    const float* __restrict__ control, const float* __restrict__ f0,
    const float* __restrict__ acc, const float* __restrict__ z0)
{
    __shared__ float2 L[8 * 241];
    __shared__ float ctlA[600], ctlB[600];
    __shared__ float f0A[200], f0B[200];
    int q = blockIdx.y;
    int b1 = 2 * q, b2 = 2 * q + 1;
    int n20 = blockIdx.x * 8;
    int tid = threadIdx.x;
    for (int i = tid; i < 600; i += 128) {
        ctlA[i] = control[(size_t)b1 * 1600 + i];
        ctlB[i] = control[(size_t)b2 * 1600 + i];
    }
    for (int i = tid; i < 200; i += 128) {
        f0A[i] = f0[b1 * 200 + i];
        f0B[i] = f0[b2 * 200 + i];
    }
    {
        int f1 = tid >> 3, j = tid & 7;
        int n2 = n20 + j;
        float2 u[15];
#pragma unroll
        for (int f2 = 0; f2 < 15; ++f2)
            u[f2] = I[(size_t)q * NA + (size_t)(f1 + 16 * f2) * 200 + n2];
        fft15<+1>(u);
        float2* col = L + j * 241;
#pragma unroll
        for (int b = 0; b < 15; ++b) col[f1 * 15 + b] = u[b];
    }
    __syncthreads();
    if (tid < 120) {
        int b = tid >> 3, j = tid & 7;
        int n2 = n20 + j;
        float2* col = L + j * 241;
        float var1 = (acc[b1] - z0[b1] * z0[b1]) / (48000.f * 47999.f);
        float sc1 = 0.1f / sqrtf(var1);
        float var2 = (acc[b2] - z0[b2] * z0[b2]) / (48000.f * 47999.f);
        float sc2 = 0.1f / sqrtf(var2);
        float2 w[16];
#pragma unroll
        for (int f1 = 0; f1 < 16; ++f1) w[f1] = col[f1 * 15 + b];
#pragma unroll
        for (int f1 = 1; f1 < 16; ++f1)
            w[f1] = cmul(w[f1], cis_rev((float)(b * f1) * (1.f / 240.f)));
        fft16<+1>(w);
#pragma unroll
        for (int a = 0; a < 16; ++a) {
            int n = 200 * (15 * a + b) + n2;
            float sf = ((float)n + 0.5f) * (1.f / 240.f) - 0.5f;
            sf = fminf(fmaxf(sf, 0.f), 199.f);
            int i0 = (int)sf;
            int i1 = min(i0 + 1, 199);
            float wt = sf - (float)i0, w0 = 1.f - wt;
            float inh = ctlA[i0] * w0 + ctlA[i1] * wt;
            float exh = ctlA[200 + i0] * w0 + ctlA[200 + i1] * wt;
            float pr  = ctlA[400 + i0] * w0 + ctlA[400 + i1] * wt;
            float vv  = (f0A[i0] > 0.f ? 1.f : 0.f) * w0 + (f0A[i1] > 0.f ? 1.f : 0.f) * wt;
            float m1 = inh * (1.f - vv) + exh * pr;
            inh = ctlB[i0] * w0 + ctlB[i1] * wt;
            exh = ctlB[200 + i0] * w0 + ctlB[200 + i1] * wt;
            pr  = ctlB[400 + i0] * w0 + ctlB[400 + i1] * wt;
            vv  = (f0B[i0] > 0.f ? 1.f : 0.f) * w0 + (f0B[i1] > 0.f ? 1.f : 0.f) * wt;
            float m2 = inh * (1.f - vv) + exh * pr;
            w[a] = make_float2(w[a].x * sc1 * m1, w[a].y * sc2 * m2);
        }
        fft16<-1>(w);
#pragma unroll
        for (int f1 = 1; f1 < 16; ++f1)
            w[f1] = cmul(w[f1], cis_rev(-(float)(b * f1) * (1.f / 240.f)));
#pragma unroll
        for (int f1 = 0; f1 < 16; ++f1) col[f1 * 15 + b] = w[f1];
    }
    __syncthreads();
    {
        int f1 = tid >> 3, j = tid & 7;
        int n2 = n20 + j;
        float2* col = L + j * 241;
        float2 u[15];
#pragma unroll
        for (int b = 0; b < 15; ++b) u[b] = col[f1 * 15 + b];
        fft15<-1>(u);
#pragma unroll
        for (int f2 = 0; f2 < 15; ++f2) {
            int f = f1 + 16 * f2;
            I[(size_t)q * NA + (size_t)f * 200 + n2] =
                cmul(u[f2], cis_rev(-(float)(n2 * f) * (1.f / (float)NA)));
        }
    }
}

// pass D: inv240 -> two real outputs; 8 columns/block, 64 threads (single wave).
__global__ __launch_bounds__(64) void passD_kernel(const float2* __restrict__ I,
                                                   float* __restrict__ out)
{
    __shared__ float2 L[8 * 241];
    int q = blockIdx.y;
    int b1 = 2 * q, b2 = 2 * q + 1;
    int n20 = blockIdx.x * 8;
    int tid = threadIdx.x;
    for (int task = tid; task < 128; task += 64) {
        int f1 = task >> 3, j = task & 7;
        int n2 = n20 + j;
        float2 u[15];
#pragma unroll
        for (int f2 = 0; f2 < 15; ++f2)
            u[f2] = I[(size_t)q * NA + (size_t)(f1 + 16 * f2) * 200 + n2];
        fft15<+1>(u);
        float2* col = L + j * 241;
#pragma unroll
        for (int b = 0; b < 15; ++b) col[f1 * 15 + b] = u[b];
    }
    __syncthreads();
    for (int task = tid; task < 120; task += 64) {
        int b = task >> 3, j = task & 7;
        int n2 = n20 + j;
        float2* col = L + j * 241;
        float2 w[16];
#pragma unroll
        for (int f1 = 0; f1 < 16; ++f1) w[f1] = col[f1 * 15 + b];
#pragma unroll
        for (int f1 = 1; f1 < 16; ++f1)
            w[f1] = cmul(w[f1], cis_rev((float)(b * f1) * (1.f / 240.f)));
        fft16<+1>(w);
#pragma unroll
        for (int a = 0; a < 16; ++a) {
            int n = 200 * (15 * a + b) + n2;
            out[(size_t)b1 * NA + n] = w[a].x;
            out[(size_t)b2 * NA + n] = w[a].y;
        }
    }
}

// ---------------- head: grid (4, BB) x 64 threads; 50 t-rows per block ----------------
__global__ __launch_bounds__(64) void head_kernel(const unsigned short* __restrict__ h3T,
                            const float* __restrict__ w4,
                            const float* __restrict__ b4, float* __restrict__ control,
                            float* __restrict__ avg_shape, float* __restrict__ out_bf,
                            float* __restrict__ loc_w)
{
    __shared__ float w4s[40 * 64];
    __shared__ float b4s[40];
    __shared__ float sp[50 * 33];
    __shared__ float turbsh[5][50];
    int b = blockIdx.y;
    int t0 = blockIdx.x * 50;
    int tid = threadIdx.x;
    for (int j = tid; j < 40 * 64; j += 64) w4s[j] = w4[j];
    if (tid < 40) b4s[tid] = b4[tid];
    __syncthreads();
    if (tid < 50) {
        int t = t0 + tid;
        float p[40];
#pragma unroll
        for (int o = 0; o < 40; ++o) p[o] = b4s[o];
        const unsigned short* hb = h3T + ((size_t)b * 200 + t) * 64;
        for (int i = 0; i < 64; ++i) {
            float h = bf2f(hb[i]);
#pragma unroll
            for (int o = 0; o < 40; ++o) p[o] += h * w4s[o * 64 + i];
        }
        float inh = 1.f / (1.f + expf(-p[0]));
        float exh = 1.f / (1.f + expf(-p[1]));
        float pr  = 1.f / (1.f + expf(-p[2]));
        float mx = p[3];
#pragma unroll
        for (int c = 1; c < 32; ++c) mx = fmaxf(mx, p[3 + c]);
        float e[32];
        float sum = 0.f;
#pragma unroll
        for (int c = 0; c < 32; ++c) { e[c] = expf(p[3 + c] - mx); sum += e[c]; }
        float inv = 1.f / sum;
#pragma unroll
        for (int c = 0; c < 32; ++c) sp[tid * 33 + c] = e[c] * inv;
        float mx2 = p[35];
#pragma unroll
        for (int c = 1; c < 5; ++c) mx2 = fmaxf(mx2, p[35 + c]);
        float e2[5];
        float s2 = 0.f;
#pragma unroll
        for (int c = 0; c < 5; ++c) { e2[c] = expf(p[35 + c] - mx2); s2 += e2[c]; }
        float inv2 = 1.f / s2;
        float* ctl = control + (size_t)b * 8 * 200;
        ctl[0 * 200 + t] = inh;
        ctl[1 * 200 + t] = exh;
        ctl[2 * 200 + t] = pr;
#pragma unroll
        for (int c = 0; c < 5; ++c) {
            float tv = e2[c] * inv2;
            ctl[(3 + c) * 200 + t] = tv;
            turbsh[c][tid] = tv;
        }
        float* bf = out_bf + (size_t)b * 3 * 200;
        bf[0 * 200 + t] = pr;
        bf[1 * 200 + t] = inh;
        bf[2 * 200 + t] = exh;
    }
    __syncthreads();
    if (tid < 32) {
        float s = 0.f;
        for (int j = 0; j < 50; ++j) s += sp[j * 33 + tid];
        atomicAdd(&avg_shape[b * 32 + tid], s * (1.f / 200.f));
    } else if (tid < 37) {
        int c = tid - 32;
        float s = 0.f;
        for (int j = 0; j < 50; ++j) s += turbsh[c][j];
        atomicAdd(&loc_w[b * 5 + c], s * (1.f / 200.f));
    }
}

extern "C" void kernel_launch(void* const* d_in, const int* in_sizes, int n_in,
                              void* d_out, int out_size, void* d_ws, size_t ws_size,
                              hipStream_t stream)
{
    const float* cond = (const float*)d_in[0];
    const float* f0   = (const float*)d_in[1];
    const float* wn   = (const float*)d_in[2];
    const float* w1   = (const float*)d_in[3];
    const float* b1   = (const float*)d_in[4];
    const float* w2   = (const float*)d_in[5];
    const float* b2   = (const float*)d_in[6];
    const float* w3   = (const float*)d_in[7];
    const float* b3   = (const float*)d_in[8];
    const float* w4   = (const float*)d_in[9];
    const float* b4   = (const float*)d_in[10];

    float* out = (float*)d_out;
    float* filtered = out;
    float* bf_out   = out + (size_t)BB * NA;

    char* ws = (char*)d_ws;
    size_t off = 0;
    float2* I = (float2*)(ws + off);            off += 24576000;
    unsigned short* xpT1 = (unsigned short*)(ws + off); off += (size_t)BB * 212 * 160 * 2;
    unsigned short* xpT2 = (unsigned short*)(ws + off); off += (size_t)BB * 210 * 256 * 2;
    unsigned short* xpT3 = (unsigned short*)(ws + off); off += (size_t)BB * 210 * 128 * 2;
    unsigned short* xpT4 = (unsigned short*)(ws + off); off += (size_t)BB * 200 * 64 * 2;
    unsigned short* wT1  = (unsigned short*)(ws + off); off += (size_t)5 * 256 * 160 * 2;
    unsigned short* wT2  = (unsigned short*)(ws + off); off += (size_t)3 * 128 * 256 * 2;
    unsigned short* wT3  = (unsigned short*)(ws + off); off += (size_t)3 * 64 * 128 * 2;
    float* control   = (float*)(ws + off);
    float* avg_shape = control + 102400;
    float* loc_w     = avg_shape + 2048;
    float* acc       = loc_w + 320;
    float* z0        = acc + 64;

    dim3 blk(256);

    // single merged prep launch (x1 staging + halo zero + stat zero + weight transpose)
    {
        int total = N_X1 + N_H2 + N_H3 + N_ZF + NW1 + NW2 + NW3;
        prep_all_kernel<<<dim3((total + 255) / 256), blk, 0, stream>>>(
            cond, f0, w1, w2, w3, xpT1, (uint4*)xpT2, (uint4*)xpT3,
            wT1, wT2, wT3, (uint4*)avg_shape);
    }

    // MFMA conv stack
    conv_mfma_kernel<4, 5, 5, 160, 256><<<dim3(13, BB), blk, 0, stream>>>(
        xpT1, 212, wT1, b1, xpT2, 210, 1);
    conv_mfma_kernel<2, 3, 8, 256, 128><<<dim3(13, BB), blk, 0, stream>>>(
        xpT2, 210, wT2, b2, xpT3, 210, 1);
    conv_mfma_kernel<1, 3, 4, 128, 64><<<dim3(13, BB), blk, 0, stream>>>(
        xpT3, 210, wT3, b3, xpT4, 200, 0);

    head_kernel<<<dim3(4, BB), dim3(64), 0, stream>>>(xpT4, w4, b4, control, avg_shape, bf_out, loc_w);

    // batch-paired four-step FFT pipeline (32 complex signals carry 64 real batches)
    passA_kernel<<<dim3(25, 32), dim3(64), 0, stream>>>(wn, I);
    passB_kernel<0><<<dim3(30, 32), dim3(64), 0, stream>>>(I, avg_shape, loc_w, acc, z0);
    passC_kernel<<<dim3(25, 32), dim3(128), 0, stream>>>(I, control, f0, acc, z0);
    passB_kernel<1><<<dim3(30, 32), dim3(64), 0, stream>>>(I, avg_shape, loc_w, acc, z0);
    passD_kernel<<<dim3(25, 32), dim3(64), 0, stream>>>(I, filtered);
}